// Round 1
// baseline (430.779 us; speedup 1.0000x reference)
//
#include <hip/hip_runtime.h>
#include <hip/hip_bf16.h>
#include <stdint.h>

// ---------------------------------------------------------------------------
// CrossAttention: out = softmax((X Wq)(K Wk)^T * s) (V Wv) Wo  (+biases)
// B=4, Nq=4096, Nk=1024, QUERY_DIM=1024, KEY_DIM=768, H=16, HD=64
// R5: baseline re-establish after infra failure. Only change vs the verified
//     438.7 µs kernel: key+value f32->bf16 conversions merged into one
//     launch (blockIdx.z-style select via blockIdx.y). All compute kernels
//     byte-identical.
// Carried: XOR-swizzled LDS, no-max exp2 softmax, packed bf16 cvt, MFMA
//     row-sum on the idle matrix pipe, fused K/V projection.
// ---------------------------------------------------------------------------

typedef unsigned short u16;
typedef __attribute__((ext_vector_type(8))) short short8;   // 8 bf16 = 4 VGPRs
typedef __attribute__((ext_vector_type(4))) float f32x4;    // MFMA C/D frag

#define B_SZ 4
#define NQ   4096
#define NK   1024
#define QDIM 1024
#define KDIM 768
#define NH   16
#define HD   64
// scale * log2(e): softmax computed in exp2 domain (folded into Q projection)
#define QSCALE (0.125f * 1.44269504f)

__device__ __forceinline__ u16 f2bf(float f) {
  union { float f; uint32_t u; } v; v.f = f;
  uint32_t u = v.u;
  return (u16)((u + 0x7FFFu + ((u >> 16) & 1u)) >> 16);  // RNE
}

// packed f32x2 -> bf16x2 (v_cvt_pk_bf16_f32 on gfx950)
__device__ __forceinline__ uint32_t pk2(float a, float b) {
  union { __hip_bfloat162 h; uint32_t u; } cv;
  cv.h = __float22bfloat162_rn(float2{a, b});
  return cv.u;
}

__device__ __forceinline__ float fexp2(float x) {
  return exp2f(x);  // v_exp_f32
}

// global -> LDS async copy, 16B per lane; lds base must be wave-uniform.
__device__ __forceinline__ void async16(u16* lds, const u16* g) {
  __builtin_amdgcn_global_load_lds(
      (__attribute__((address_space(1))) void*)(g),
      (__attribute__((address_space(3))) void*)(lds), 16, 0, 0);
}

// ---------------------------------------------------------------------------
// fp32 -> bf16 elementwise (vectorized x4, packed cvt)
// ---------------------------------------------------------------------------
__global__ __launch_bounds__(256) void f32_to_bf16_k(const float* __restrict__ in,
                                                     u16* __restrict__ out, int n4) {
  int i = blockIdx.x * 256 + threadIdx.x;
  if (i < n4) {
    f32x4 v = ((const f32x4*)in)[i];
    uint2 o = {pk2(v.x, v.y), pk2(v.z, v.w)};
    ((uint2*)out)[i] = o;
  }
}

// two-tensor variant: blockIdx.y selects (a->oa) or (b->ob); one launch for K+V
__global__ __launch_bounds__(256) void f32_to_bf16_2k(const float* __restrict__ a,
                                                      const float* __restrict__ b,
                                                      u16* __restrict__ oa,
                                                      u16* __restrict__ ob, int n4) {
  int i = blockIdx.x * 256 + threadIdx.x;
  const float* in = blockIdx.y ? b : a;
  u16* out = blockIdx.y ? ob : oa;
  if (i < n4) {
    f32x4 v = ((const f32x4*)in)[i];
    uint2 o = {pk2(v.x, v.y), pk2(v.z, v.w)};
    ((uint2*)out)[i] = o;
  }
}

// ---------------------------------------------------------------------------
// W (K x N fp32, row-major) -> Wt (N x K bf16, row-major)   [LDS-tiled]
// ---------------------------------------------------------------------------
__global__ __launch_bounds__(256) void transpose_bf16_k(const float* __restrict__ W,
                                                        u16* __restrict__ Wt,
                                                        int K, int N) {
  __shared__ float t[32][33];
  int tx = threadIdx.x & 31, ty = threadIdx.x >> 5;  // 32 x 8
  int nb = blockIdx.x * 32, kb = blockIdx.y * 32;
#pragma unroll
  for (int i = 0; i < 4; ++i)
    t[ty + i * 8][tx] = W[(size_t)(kb + ty + i * 8) * N + nb + tx];
  __syncthreads();
#pragma unroll
  for (int i = 0; i < 4; ++i)
    Wt[(size_t)(nb + ty + i * 8) * K + kb + tx] = f2bf(t[tx][ty + i * 8]);
}

// ---------------------------------------------------------------------------
// C[M,N] = (A[M,K] * Bt[N,K]^T + bias) * scale ; out bf16 or fp32
// 128x128 tile, BK=64, 256 threads (4 waves, each 64x64 = 4x4 16x16 frags)
// LDS rows (128B) chunk-swizzled: physical 16B chunk p holds logical p^(row&7)
// ---------------------------------------------------------------------------
__global__ __launch_bounds__(256) void gemm_bt(const u16* __restrict__ A,
                                               const u16* __restrict__ Bt,
                                               const float* __restrict__ bias,
                                               float* __restrict__ Cf,
                                               u16* __restrict__ Cb,
                                               int M, int N, int K, int out_bf16,
                                               float scale) {
  __shared__ __align__(16) u16 Al[128 * 64];
  __shared__ __align__(16) u16 Bl[128 * 64];
  const int tid = threadIdx.x;
  const int w = tid >> 6, lane = tid & 63;
  const int g = lane >> 4, l15 = lane & 15;
  const int sw = l15 & 7;  // fragment-row swizzle key (row&7 == l15&7)
  const int mbase = blockIdx.x * 128, nbase = blockIdx.y * 128;
  const int wm = (w & 1) * 64, wn = (w >> 1) * 64;

  f32x4 zero4 = {0.f, 0.f, 0.f, 0.f};
  f32x4 acc[4][4];
#pragma unroll
  for (int i = 0; i < 4; ++i)
#pragma unroll
    for (int j = 0; j < 4; ++j) acc[i][j] = zero4;

  for (int kb = 0; kb < K; kb += 64) {
#pragma unroll
    for (int i = 0; i < 4; ++i) {
      int cbase = w * 256 + i * 64;          // wave-uniform region base (chunks)
      int c = cbase + lane;
      int row = c >> 3;
      int kc8 = ((c & 7) ^ (row & 7)) * 8;   // swizzled source chunk
      async16(&Al[cbase * 8], A + (size_t)(mbase + row) * K + kb + kc8);
      async16(&Bl[cbase * 8], Bt + (size_t)(nbase + row) * K + kb + kc8);
    }
    __syncthreads();
#pragma unroll
    for (int ks = 0; ks < 2; ++ks) {
      short8 af[4], bf[4];
#pragma unroll
      for (int mt = 0; mt < 4; ++mt)
        af[mt] = *(const short8*)&Al[(wm + mt * 16 + l15) * 64 + ((ks * 4 + g) ^ sw) * 8];
#pragma unroll
      for (int nt = 0; nt < 4; ++nt)
        bf[nt] = *(const short8*)&Bl[(wn + nt * 16 + l15) * 64 + ((ks * 4 + g) ^ sw) * 8];
#pragma unroll
      for (int mt = 0; mt < 4; ++mt)
#pragma unroll
        for (int nt = 0; nt < 4; ++nt)
          acc[mt][nt] = __builtin_amdgcn_mfma_f32_16x16x32_bf16(af[mt], bf[nt],
                                                                acc[mt][nt], 0, 0, 0);
    }
    __syncthreads();
  }

#pragma unroll
  for (int nt = 0; nt < 4; ++nt) {
    int col = nbase + wn + nt * 16 + l15;
    float bv = bias[col];
#pragma unroll
    for (int mt = 0; mt < 4; ++mt)
#pragma unroll
      for (int r = 0; r < 4; ++r) {
        int row = mbase + wm + mt * 16 + g * 4 + r;
        float v = (acc[mt][nt][r] + bv) * scale;
        if (out_bf16) Cb[(size_t)row * N + col] = f2bf(v);
        else          Cf[(size_t)row * N + col] = v;
      }
  }
}

// ---------------------------------------------------------------------------
// Combined K/V projection: blockIdx.z==0 -> Kp[M,N] = kA*Wk^T + bk (row store)
//                          blockIdx.z==1 -> VT[N,M] = (vA*Wv^T + bv)^T
// ---------------------------------------------------------------------------
__global__ __launch_bounds__(256) void gemm_kv(const u16* __restrict__ kA,
                                               const u16* __restrict__ vA,
                                               const u16* __restrict__ Wk,
                                               const u16* __restrict__ Wv,
                                               const float* __restrict__ bk,
                                               const float* __restrict__ bv,
                                               u16* __restrict__ Kp,
                                               u16* __restrict__ VT,
                                               int M, int N, int K) {
  __shared__ __align__(16) u16 Al[128 * 64];
  __shared__ __align__(16) u16 Bl[128 * 64];
  const int ct = blockIdx.z;  // uniform
  const u16* A  = ct ? vA : kA;
  const u16* Bt = ct ? Wv : Wk;
  const float* bias = ct ? bv : bk;
  const int tid = threadIdx.x;
  const int w = tid >> 6, lane = tid & 63;
  const int g = lane >> 4, l15 = lane & 15;
  const int sw = l15 & 7;
  const int mbase = blockIdx.x * 128, nbase = blockIdx.y * 128;
  const int wm = (w & 1) * 64, wn = (w >> 1) * 64;

  f32x4 zero4 = {0.f, 0.f, 0.f, 0.f};
  f32x4 acc[4][4];  // z=0: [mt][nt]; z=1: [nt][mt] (transposed D)
#pragma unroll
  for (int i = 0; i < 4; ++i)
#pragma unroll
    for (int j = 0; j < 4; ++j) acc[i][j] = zero4;

  for (int kb = 0; kb < K; kb += 64) {
#pragma unroll
    for (int i = 0; i < 4; ++i) {
      int cbase = w * 256 + i * 64;
      int c = cbase + lane;
      int row = c >> 3;
      int kc8 = ((c & 7) ^ (row & 7)) * 8;
      async16(&Al[cbase * 8], A + (size_t)(mbase + row) * K + kb + kc8);
      async16(&Bl[cbase * 8], Bt + (size_t)(nbase + row) * K + kb + kc8);
    }
    __syncthreads();
#pragma unroll
    for (int ks = 0; ks < 2; ++ks) {
      short8 af[4], bf[4];
#pragma unroll
      for (int mt = 0; mt < 4; ++mt)
        af[mt] = *(const short8*)&Al[(wm + mt * 16 + l15) * 64 + ((ks * 4 + g) ^ sw) * 8];
#pragma unroll
      for (int nt = 0; nt < 4; ++nt)
        bf[nt] = *(const short8*)&Bl[(wn + nt * 16 + l15) * 64 + ((ks * 4 + g) ^ sw) * 8];
      if (ct) {
#pragma unroll
        for (int nt = 0; nt < 4; ++nt)
#pragma unroll
          for (int mt = 0; mt < 4; ++mt)
            acc[nt][mt] = __builtin_amdgcn_mfma_f32_16x16x32_bf16(bf[nt], af[mt],
                                                                  acc[nt][mt], 0, 0, 0);
      } else {
#pragma unroll
        for (int mt = 0; mt < 4; ++mt)
#pragma unroll
          for (int nt = 0; nt < 4; ++nt)
            acc[mt][nt] = __builtin_amdgcn_mfma_f32_16x16x32_bf16(af[mt], bf[nt],
                                                                  acc[mt][nt], 0, 0, 0);
      }
    }
    __syncthreads();
  }

  if (ct) {
    // D = C^T: lane holds VT[n=nbase+wn+nt*16+g*4+r][m=mbase+wm+mt*16+l15]
#pragma unroll
    for (int mt = 0; mt < 4; ++mt) {
      int m = mbase + wm + mt * 16 + l15;
#pragma unroll
      for (int nt = 0; nt < 4; ++nt)
#pragma unroll
        for (int r = 0; r < 4; ++r) {
          int n = nbase + wn + nt * 16 + g * 4 + r;
          VT[(size_t)n * M + m] = f2bf(acc[nt][mt][r] + bias[n]);
        }
    }
  } else {
#pragma unroll
    for (int nt = 0; nt < 4; ++nt) {
      int col = nbase + wn + nt * 16 + l15;
      float bvv = bias[col];
#pragma unroll
      for (int mt = 0; mt < 4; ++mt)
#pragma unroll
        for (int r = 0; r < 4; ++r) {
          int row = mbase + wm + mt * 16 + g * 4 + r;
          Kp[(size_t)row * N + col] = f2bf(acc[mt][nt][r] + bvv);
        }
    }
  }
}

// ---------------------------------------------------------------------------
// Fused flash attention, S^T/O^T orientation, no-max softmax, MFMA row-sum.
// Grid: (Nq/128, B*H). 256 thr = 4 waves; wave owns 32 q-rows (2 subtiles).
// Qp: (B*Nq,1024) bf16 pre-scaled by QSCALE. Kp: (B*Nk,1024) bf16.
// VT: (1024, B*Nk) bf16 (projected V, transposed). AO: (B*Nq,1024) bf16.
// ---------------------------------------------------------------------------
__global__ __launch_bounds__(256) void attn_kernel(const u16* __restrict__ Qp,
                                                   const u16* __restrict__ Kp,
                                                   const u16* __restrict__ VT,
                                                   u16* __restrict__ AO) {
  __shared__ __align__(16) u16 K_lds[64 * 64];        // [kcol][d]   swizzled
  __shared__ __align__(16) u16 Vt_lds[64 * 64];       // [d][kcol]   swizzled
  __shared__ __align__(16) u16 P_lds[4][32 * 64];     // per-wave [qrow][kcol] swizzled

  const int tid = threadIdx.x;
  const int w = tid >> 6, lane = tid & 63;
  const int g = lane >> 4, l15 = lane & 15;
  const int sw = l15 & 7;
  const int bh = blockIdx.y, b = bh >> 4, h = bh & 15;
  const int qrow0 = blockIdx.x * 128 + w * 32;
  const int MT = B_SZ * NK;  // VT leading dim

  // ones A-fragment (bf16 1.0 in every slot) for the MFMA row-sum
  short8 ones8;
#pragma unroll
  for (int j = 0; j < 8; ++j) ones8[j] = (short)0x3F80;

  // Q fragments (B-operand role): lane holds Q[qrow=qt*16+l15][d=ks*32+g*8+j]
  short8 qf[2][2];
#pragma unroll
  for (int qt = 0; qt < 2; ++qt)
#pragma unroll
    for (int ks = 0; ks < 2; ++ks) {
      size_t row = (size_t)(b * NQ + qrow0 + qt * 16 + l15);
      qf[qt][ks] = *(const short8*)(Qp + row * QDIM + h * HD + ks * 32 + g * 8);
    }

  f32x4 zero4 = {0.f, 0.f, 0.f, 0.f};
  f32x4 o4[4][2];              // O^T frags: [dt][qt], r-index = d
  f32x4 lacc[2];               // row-sum via mfma(ones, P): col=qrow, rows dup
#pragma unroll
  for (int dt = 0; dt < 4; ++dt)
#pragma unroll
    for (int qt = 0; qt < 2; ++qt) o4[dt][qt] = zero4;
  lacc[0] = zero4; lacc[1] = zero4;

  for (int kc = 0; kc < NK / 64; ++kc) {
    const u16* Ksrc  = Kp + (size_t)(b * NK + kc * 64) * QDIM + h * HD;
    const u16* Vtsrc = VT + (size_t)(h * HD) * MT + b * NK + kc * 64;
#pragma unroll
    for (int i = 0; i < 2; ++i) {
      int cbase = (w * 2 + i) * 64;
      int c = cbase + lane;
      int row = c >> 3;
      int kc8 = ((c & 7) ^ (row & 7)) * 8;
      async16(&K_lds[cbase * 8],  Ksrc  + (size_t)row * QDIM + kc8);
      async16(&Vt_lds[cbase * 8], Vtsrc + (size_t)row * MT   + kc8);
    }
    __syncthreads();

    // S^T = K * Q^T : lane holds S[qrow=qt*16+l15][kcol=mt*16+g*4+r]
    f32x4 sc[4][2];
#pragma unroll
    for (int mt = 0; mt < 4; ++mt)
#pragma unroll
      for (int qt = 0; qt < 2; ++qt) sc[mt][qt] = zero4;
#pragma unroll
    for (int ks = 0; ks < 2; ++ks) {
      short8 kf[4];
#pragma unroll
      for (int mt = 0; mt < 4; ++mt)
        kf[mt] = *(const short8*)&K_lds[(mt * 16 + l15) * 64 + ((ks * 4 + g) ^ sw) * 8];
#pragma unroll
      for (int mt = 0; mt < 4; ++mt)
#pragma unroll
        for (int qt = 0; qt < 2; ++qt)
          sc[mt][qt] = __builtin_amdgcn_mfma_f32_16x16x32_bf16(kf[mt], qf[qt][ks],
                                                               sc[mt][qt], 0, 0, 0);
    }

    // P = exp2(s) -> bf16 -> wave-private P_lds (row-sum comes later via MFMA)
#pragma unroll
    for (int qt = 0; qt < 2; ++qt) {
#pragma unroll
      for (int mt = 0; mt < 4; ++mt) {
        float p0 = fexp2(sc[mt][qt][0]);
        float p1 = fexp2(sc[mt][qt][1]);
        float p2 = fexp2(sc[mt][qt][2]);
        float p3 = fexp2(sc[mt][qt][3]);
        uint2 pk = {pk2(p0, p1), pk2(p2, p3)};
        *(uint2*)&P_lds[w][(qt * 16 + l15) * 64 +
                           (((mt * 2) + (g >> 1)) ^ sw) * 8 + (g & 1) * 4] = pk;
      }
    }
    // P_lds[w] is wave-private: no barrier between write and read.

    // O^T += mfma(Vt-frag, P-frag); l += mfma(ones, P-frag)
#pragma unroll
    for (int ks = 0; ks < 2; ++ks) {
      short8 vf[4], pb[2];
#pragma unroll
      for (int dt = 0; dt < 4; ++dt)
        vf[dt] = *(const short8*)&Vt_lds[(dt * 16 + l15) * 64 + ((ks * 4 + g) ^ sw) * 8];
#pragma unroll
      for (int qt = 0; qt < 2; ++qt)
        pb[qt] = *(const short8*)&P_lds[w][(qt * 16 + l15) * 64 + ((ks * 4 + g) ^ sw) * 8];
#pragma unroll
      for (int qt = 0; qt < 2; ++qt)
        lacc[qt] = __builtin_amdgcn_mfma_f32_16x16x32_bf16(ones8, pb[qt],
                                                           lacc[qt], 0, 0, 0);
#pragma unroll
      for (int dt = 0; dt < 4; ++dt)
#pragma unroll
        for (int qt = 0; qt < 2; ++qt)
          o4[dt][qt] = __builtin_amdgcn_mfma_f32_16x16x32_bf16(vf[dt], pb[qt],
                                                               o4[dt][qt], 0, 0, 0);
    }
    __syncthreads();  // protect K_lds/Vt_lds before next staging
  }

  // epilogue: lacc[qt][r] all hold the full row-sum for qrow=qt*16+l15
#pragma unroll
  for (int qt = 0; qt < 2; ++qt) {
    float inv = 1.0f / lacc[qt][0];
    size_t row = (size_t)(b * NQ + qrow0 + qt * 16 + l15);
#pragma unroll
    for (int dt = 0; dt < 4; ++dt) {
      uint2 pk = {pk2(o4[dt][qt][0] * inv, o4[dt][qt][1] * inv),
                  pk2(o4[dt][qt][2] * inv, o4[dt][qt][3] * inv)};
      *(uint2*)(AO + row * QDIM + h * HD + dt * 16 + g * 4) = pk;
    }
  }
}

// ---------------------------------------------------------------------------
extern "C" void kernel_launch(void* const* d_in, const int* in_sizes, int n_in,
                              void* d_out, int out_size, void* d_ws, size_t ws_size,
                              hipStream_t stream) {
  const float* query = (const float*)d_in[0];
  const float* key   = (const float*)d_in[1];
  const float* value = (const float*)d_in[2];
  const float* Wq = (const float*)d_in[3];
  const float* bq = (const float*)d_in[4];
  const float* Wk = (const float*)d_in[5];
  const float* bk = (const float*)d_in[6];
  const float* Wv = (const float*)d_in[7];
  const float* bv = (const float*)d_in[8];
  const float* Wo = (const float*)d_in[9];
  const float* bo = (const float*)d_in[10];

  char* ws = (char*)d_ws;
  size_t off = 0;
  auto alloc = [&](size_t bytes) -> void* {
    void* p = ws + off;
    off += (bytes + 255) & ~(size_t)255;
    return p;
  };
  const size_t NQTOT = (size_t)B_SZ * NQ;        // 16384
  const size_t NKTOT = (size_t)B_SZ * NK;        // 4096
  u16* qbf = (u16*)alloc(NQTOT * QDIM * 2);      // query bf16; reused as AO later
  u16* kbf = (u16*)alloc(NKTOT * KDIM * 2);
  u16* vbf = (u16*)alloc(NKTOT * KDIM * 2);
  u16* wqt = (u16*)alloc((size_t)QDIM * QDIM * 2);
  u16* wkt = (u16*)alloc((size_t)KDIM * QDIM * 2);
  u16* wvt = (u16*)alloc((size_t)KDIM * QDIM * 2);
  u16* wot = (u16*)alloc((size_t)QDIM * QDIM * 2);
  u16* Qp  = (u16*)alloc(NQTOT * QDIM * 2);
  u16* Kp  = (u16*)alloc(NKTOT * QDIM * 2);
  u16* VT  = (u16*)alloc((size_t)QDIM * NKTOT * 2);  // (1024, B*NK) transposed V-proj
  u16* AO  = qbf;  // qbf dead after Q-projection

  // 1) dtype conversions (query alone; key+value merged into one launch)
  {
    int n4 = (int)(NQTOT * QDIM / 4);
    f32_to_bf16_k<<<(n4 + 255) / 256, 256, 0, stream>>>(query, qbf, n4);
  }
  {
    int n4 = (int)(NKTOT * KDIM / 4);
    f32_to_bf16_2k<<<dim3((n4 + 255) / 256, 2), 256, 0, stream>>>(key, value, kbf,
                                                                  vbf, n4);
  }
  // 2) weight transposes (K x N -> N x K bf16)
  transpose_bf16_k<<<dim3(QDIM / 32, QDIM / 32), 256, 0, stream>>>(Wq, wqt, QDIM, QDIM);
  transpose_bf16_k<<<dim3(QDIM / 32, KDIM / 32), 256, 0, stream>>>(Wk, wkt, KDIM, QDIM);
  transpose_bf16_k<<<dim3(QDIM / 32, KDIM / 32), 256, 0, stream>>>(Wv, wvt, KDIM, QDIM);
  transpose_bf16_k<<<dim3(QDIM / 32, QDIM / 32), 256, 0, stream>>>(Wo, wot, QDIM, QDIM);

  // 3) projections: Q scaled by QSCALE (softmax exp2-domain fold); K+V fused
  gemm_bt<<<dim3(NQTOT / 128, QDIM / 128), 256, 0, stream>>>(
      qbf, wqt, bq, nullptr, Qp, (int)NQTOT, QDIM, QDIM, 1, QSCALE);
  gemm_kv<<<dim3(NKTOT / 128, QDIM / 128, 2), 256, 0, stream>>>(
      kbf, vbf, wkt, wvt, bk, bv, Kp, VT, (int)NKTOT, QDIM, KDIM);

  // 4) fused attention -> AO (bf16, (B*Nq, 1024))
  attn_kernel<<<dim3(NQ / 128, B_SZ * NH), 256, 0, stream>>>(Qp, Kp, VT, AO);

  // 5) output projection (fp32 out)
  gemm_bt<<<dim3(NQTOT / 128, QDIM / 128), 256, 0, stream>>>(
      AO, wot, bo, (float*)d_out, nullptr, (int)NQTOT, QDIM, QDIM, 0, 1.0f);

  (void)in_sizes; (void)n_in; (void)out_size; (void)ws_size;
}

// Round 2
// 428.054 us; speedup vs baseline: 1.0064x; 1.0064x over previous
//
#include <hip/hip_runtime.h>
#include <hip/hip_bf16.h>
#include <stdint.h>

// ---------------------------------------------------------------------------
// CrossAttention: out = softmax((X Wq)(K Wk)^T * s) (V Wv) Wo  (+biases)
// B=4, Nq=4096, Nk=1024, QUERY_DIM=1024, KEY_DIM=768, H=16, HD=64
// R6: attn VALU-pressure attack (counters: MfmaUtil 23 + VALUBusy 69 = 92%
//     issue-bound, exp2f expands to guarded multi-op sequence):
//     (a) raw v_exp_f32 via __builtin_amdgcn_exp2f (softmax tolerates
//         denormal flush),
//     (b) sc zero-init removed (ks=0 MFMA takes zero4 as C-operand),
//     (c) LDS read/write offsets decomposed into lane-constant bases +
//         compile-time immediates; incremental global src pointers,
//     (d) K/V double-buffered, 2-phase schedule: stage kc+1 before compute
//         of kc, ONE barrier per kc (was 2),
//     (e) s_setprio(1) around MFMA clusters, rcp for row-sum reciprocal.
// Carried: XOR-swizzled LDS, no-max exp2 softmax, packed bf16 cvt, MFMA
//     row-sum on the matrix pipe, fused K/V projection.
// ---------------------------------------------------------------------------

typedef unsigned short u16;
typedef __attribute__((ext_vector_type(8))) short short8;   // 8 bf16 = 4 VGPRs
typedef __attribute__((ext_vector_type(4))) float f32x4;    // MFMA C/D frag

#define B_SZ 4
#define NQ   4096
#define NK   1024
#define QDIM 1024
#define KDIM 768
#define NH   16
#define HD   64
// scale * log2(e): softmax computed in exp2 domain (folded into Q projection)
#define QSCALE (0.125f * 1.44269504f)

__device__ __forceinline__ u16 f2bf(float f) {
  union { float f; uint32_t u; } v; v.f = f;
  uint32_t u = v.u;
  return (u16)((u + 0x7FFFu + ((u >> 16) & 1u)) >> 16);  // RNE
}

// packed f32x2 -> bf16x2 (v_cvt_pk_bf16_f32 on gfx950)
__device__ __forceinline__ uint32_t pk2(float a, float b) {
  union { __hip_bfloat162 h; uint32_t u; } cv;
  cv.h = __float22bfloat162_rn(float2{a, b});
  return cv.u;
}

// raw v_exp_f32 (no denormal-guard expansion; underflow flushes to 0 - fine
// for softmax numerator)
__device__ __forceinline__ float fexp2(float x) {
  return __builtin_amdgcn_exp2f(x);
}

// global -> LDS async copy, 16B per lane; lds base must be wave-uniform.
__device__ __forceinline__ void async16(u16* lds, const u16* g) {
  __builtin_amdgcn_global_load_lds(
      (__attribute__((address_space(1))) void*)(g),
      (__attribute__((address_space(3))) void*)(lds), 16, 0, 0);
}

// ---------------------------------------------------------------------------
// fp32 -> bf16 elementwise (vectorized x4, packed cvt)
// ---------------------------------------------------------------------------
__global__ __launch_bounds__(256) void f32_to_bf16_k(const float* __restrict__ in,
                                                     u16* __restrict__ out, int n4) {
  int i = blockIdx.x * 256 + threadIdx.x;
  if (i < n4) {
    f32x4 v = ((const f32x4*)in)[i];
    uint2 o = {pk2(v.x, v.y), pk2(v.z, v.w)};
    ((uint2*)out)[i] = o;
  }
}

// two-tensor variant: blockIdx.y selects (a->oa) or (b->ob); one launch for K+V
__global__ __launch_bounds__(256) void f32_to_bf16_2k(const float* __restrict__ a,
                                                      const float* __restrict__ b,
                                                      u16* __restrict__ oa,
                                                      u16* __restrict__ ob, int n4) {
  int i = blockIdx.x * 256 + threadIdx.x;
  const float* in = blockIdx.y ? b : a;
  u16* out = blockIdx.y ? ob : oa;
  if (i < n4) {
    f32x4 v = ((const f32x4*)in)[i];
    uint2 o = {pk2(v.x, v.y), pk2(v.z, v.w)};
    ((uint2*)out)[i] = o;
  }
}

// ---------------------------------------------------------------------------
// W (K x N fp32, row-major) -> Wt (N x K bf16, row-major)   [LDS-tiled]
// ---------------------------------------------------------------------------
__global__ __launch_bounds__(256) void transpose_bf16_k(const float* __restrict__ W,
                                                        u16* __restrict__ Wt,
                                                        int K, int N) {
  __shared__ float t[32][33];
  int tx = threadIdx.x & 31, ty = threadIdx.x >> 5;  // 32 x 8
  int nb = blockIdx.x * 32, kb = blockIdx.y * 32;
#pragma unroll
  for (int i = 0; i < 4; ++i)
    t[ty + i * 8][tx] = W[(size_t)(kb + ty + i * 8) * N + nb + tx];
  __syncthreads();
#pragma unroll
  for (int i = 0; i < 4; ++i)
    Wt[(size_t)(nb + ty + i * 8) * K + kb + tx] = f2bf(t[tx][ty + i * 8]);
}

// ---------------------------------------------------------------------------
// C[M,N] = (A[M,K] * Bt[N,K]^T + bias) * scale ; out bf16 or fp32
// 128x128 tile, BK=64, 256 threads (4 waves, each 64x64 = 4x4 16x16 frags)
// LDS rows (128B) chunk-swizzled: physical 16B chunk p holds logical p^(row&7)
// ---------------------------------------------------------------------------
__global__ __launch_bounds__(256) void gemm_bt(const u16* __restrict__ A,
                                               const u16* __restrict__ Bt,
                                               const float* __restrict__ bias,
                                               float* __restrict__ Cf,
                                               u16* __restrict__ Cb,
                                               int M, int N, int K, int out_bf16,
                                               float scale) {
  __shared__ __align__(16) u16 Al[128 * 64];
  __shared__ __align__(16) u16 Bl[128 * 64];
  const int tid = threadIdx.x;
  const int w = tid >> 6, lane = tid & 63;
  const int g = lane >> 4, l15 = lane & 15;
  const int sw = l15 & 7;  // fragment-row swizzle key (row&7 == l15&7)
  const int mbase = blockIdx.x * 128, nbase = blockIdx.y * 128;
  const int wm = (w & 1) * 64, wn = (w >> 1) * 64;

  f32x4 zero4 = {0.f, 0.f, 0.f, 0.f};
  f32x4 acc[4][4];
#pragma unroll
  for (int i = 0; i < 4; ++i)
#pragma unroll
    for (int j = 0; j < 4; ++j) acc[i][j] = zero4;

  for (int kb = 0; kb < K; kb += 64) {
#pragma unroll
    for (int i = 0; i < 4; ++i) {
      int cbase = w * 256 + i * 64;          // wave-uniform region base (chunks)
      int c = cbase + lane;
      int row = c >> 3;
      int kc8 = ((c & 7) ^ (row & 7)) * 8;   // swizzled source chunk
      async16(&Al[cbase * 8], A + (size_t)(mbase + row) * K + kb + kc8);
      async16(&Bl[cbase * 8], Bt + (size_t)(nbase + row) * K + kb + kc8);
    }
    __syncthreads();
#pragma unroll
    for (int ks = 0; ks < 2; ++ks) {
      short8 af[4], bf[4];
#pragma unroll
      for (int mt = 0; mt < 4; ++mt)
        af[mt] = *(const short8*)&Al[(wm + mt * 16 + l15) * 64 + ((ks * 4 + g) ^ sw) * 8];
#pragma unroll
      for (int nt = 0; nt < 4; ++nt)
        bf[nt] = *(const short8*)&Bl[(wn + nt * 16 + l15) * 64 + ((ks * 4 + g) ^ sw) * 8];
#pragma unroll
      for (int mt = 0; mt < 4; ++mt)
#pragma unroll
        for (int nt = 0; nt < 4; ++nt)
          acc[mt][nt] = __builtin_amdgcn_mfma_f32_16x16x32_bf16(af[mt], bf[nt],
                                                                acc[mt][nt], 0, 0, 0);
    }
    __syncthreads();
  }

#pragma unroll
  for (int nt = 0; nt < 4; ++nt) {
    int col = nbase + wn + nt * 16 + l15;
    float bv = bias[col];
#pragma unroll
    for (int mt = 0; mt < 4; ++mt)
#pragma unroll
      for (int r = 0; r < 4; ++r) {
        int row = mbase + wm + mt * 16 + g * 4 + r;
        float v = (acc[mt][nt][r] + bv) * scale;
        if (out_bf16) Cb[(size_t)row * N + col] = f2bf(v);
        else          Cf[(size_t)row * N + col] = v;
      }
  }
}

// ---------------------------------------------------------------------------
// Combined K/V projection: blockIdx.z==0 -> Kp[M,N] = kA*Wk^T + bk (row store)
//                          blockIdx.z==1 -> VT[N,M] = (vA*Wv^T + bv)^T
// ---------------------------------------------------------------------------
__global__ __launch_bounds__(256) void gemm_kv(const u16* __restrict__ kA,
                                               const u16* __restrict__ vA,
                                               const u16* __restrict__ Wk,
                                               const u16* __restrict__ Wv,
                                               const float* __restrict__ bk,
                                               const float* __restrict__ bv,
                                               u16* __restrict__ Kp,
                                               u16* __restrict__ VT,
                                               int M, int N, int K) {
  __shared__ __align__(16) u16 Al[128 * 64];
  __shared__ __align__(16) u16 Bl[128 * 64];
  const int ct = blockIdx.z;  // uniform
  const u16* A  = ct ? vA : kA;
  const u16* Bt = ct ? Wv : Wk;
  const float* bias = ct ? bv : bk;
  const int tid = threadIdx.x;
  const int w = tid >> 6, lane = tid & 63;
  const int g = lane >> 4, l15 = lane & 15;
  const int sw = l15 & 7;
  const int mbase = blockIdx.x * 128, nbase = blockIdx.y * 128;
  const int wm = (w & 1) * 64, wn = (w >> 1) * 64;

  f32x4 zero4 = {0.f, 0.f, 0.f, 0.f};
  f32x4 acc[4][4];  // z=0: [mt][nt]; z=1: [nt][mt] (transposed D)
#pragma unroll
  for (int i = 0; i < 4; ++i)
#pragma unroll
    for (int j = 0; j < 4; ++j) acc[i][j] = zero4;

  for (int kb = 0; kb < K; kb += 64) {
#pragma unroll
    for (int i = 0; i < 4; ++i) {
      int cbase = w * 256 + i * 64;
      int c = cbase + lane;
      int row = c >> 3;
      int kc8 = ((c & 7) ^ (row & 7)) * 8;
      async16(&Al[cbase * 8], A + (size_t)(mbase + row) * K + kb + kc8);
      async16(&Bl[cbase * 8], Bt + (size_t)(nbase + row) * K + kb + kc8);
    }
    __syncthreads();
#pragma unroll
    for (int ks = 0; ks < 2; ++ks) {
      short8 af[4], bf[4];
#pragma unroll
      for (int mt = 0; mt < 4; ++mt)
        af[mt] = *(const short8*)&Al[(wm + mt * 16 + l15) * 64 + ((ks * 4 + g) ^ sw) * 8];
#pragma unroll
      for (int nt = 0; nt < 4; ++nt)
        bf[nt] = *(const short8*)&Bl[(wn + nt * 16 + l15) * 64 + ((ks * 4 + g) ^ sw) * 8];
      if (ct) {
#pragma unroll
        for (int nt = 0; nt < 4; ++nt)
#pragma unroll
          for (int mt = 0; mt < 4; ++mt)
            acc[nt][mt] = __builtin_amdgcn_mfma_f32_16x16x32_bf16(bf[nt], af[mt],
                                                                  acc[nt][mt], 0, 0, 0);
      } else {
#pragma unroll
        for (int mt = 0; mt < 4; ++mt)
#pragma unroll
          for (int nt = 0; nt < 4; ++nt)
            acc[mt][nt] = __builtin_amdgcn_mfma_f32_16x16x32_bf16(af[mt], bf[nt],
                                                                  acc[mt][nt], 0, 0, 0);
      }
    }
    __syncthreads();
  }

  if (ct) {
    // D = C^T: lane holds VT[n=nbase+wn+nt*16+g*4+r][m=mbase+wm+mt*16+l15]
#pragma unroll
    for (int mt = 0; mt < 4; ++mt) {
      int m = mbase + wm + mt * 16 + l15;
#pragma unroll
      for (int nt = 0; nt < 4; ++nt)
#pragma unroll
        for (int r = 0; r < 4; ++r) {
          int n = nbase + wn + nt * 16 + g * 4 + r;
          VT[(size_t)n * M + m] = f2bf(acc[nt][mt][r] + bias[n]);
        }
    }
  } else {
#pragma unroll
    for (int nt = 0; nt < 4; ++nt) {
      int col = nbase + wn + nt * 16 + l15;
      float bvv = bias[col];
#pragma unroll
      for (int mt = 0; mt < 4; ++mt)
#pragma unroll
        for (int r = 0; r < 4; ++r) {
          int row = mbase + wm + mt * 16 + g * 4 + r;
          Kp[(size_t)row * N + col] = f2bf(acc[mt][nt][r] + bvv);
        }
    }
  }
}

// ---------------------------------------------------------------------------
// Fused flash attention, S^T/O^T orientation, no-max softmax, MFMA row-sum.
// Grid: (Nq/128, B*H). 256 thr = 4 waves; wave owns 32 q-rows (2 subtiles).
// Qp: (B*Nq,1024) bf16 pre-scaled by QSCALE. Kp: (B*Nk,1024) bf16.
// VT: (1024, B*Nk) bf16 (projected V, transposed). AO: (B*Nq,1024) bf16.
// R6: double-buffered K/V (2-phase schedule, 1 barrier/kc), raw v_exp_f32,
//     no sc zero-init, hoisted LDS offsets, setprio around MFMA clusters.
// ---------------------------------------------------------------------------
__global__ __launch_bounds__(256) void attn_kernel(const u16* __restrict__ Qp,
                                                   const u16* __restrict__ Kp,
                                                   const u16* __restrict__ VT,
                                                   u16* __restrict__ AO) {
  __shared__ __align__(16) u16 K_lds[2][64 * 64];     // [buf][kcol][d] swizzled
  __shared__ __align__(16) u16 Vt_lds[2][64 * 64];    // [buf][d][kcol] swizzled
  __shared__ __align__(16) u16 P_lds[4][32 * 64];     // per-wave [qrow][kcol] swz

  const int tid = threadIdx.x;
  const int w = tid >> 6, lane = tid & 63;
  const int g = lane >> 4, l15 = lane & 15;
  const int sw = l15 & 7;
  const int bh = blockIdx.y, b = bh >> 4, h = bh & 15;
  const int qrow0 = blockIdx.x * 128 + w * 32;
  const int MT = B_SZ * NK;  // VT leading dim

  // ---- staging lane constants (two 64-chunk regions per wave) ----
  const int cbase0 = (w * 2 + 0) * 64;
  const int cbase1 = (w * 2 + 1) * 64;
  const int c0 = cbase0 + lane, c1 = cbase1 + lane;
  const int row0 = c0 >> 3, kc80 = ((c0 & 7) ^ (row0 & 7)) * 8;
  const int row1 = c1 >> 3, kc81 = ((c1 & 7) ^ (row1 & 7)) * 8;

  // incremental per-lane global source pointers
  const u16* kp0 = Kp + (size_t)(b * NK + row0) * QDIM + h * HD + kc80;
  const u16* kp1 = Kp + (size_t)(b * NK + row1) * QDIM + h * HD + kc81;
  const u16* vp0 = VT + (size_t)(h * HD + row0) * MT + b * NK + kc80;
  const u16* vp1 = VT + (size_t)(h * HD + row1) * MT + b * NK + kc81;

  // ---- compute lane constants ----
  const int rb = l15 * 64;                      // fragment row base (elements)
  const int cs0 = (g ^ sw) * 8;                 // ks=0 chunk select
  const int cs1 = ((4 + g) ^ sw) * 8;           // ks=1 chunk select
  // P-store: addr = qt*1024 + pwb + ((mt*2)^pms)*8
  const int pwb = rb + (((g >> 1) ^ (sw & 1)) * 8) + (g & 1) * 4;
  const int pms = sw & 6;

  // ones A-fragment (bf16 1.0 in every slot) for the MFMA row-sum
  short8 ones8;
#pragma unroll
  for (int j = 0; j < 8; ++j) ones8[j] = (short)0x3F80;

  // Q fragments (B-operand role): lane holds Q[qrow=qt*16+l15][d=ks*32+g*8+j]
  short8 qf[2][2];
#pragma unroll
  for (int qt = 0; qt < 2; ++qt)
#pragma unroll
    for (int ks = 0; ks < 2; ++ks) {
      size_t row = (size_t)(b * NQ + qrow0 + qt * 16 + l15);
      qf[qt][ks] = *(const short8*)(Qp + row * QDIM + h * HD + ks * 32 + g * 8);
    }

  f32x4 zero4 = {0.f, 0.f, 0.f, 0.f};
  f32x4 o4[4][2];              // O^T frags: [dt][qt], r-index = d
  f32x4 lacc[2];               // row-sum via mfma(ones, P): col=qrow, rows dup
#pragma unroll
  for (int dt = 0; dt < 4; ++dt)
#pragma unroll
    for (int qt = 0; qt < 2; ++qt) o4[dt][qt] = zero4;
  lacc[0] = zero4; lacc[1] = zero4;

  // prologue: stage tile 0 into buf 0
  async16(&K_lds[0][cbase0 * 8], kp0);
  async16(&K_lds[0][cbase1 * 8], kp1);
  async16(&Vt_lds[0][cbase0 * 8], vp0);
  async16(&Vt_lds[0][cbase1 * 8], vp1);
  kp0 += 64 * QDIM; kp1 += 64 * QDIM; vp0 += 64; vp1 += 64;
  __syncthreads();  // drains vmcnt + barrier

  int cur = 0;
  for (int kc = 0; kc < NK / 64; ++kc) {
    // 2-phase: issue next tile's loads before computing current tile
    if (kc + 1 < NK / 64) {
      int nb = cur ^ 1;
      async16(&K_lds[nb][cbase0 * 8], kp0);
      async16(&K_lds[nb][cbase1 * 8], kp1);
      async16(&Vt_lds[nb][cbase0 * 8], vp0);
      async16(&Vt_lds[nb][cbase1 * 8], vp1);
      kp0 += 64 * QDIM; kp1 += 64 * QDIM; vp0 += 64; vp1 += 64;
    }
    const u16* Kl = &K_lds[cur][0];
    const u16* Vl = &Vt_lds[cur][0];
    u16* Pl = &P_lds[w][0];

    // S^T = K * Q^T : lane holds S[qrow=qt*16+l15][kcol=mt*16+g*4+r]
    f32x4 sc[4][2];
    {
      short8 kf[4];
#pragma unroll
      for (int mt = 0; mt < 4; ++mt)
        kf[mt] = *(const short8*)&Kl[mt * 1024 + rb + cs0];
      __builtin_amdgcn_s_setprio(1);
#pragma unroll
      for (int mt = 0; mt < 4; ++mt)
#pragma unroll
        for (int qt = 0; qt < 2; ++qt)
          sc[mt][qt] = __builtin_amdgcn_mfma_f32_16x16x32_bf16(kf[mt], qf[qt][0],
                                                               zero4, 0, 0, 0);
      __builtin_amdgcn_s_setprio(0);
#pragma unroll
      for (int mt = 0; mt < 4; ++mt)
        kf[mt] = *(const short8*)&Kl[mt * 1024 + rb + cs1];
      __builtin_amdgcn_s_setprio(1);
#pragma unroll
      for (int mt = 0; mt < 4; ++mt)
#pragma unroll
        for (int qt = 0; qt < 2; ++qt)
          sc[mt][qt] = __builtin_amdgcn_mfma_f32_16x16x32_bf16(kf[mt], qf[qt][1],
                                                               sc[mt][qt], 0, 0, 0);
      __builtin_amdgcn_s_setprio(0);
    }

    // P = exp2(s) -> bf16 -> wave-private P_lds (raw v_exp_f32)
#pragma unroll
    for (int qt = 0; qt < 2; ++qt) {
#pragma unroll
      for (int mt = 0; mt < 4; ++mt) {
        float p0 = fexp2(sc[mt][qt][0]);
        float p1 = fexp2(sc[mt][qt][1]);
        float p2 = fexp2(sc[mt][qt][2]);
        float p3 = fexp2(sc[mt][qt][3]);
        uint2 pk = {pk2(p0, p1), pk2(p2, p3)};
        *(uint2*)&Pl[qt * 1024 + pwb + ((mt * 2) ^ pms) * 8] = pk;
      }
    }
    // P_lds[w] is wave-private: no barrier between write and read.

    // O^T += mfma(Vt-frag, P-frag); l += mfma(ones, P-frag)
#pragma unroll
    for (int ks = 0; ks < 2; ++ks) {
      const int cs = ks ? cs1 : cs0;
      short8 vf[4], pb[2];
#pragma unroll
      for (int dt = 0; dt < 4; ++dt)
        vf[dt] = *(const short8*)&Vl[dt * 1024 + rb + cs];
#pragma unroll
      for (int qt = 0; qt < 2; ++qt)
        pb[qt] = *(const short8*)&Pl[qt * 1024 + rb + cs];
      __builtin_amdgcn_s_setprio(1);
#pragma unroll
      for (int qt = 0; qt < 2; ++qt)
        lacc[qt] = __builtin_amdgcn_mfma_f32_16x16x32_bf16(ones8, pb[qt],
                                                           lacc[qt], 0, 0, 0);
#pragma unroll
      for (int dt = 0; dt < 4; ++dt)
#pragma unroll
        for (int qt = 0; qt < 2; ++qt)
          o4[dt][qt] = __builtin_amdgcn_mfma_f32_16x16x32_bf16(vf[dt], pb[qt],
                                                               o4[dt][qt], 0, 0, 0);
      __builtin_amdgcn_s_setprio(0);
    }
    if (kc + 1 < NK / 64) __syncthreads();  // drain next-tile loads + protect bufs
    cur ^= 1;
  }

  // epilogue: lacc[qt][r] all hold the full row-sum for qrow=qt*16+l15
#pragma unroll
  for (int qt = 0; qt < 2; ++qt) {
    float inv = __builtin_amdgcn_rcpf(lacc[qt][0]);
    size_t row = (size_t)(b * NQ + qrow0 + qt * 16 + l15);
#pragma unroll
    for (int dt = 0; dt < 4; ++dt) {
      uint2 pk = {pk2(o4[dt][qt][0] * inv, o4[dt][qt][1] * inv),
                  pk2(o4[dt][qt][2] * inv, o4[dt][qt][3] * inv)};
      *(uint2*)(AO + row * QDIM + h * HD + dt * 16 + g * 4) = pk;
    }
  }
}

// ---------------------------------------------------------------------------
extern "C" void kernel_launch(void* const* d_in, const int* in_sizes, int n_in,
                              void* d_out, int out_size, void* d_ws, size_t ws_size,
                              hipStream_t stream) {
  const float* query = (const float*)d_in[0];
  const float* key   = (const float*)d_in[1];
  const float* value = (const float*)d_in[2];
  const float* Wq = (const float*)d_in[3];
  const float* bq = (const float*)d_in[4];
  const float* Wk = (const float*)d_in[5];
  const float* bk = (const float*)d_in[6];
  const float* Wv = (const float*)d_in[7];
  const float* bv = (const float*)d_in[8];
  const float* Wo = (const float*)d_in[9];
  const float* bo = (const float*)d_in[10];

  char* ws = (char*)d_ws;
  size_t off = 0;
  auto alloc = [&](size_t bytes) -> void* {
    void* p = ws + off;
    off += (bytes + 255) & ~(size_t)255;
    return p;
  };
  const size_t NQTOT = (size_t)B_SZ * NQ;        // 16384
  const size_t NKTOT = (size_t)B_SZ * NK;        // 4096
  u16* qbf = (u16*)alloc(NQTOT * QDIM * 2);      // query bf16; reused as AO later
  u16* kbf = (u16*)alloc(NKTOT * KDIM * 2);
  u16* vbf = (u16*)alloc(NKTOT * KDIM * 2);
  u16* wqt = (u16*)alloc((size_t)QDIM * QDIM * 2);
  u16* wkt = (u16*)alloc((size_t)KDIM * QDIM * 2);
  u16* wvt = (u16*)alloc((size_t)KDIM * QDIM * 2);
  u16* wot = (u16*)alloc((size_t)QDIM * QDIM * 2);
  u16* Qp  = (u16*)alloc(NQTOT * QDIM * 2);
  u16* Kp  = (u16*)alloc(NKTOT * QDIM * 2);
  u16* VT  = (u16*)alloc((size_t)QDIM * NKTOT * 2);  // (1024, B*NK) transposed V-proj
  u16* AO  = qbf;  // qbf dead after Q-projection

  // 1) dtype conversions (query alone; key+value merged into one launch)
  {
    int n4 = (int)(NQTOT * QDIM / 4);
    f32_to_bf16_k<<<(n4 + 255) / 256, 256, 0, stream>>>(query, qbf, n4);
  }
  {
    int n4 = (int)(NKTOT * KDIM / 4);
    f32_to_bf16_2k<<<dim3((n4 + 255) / 256, 2), 256, 0, stream>>>(key, value, kbf,
                                                                  vbf, n4);
  }
  // 2) weight transposes (K x N -> N x K bf16)
  transpose_bf16_k<<<dim3(QDIM / 32, QDIM / 32), 256, 0, stream>>>(Wq, wqt, QDIM, QDIM);
  transpose_bf16_k<<<dim3(QDIM / 32, KDIM / 32), 256, 0, stream>>>(Wk, wkt, KDIM, QDIM);
  transpose_bf16_k<<<dim3(QDIM / 32, KDIM / 32), 256, 0, stream>>>(Wv, wvt, KDIM, QDIM);
  transpose_bf16_k<<<dim3(QDIM / 32, QDIM / 32), 256, 0, stream>>>(Wo, wot, QDIM, QDIM);

  // 3) projections: Q scaled by QSCALE (softmax exp2-domain fold); K+V fused
  gemm_bt<<<dim3(NQTOT / 128, QDIM / 128), 256, 0, stream>>>(
      qbf, wqt, bq, nullptr, Qp, (int)NQTOT, QDIM, QDIM, 1, QSCALE);
  gemm_kv<<<dim3(NKTOT / 128, QDIM / 128, 2), 256, 0, stream>>>(
      kbf, vbf, wkt, wvt, bk, bv, Kp, VT, (int)NKTOT, QDIM, KDIM);

  // 4) fused attention -> AO (bf16, (B*Nq, 1024))
  attn_kernel<<<dim3(NQ / 128, B_SZ * NH), 256, 0, stream>>>(Qp, Kp, VT, AO);

  // 5) output projection (fp32 out)
  gemm_bt<<<dim3(NQTOT / 128, QDIM / 128), 256, 0, stream>>>(
      AO, wot, bo, (float*)d_out, nullptr, (int)NQTOT, QDIM, QDIM, 0, 1.0f);

  (void)in_sizes; (void)n_in; (void)out_size; (void)ws_size;
}

// Round 3
// 423.071 us; speedup vs baseline: 1.0182x; 1.0118x over previous
//
#include <hip/hip_runtime.h>
#include <hip/hip_bf16.h>
#include <stdint.h>

// ---------------------------------------------------------------------------
// CrossAttention: out = softmax((X Wq)(K Wk)^T * s) (V Wv) Wo  (+biases)
// B=4, Nq=4096, Nk=1024, QUERY_DIM=1024, KEY_DIM=768, H=16, HD=64
// R7: attn T15 deferred-PV pipeline. Counters showed latency-bound (no pipe
//     >55%, MfmaUtil 24% == achieved-TF/peak): QK^T -> exp -> PV strictly
//     serial per wave. Now PV(kc-1) runs in the same MFMA cluster as
//     QK^T(kc); exp(kc) trails. V triple-buffered (PV lags one tile), K
//     double, P single (same-wave DS in-order write-after-read). All frag
//     ds_reads hoisted to loop top for a deep lgkmcnt window.
// Carried: raw v_exp_f32, no sc zero-init, hoisted LDS offsets, setprio,
//     XOR-swizzled LDS, no-max exp2 softmax, MFMA row-sum, fused K/V proj.
// ---------------------------------------------------------------------------

typedef unsigned short u16;
typedef __attribute__((ext_vector_type(8))) short short8;   // 8 bf16 = 4 VGPRs
typedef __attribute__((ext_vector_type(4))) float f32x4;    // MFMA C/D frag

#define B_SZ 4
#define NQ   4096
#define NK   1024
#define QDIM 1024
#define KDIM 768
#define NH   16
#define HD   64
// scale * log2(e): softmax computed in exp2 domain (folded into Q projection)
#define QSCALE (0.125f * 1.44269504f)

__device__ __forceinline__ u16 f2bf(float f) {
  union { float f; uint32_t u; } v; v.f = f;
  uint32_t u = v.u;
  return (u16)((u + 0x7FFFu + ((u >> 16) & 1u)) >> 16);  // RNE
}

// packed f32x2 -> bf16x2 (v_cvt_pk_bf16_f32 on gfx950)
__device__ __forceinline__ uint32_t pk2(float a, float b) {
  union { __hip_bfloat162 h; uint32_t u; } cv;
  cv.h = __float22bfloat162_rn(float2{a, b});
  return cv.u;
}

// raw v_exp_f32 (no denormal-guard expansion; underflow flushes to 0 - fine
// for softmax numerator)
__device__ __forceinline__ float fexp2(float x) {
  return __builtin_amdgcn_exp2f(x);
}

// global -> LDS async copy, 16B per lane; lds base must be wave-uniform.
__device__ __forceinline__ void async16(u16* lds, const u16* g) {
  __builtin_amdgcn_global_load_lds(
      (__attribute__((address_space(1))) void*)(g),
      (__attribute__((address_space(3))) void*)(lds), 16, 0, 0);
}

// ---------------------------------------------------------------------------
// fp32 -> bf16 elementwise (vectorized x4, packed cvt)
// ---------------------------------------------------------------------------
__global__ __launch_bounds__(256) void f32_to_bf16_k(const float* __restrict__ in,
                                                     u16* __restrict__ out, int n4) {
  int i = blockIdx.x * 256 + threadIdx.x;
  if (i < n4) {
    f32x4 v = ((const f32x4*)in)[i];
    uint2 o = {pk2(v.x, v.y), pk2(v.z, v.w)};
    ((uint2*)out)[i] = o;
  }
}

// two-tensor variant: blockIdx.y selects (a->oa) or (b->ob); one launch for K+V
__global__ __launch_bounds__(256) void f32_to_bf16_2k(const float* __restrict__ a,
                                                      const float* __restrict__ b,
                                                      u16* __restrict__ oa,
                                                      u16* __restrict__ ob, int n4) {
  int i = blockIdx.x * 256 + threadIdx.x;
  const float* in = blockIdx.y ? b : a;
  u16* out = blockIdx.y ? ob : oa;
  if (i < n4) {
    f32x4 v = ((const f32x4*)in)[i];
    uint2 o = {pk2(v.x, v.y), pk2(v.z, v.w)};
    ((uint2*)out)[i] = o;
  }
}

// ---------------------------------------------------------------------------
// W (K x N fp32, row-major) -> Wt (N x K bf16, row-major)   [LDS-tiled]
// ---------------------------------------------------------------------------
__global__ __launch_bounds__(256) void transpose_bf16_k(const float* __restrict__ W,
                                                        u16* __restrict__ Wt,
                                                        int K, int N) {
  __shared__ float t[32][33];
  int tx = threadIdx.x & 31, ty = threadIdx.x >> 5;  // 32 x 8
  int nb = blockIdx.x * 32, kb = blockIdx.y * 32;
#pragma unroll
  for (int i = 0; i < 4; ++i)
    t[ty + i * 8][tx] = W[(size_t)(kb + ty + i * 8) * N + nb + tx];
  __syncthreads();
#pragma unroll
  for (int i = 0; i < 4; ++i)
    Wt[(size_t)(nb + ty + i * 8) * K + kb + tx] = f2bf(t[tx][ty + i * 8]);
}

// ---------------------------------------------------------------------------
// C[M,N] = (A[M,K] * Bt[N,K]^T + bias) * scale ; out bf16 or fp32
// 128x128 tile, BK=64, 256 threads (4 waves, each 64x64 = 4x4 16x16 frags)
// LDS rows (128B) chunk-swizzled: physical 16B chunk p holds logical p^(row&7)
// ---------------------------------------------------------------------------
__global__ __launch_bounds__(256) void gemm_bt(const u16* __restrict__ A,
                                               const u16* __restrict__ Bt,
                                               const float* __restrict__ bias,
                                               float* __restrict__ Cf,
                                               u16* __restrict__ Cb,
                                               int M, int N, int K, int out_bf16,
                                               float scale) {
  __shared__ __align__(16) u16 Al[128 * 64];
  __shared__ __align__(16) u16 Bl[128 * 64];
  const int tid = threadIdx.x;
  const int w = tid >> 6, lane = tid & 63;
  const int g = lane >> 4, l15 = lane & 15;
  const int sw = l15 & 7;  // fragment-row swizzle key (row&7 == l15&7)
  const int mbase = blockIdx.x * 128, nbase = blockIdx.y * 128;
  const int wm = (w & 1) * 64, wn = (w >> 1) * 64;

  f32x4 zero4 = {0.f, 0.f, 0.f, 0.f};
  f32x4 acc[4][4];
#pragma unroll
  for (int i = 0; i < 4; ++i)
#pragma unroll
    for (int j = 0; j < 4; ++j) acc[i][j] = zero4;

  for (int kb = 0; kb < K; kb += 64) {
#pragma unroll
    for (int i = 0; i < 4; ++i) {
      int cbase = w * 256 + i * 64;          // wave-uniform region base (chunks)
      int c = cbase + lane;
      int row = c >> 3;
      int kc8 = ((c & 7) ^ (row & 7)) * 8;   // swizzled source chunk
      async16(&Al[cbase * 8], A + (size_t)(mbase + row) * K + kb + kc8);
      async16(&Bl[cbase * 8], Bt + (size_t)(nbase + row) * K + kb + kc8);
    }
    __syncthreads();
#pragma unroll
    for (int ks = 0; ks < 2; ++ks) {
      short8 af[4], bf[4];
#pragma unroll
      for (int mt = 0; mt < 4; ++mt)
        af[mt] = *(const short8*)&Al[(wm + mt * 16 + l15) * 64 + ((ks * 4 + g) ^ sw) * 8];
#pragma unroll
      for (int nt = 0; nt < 4; ++nt)
        bf[nt] = *(const short8*)&Bl[(wn + nt * 16 + l15) * 64 + ((ks * 4 + g) ^ sw) * 8];
#pragma unroll
      for (int mt = 0; mt < 4; ++mt)
#pragma unroll
        for (int nt = 0; nt < 4; ++nt)
          acc[mt][nt] = __builtin_amdgcn_mfma_f32_16x16x32_bf16(af[mt], bf[nt],
                                                                acc[mt][nt], 0, 0, 0);
    }
    __syncthreads();
  }

#pragma unroll
  for (int nt = 0; nt < 4; ++nt) {
    int col = nbase + wn + nt * 16 + l15;
    float bv = bias[col];
#pragma unroll
    for (int mt = 0; mt < 4; ++mt)
#pragma unroll
      for (int r = 0; r < 4; ++r) {
        int row = mbase + wm + mt * 16 + g * 4 + r;
        float v = (acc[mt][nt][r] + bv) * scale;
        if (out_bf16) Cb[(size_t)row * N + col] = f2bf(v);
        else          Cf[(size_t)row * N + col] = v;
      }
  }
}

// ---------------------------------------------------------------------------
// Combined K/V projection: blockIdx.z==0 -> Kp[M,N] = kA*Wk^T + bk (row store)
//                          blockIdx.z==1 -> VT[N,M] = (vA*Wv^T + bv)^T
// ---------------------------------------------------------------------------
__global__ __launch_bounds__(256) void gemm_kv(const u16* __restrict__ kA,
                                               const u16* __restrict__ vA,
                                               const u16* __restrict__ Wk,
                                               const u16* __restrict__ Wv,
                                               const float* __restrict__ bk,
                                               const float* __restrict__ bv,
                                               u16* __restrict__ Kp,
                                               u16* __restrict__ VT,
                                               int M, int N, int K) {
  __shared__ __align__(16) u16 Al[128 * 64];
  __shared__ __align__(16) u16 Bl[128 * 64];
  const int ct = blockIdx.z;  // uniform
  const u16* A  = ct ? vA : kA;
  const u16* Bt = ct ? Wv : Wk;
  const float* bias = ct ? bv : bk;
  const int tid = threadIdx.x;
  const int w = tid >> 6, lane = tid & 63;
  const int g = lane >> 4, l15 = lane & 15;
  const int sw = l15 & 7;
  const int mbase = blockIdx.x * 128, nbase = blockIdx.y * 128;
  const int wm = (w & 1) * 64, wn = (w >> 1) * 64;

  f32x4 zero4 = {0.f, 0.f, 0.f, 0.f};
  f32x4 acc[4][4];  // z=0: [mt][nt]; z=1: [nt][mt] (transposed D)
#pragma unroll
  for (int i = 0; i < 4; ++i)
#pragma unroll
    for (int j = 0; j < 4; ++j) acc[i][j] = zero4;

  for (int kb = 0; kb < K; kb += 64) {
#pragma unroll
    for (int i = 0; i < 4; ++i) {
      int cbase = w * 256 + i * 64;
      int c = cbase + lane;
      int row = c >> 3;
      int kc8 = ((c & 7) ^ (row & 7)) * 8;
      async16(&Al[cbase * 8], A + (size_t)(mbase + row) * K + kb + kc8);
      async16(&Bl[cbase * 8], Bt + (size_t)(nbase + row) * K + kb + kc8);
    }
    __syncthreads();
#pragma unroll
    for (int ks = 0; ks < 2; ++ks) {
      short8 af[4], bf[4];
#pragma unroll
      for (int mt = 0; mt < 4; ++mt)
        af[mt] = *(const short8*)&Al[(wm + mt * 16 + l15) * 64 + ((ks * 4 + g) ^ sw) * 8];
#pragma unroll
      for (int nt = 0; nt < 4; ++nt)
        bf[nt] = *(const short8*)&Bl[(wn + nt * 16 + l15) * 64 + ((ks * 4 + g) ^ sw) * 8];
      if (ct) {
#pragma unroll
        for (int nt = 0; nt < 4; ++nt)
#pragma unroll
          for (int mt = 0; mt < 4; ++mt)
            acc[nt][mt] = __builtin_amdgcn_mfma_f32_16x16x32_bf16(bf[nt], af[mt],
                                                                  acc[nt][mt], 0, 0, 0);
      } else {
#pragma unroll
        for (int mt = 0; mt < 4; ++mt)
#pragma unroll
          for (int nt = 0; nt < 4; ++nt)
            acc[mt][nt] = __builtin_amdgcn_mfma_f32_16x16x32_bf16(af[mt], bf[nt],
                                                                  acc[mt][nt], 0, 0, 0);
      }
    }
    __syncthreads();
  }

  if (ct) {
    // D = C^T: lane holds VT[n=nbase+wn+nt*16+g*4+r][m=mbase+wm+mt*16+l15]
#pragma unroll
    for (int mt = 0; mt < 4; ++mt) {
      int m = mbase + wm + mt * 16 + l15;
#pragma unroll
      for (int nt = 0; nt < 4; ++nt)
#pragma unroll
        for (int r = 0; r < 4; ++r) {
          int n = nbase + wn + nt * 16 + g * 4 + r;
          VT[(size_t)n * M + m] = f2bf(acc[nt][mt][r] + bias[n]);
        }
    }
  } else {
#pragma unroll
    for (int nt = 0; nt < 4; ++nt) {
      int col = nbase + wn + nt * 16 + l15;
      float bvv = bias[col];
#pragma unroll
      for (int mt = 0; mt < 4; ++mt)
#pragma unroll
        for (int r = 0; r < 4; ++r) {
          int row = mbase + wm + mt * 16 + g * 4 + r;
          Kp[(size_t)row * N + col] = f2bf(acc[mt][nt][r] + bvv);
        }
    }
  }
}

// ---------------------------------------------------------------------------
// Fused flash attention, S^T/O^T orientation, no-max softmax, MFMA row-sum.
// Grid: (Nq/128, B*H). 256 thr = 4 waves; wave owns 32 q-rows (2 subtiles).
// R7 pipeline: per iteration kc: [stage kc+1] [ds_read pb(kc-1), vf(kc-1),
// kf(kc)] [MFMA: QK^T(kc) ++ PV(kc-1)] [exp(kc) -> P_lds] [barrier].
// V triple-buffered, K double, P single per wave (same-wave DS in-order).
// ---------------------------------------------------------------------------
__global__ __launch_bounds__(256, 2) void attn_kernel(const u16* __restrict__ Qp,
                                                      const u16* __restrict__ Kp,
                                                      const u16* __restrict__ VT,
                                                      u16* __restrict__ AO) {
  __shared__ __align__(16) u16 K_lds[2][64 * 64];     // [buf][kcol][d] swizzled
  __shared__ __align__(16) u16 V_lds[3][64 * 64];     // [buf][d][kcol] swizzled
  __shared__ __align__(16) u16 P_lds[4][32 * 64];     // per-wave [qrow][kcol] swz

  const int tid = threadIdx.x;
  const int w = tid >> 6, lane = tid & 63;
  const int g = lane >> 4, l15 = lane & 15;
  const int sw = l15 & 7;
  const int bh = blockIdx.y, b = bh >> 4, h = bh & 15;
  const int qrow0 = blockIdx.x * 128 + w * 32;
  const int MT = B_SZ * NK;  // VT leading dim

  // ---- staging lane constants (two 64-chunk regions per wave) ----
  const int cbase0 = (w * 2 + 0) * 64;
  const int cbase1 = (w * 2 + 1) * 64;
  const int c0 = cbase0 + lane, c1 = cbase1 + lane;
  const int row0 = c0 >> 3, kc80 = ((c0 & 7) ^ (row0 & 7)) * 8;
  const int row1 = c1 >> 3, kc81 = ((c1 & 7) ^ (row1 & 7)) * 8;

  // incremental per-lane global source pointers
  const u16* kp0 = Kp + (size_t)(b * NK + row0) * QDIM + h * HD + kc80;
  const u16* kp1 = Kp + (size_t)(b * NK + row1) * QDIM + h * HD + kc81;
  const u16* vp0 = VT + (size_t)(h * HD + row0) * MT + b * NK + kc80;
  const u16* vp1 = VT + (size_t)(h * HD + row1) * MT + b * NK + kc81;

  // ---- compute lane constants ----
  const int rb = l15 * 64;                      // fragment row base (elements)
  const int cs0 = (g ^ sw) * 8;                 // ks=0 chunk select
  const int cs1 = ((4 + g) ^ sw) * 8;           // ks=1 chunk select
  // P-store: addr = qt*1024 + pwb + ((mt*2)^pms)*8
  const int pwb = rb + (((g >> 1) ^ (sw & 1)) * 8) + (g & 1) * 4;
  const int pms = sw & 6;

  // ones A-fragment (bf16 1.0 in every slot) for the MFMA row-sum
  short8 ones8;
#pragma unroll
  for (int j = 0; j < 8; ++j) ones8[j] = (short)0x3F80;

  // Q fragments (B-operand role): lane holds Q[qrow=qt*16+l15][d=ks*32+g*8+j]
  short8 qf[2][2];
#pragma unroll
  for (int qt = 0; qt < 2; ++qt)
#pragma unroll
    for (int ks = 0; ks < 2; ++ks) {
      size_t row = (size_t)(b * NQ + qrow0 + qt * 16 + l15);
      qf[qt][ks] = *(const short8*)(Qp + row * QDIM + h * HD + ks * 32 + g * 8);
    }

  f32x4 zero4 = {0.f, 0.f, 0.f, 0.f};
  f32x4 o4[4][2];              // O^T frags: [dt][qt], r-index = d
  f32x4 lacc[2];               // row-sum via mfma(ones, P): col=qrow, rows dup
#pragma unroll
  for (int dt = 0; dt < 4; ++dt)
#pragma unroll
    for (int qt = 0; qt < 2; ++qt) o4[dt][qt] = zero4;
  lacc[0] = zero4; lacc[1] = zero4;

  u16* Pl = &P_lds[w][0];

  // ---- prologue: stage tile 0 (slots K0,V0), then tile 1 (K1,V1) ----
  async16(&K_lds[0][cbase0 * 8], kp0);
  async16(&K_lds[0][cbase1 * 8], kp1);
  async16(&V_lds[0][cbase0 * 8], vp0);
  async16(&V_lds[0][cbase1 * 8], vp1);
  kp0 += 64 * QDIM; kp1 += 64 * QDIM; vp0 += 64; vp1 += 64;
  __syncthreads();  // tile 0 resident

  async16(&K_lds[1][cbase0 * 8], kp0);
  async16(&K_lds[1][cbase1 * 8], kp1);
  async16(&V_lds[1][cbase0 * 8], vp0);
  async16(&V_lds[1][cbase1 * 8], vp1);
  kp0 += 64 * QDIM; kp1 += 64 * QDIM; vp0 += 64; vp1 += 64;

  // QK^T(0) + exp -> P(0)
  {
    const u16* Kl = &K_lds[0][0];
    f32x4 sc[4][2];
    short8 kf0[4], kf1[4];
#pragma unroll
    for (int mt = 0; mt < 4; ++mt) {
      kf0[mt] = *(const short8*)&Kl[mt * 1024 + rb + cs0];
      kf1[mt] = *(const short8*)&Kl[mt * 1024 + rb + cs1];
    }
    __builtin_amdgcn_s_setprio(1);
#pragma unroll
    for (int mt = 0; mt < 4; ++mt)
#pragma unroll
      for (int qt = 0; qt < 2; ++qt)
        sc[mt][qt] = __builtin_amdgcn_mfma_f32_16x16x32_bf16(kf0[mt], qf[qt][0],
                                                             zero4, 0, 0, 0);
#pragma unroll
    for (int mt = 0; mt < 4; ++mt)
#pragma unroll
      for (int qt = 0; qt < 2; ++qt)
        sc[mt][qt] = __builtin_amdgcn_mfma_f32_16x16x32_bf16(kf1[mt], qf[qt][1],
                                                             sc[mt][qt], 0, 0, 0);
    __builtin_amdgcn_s_setprio(0);
#pragma unroll
    for (int qt = 0; qt < 2; ++qt)
#pragma unroll
      for (int mt = 0; mt < 4; ++mt) {
        float p0 = fexp2(sc[mt][qt][0]);
        float p1 = fexp2(sc[mt][qt][1]);
        float p2 = fexp2(sc[mt][qt][2]);
        float p3 = fexp2(sc[mt][qt][3]);
        uint2 pk = {pk2(p0, p1), pk2(p2, p3)};
        *(uint2*)&Pl[qt * 1024 + pwb + ((mt * 2) ^ pms) * 8] = pk;
      }
  }
  __syncthreads();  // tile 1 resident (vmcnt drained by barrier)

  // ---- main loop: QK^T(kc) ++ PV(kc-1), then exp(kc) ----
  for (int kc = 1; kc < NK / 64; ++kc) {
    const int pv = (kc - 1) % 3;          // V slot of tile kc-1
    // stage tile kc+1 (K slot (kc+1)&1, V slot (kc+1)%3)
    if (kc + 1 < NK / 64) {
      const int nk = (kc + 1) & 1, nv = (kc + 1) % 3;
      async16(&K_lds[nk][cbase0 * 8], kp0);
      async16(&K_lds[nk][cbase1 * 8], kp1);
      async16(&V_lds[nv][cbase0 * 8], vp0);
      async16(&V_lds[nv][cbase1 * 8], vp1);
      kp0 += 64 * QDIM; kp1 += 64 * QDIM; vp0 += 64; vp1 += 64;
    }
    const u16* Kl = &K_lds[kc & 1][0];
    const u16* Vl = &V_lds[pv][0];

    // hoisted fragment loads: pb/vf feed PV(kc-1), kf feeds QK^T(kc)
    short8 pb[2][2], vf[2][4], kf[2][4];
#pragma unroll
    for (int qt = 0; qt < 2; ++qt) {
      pb[0][qt] = *(const short8*)&Pl[qt * 1024 + rb + cs0];
      pb[1][qt] = *(const short8*)&Pl[qt * 1024 + rb + cs1];
    }
#pragma unroll
    for (int dt = 0; dt < 4; ++dt) {
      vf[0][dt] = *(const short8*)&Vl[dt * 1024 + rb + cs0];
      vf[1][dt] = *(const short8*)&Vl[dt * 1024 + rb + cs1];
    }
#pragma unroll
    for (int mt = 0; mt < 4; ++mt) {
      kf[0][mt] = *(const short8*)&Kl[mt * 1024 + rb + cs0];
      kf[1][mt] = *(const short8*)&Kl[mt * 1024 + rb + cs1];
    }

    // merged MFMA cluster: QK^T(kc) and PV(kc-1) are independent
    f32x4 sc[4][2];
    __builtin_amdgcn_s_setprio(1);
#pragma unroll
    for (int mt = 0; mt < 4; ++mt)
#pragma unroll
      for (int qt = 0; qt < 2; ++qt)
        sc[mt][qt] = __builtin_amdgcn_mfma_f32_16x16x32_bf16(kf[0][mt], qf[qt][0],
                                                             zero4, 0, 0, 0);
#pragma unroll
    for (int qt = 0; qt < 2; ++qt)
      lacc[qt] = __builtin_amdgcn_mfma_f32_16x16x32_bf16(ones8, pb[0][qt],
                                                         lacc[qt], 0, 0, 0);
#pragma unroll
    for (int dt = 0; dt < 4; ++dt)
#pragma unroll
      for (int qt = 0; qt < 2; ++qt)
        o4[dt][qt] = __builtin_amdgcn_mfma_f32_16x16x32_bf16(vf[0][dt], pb[0][qt],
                                                             o4[dt][qt], 0, 0, 0);
#pragma unroll
    for (int mt = 0; mt < 4; ++mt)
#pragma unroll
      for (int qt = 0; qt < 2; ++qt)
        sc[mt][qt] = __builtin_amdgcn_mfma_f32_16x16x32_bf16(kf[1][mt], qf[qt][1],
                                                             sc[mt][qt], 0, 0, 0);
#pragma unroll
    for (int qt = 0; qt < 2; ++qt)
      lacc[qt] = __builtin_amdgcn_mfma_f32_16x16x32_bf16(ones8, pb[1][qt],
                                                         lacc[qt], 0, 0, 0);
#pragma unroll
    for (int dt = 0; dt < 4; ++dt)
#pragma unroll
      for (int qt = 0; qt < 2; ++qt)
        o4[dt][qt] = __builtin_amdgcn_mfma_f32_16x16x32_bf16(vf[1][dt], pb[1][qt],
                                                             o4[dt][qt], 0, 0, 0);
    __builtin_amdgcn_s_setprio(0);

    // exp(kc) -> P_lds (overwrites P(kc-1); same-wave DS in-order vs pb reads)
#pragma unroll
    for (int qt = 0; qt < 2; ++qt)
#pragma unroll
      for (int mt = 0; mt < 4; ++mt) {
        float p0 = fexp2(sc[mt][qt][0]);
        float p1 = fexp2(sc[mt][qt][1]);
        float p2 = fexp2(sc[mt][qt][2]);
        float p3 = fexp2(sc[mt][qt][3]);
        uint2 pk = {pk2(p0, p1), pk2(p2, p3)};
        *(uint2*)&Pl[qt * 1024 + pwb + ((mt * 2) ^ pms) * 8] = pk;
      }
    __syncthreads();  // staged tile resident; buffers safe to rotate
  }

  // ---- epilogue: PV for the last tile (15), V slot 15%3 = 0 ----
  {
    const u16* Vl = &V_lds[(NK / 64 - 1) % 3][0];
    short8 pb[2][2], vf[2][4];
#pragma unroll
    for (int qt = 0; qt < 2; ++qt) {
      pb[0][qt] = *(const short8*)&Pl[qt * 1024 + rb + cs0];
      pb[1][qt] = *(const short8*)&Pl[qt * 1024 + rb + cs1];
    }
#pragma unroll
    for (int dt = 0; dt < 4; ++dt) {
      vf[0][dt] = *(const short8*)&Vl[dt * 1024 + rb + cs0];
      vf[1][dt] = *(const short8*)&Vl[dt * 1024 + rb + cs1];
    }
    __builtin_amdgcn_s_setprio(1);
#pragma unroll
    for (int ks = 0; ks < 2; ++ks) {
#pragma unroll
      for (int qt = 0; qt < 2; ++qt)
        lacc[qt] = __builtin_amdgcn_mfma_f32_16x16x32_bf16(ones8, pb[ks][qt],
                                                           lacc[qt], 0, 0, 0);
#pragma unroll
      for (int dt = 0; dt < 4; ++dt)
#pragma unroll
        for (int qt = 0; qt < 2; ++qt)
          o4[dt][qt] = __builtin_amdgcn_mfma_f32_16x16x32_bf16(vf[ks][dt], pb[ks][qt],
                                                               o4[dt][qt], 0, 0, 0);
    }
    __builtin_amdgcn_s_setprio(0);
  }

  // epilogue: lacc[qt][r] all hold the full row-sum for qrow=qt*16+l15
#pragma unroll
  for (int qt = 0; qt < 2; ++qt) {
    float inv = __builtin_amdgcn_rcpf(lacc[qt][0]);
    size_t row = (size_t)(b * NQ + qrow0 + qt * 16 + l15);
#pragma unroll
    for (int dt = 0; dt < 4; ++dt) {
      uint2 pk = {pk2(o4[dt][qt][0] * inv, o4[dt][qt][1] * inv),
                  pk2(o4[dt][qt][2] * inv, o4[dt][qt][3] * inv)};
      *(uint2*)(AO + row * QDIM + h * HD + dt * 16 + g * 4) = pk;
    }
  }
}

// ---------------------------------------------------------------------------
extern "C" void kernel_launch(void* const* d_in, const int* in_sizes, int n_in,
                              void* d_out, int out_size, void* d_ws, size_t ws_size,
                              hipStream_t stream) {
  const float* query = (const float*)d_in[0];
  const float* key   = (const float*)d_in[1];
  const float* value = (const float*)d_in[2];
  const float* Wq = (const float*)d_in[3];
  const float* bq = (const float*)d_in[4];
  const float* Wk = (const float*)d_in[5];
  const float* bk = (const float*)d_in[6];
  const float* Wv = (const float*)d_in[7];
  const float* bv = (const float*)d_in[8];
  const float* Wo = (const float*)d_in[9];
  const float* bo = (const float*)d_in[10];

  char* ws = (char*)d_ws;
  size_t off = 0;
  auto alloc = [&](size_t bytes) -> void* {
    void* p = ws + off;
    off += (bytes + 255) & ~(size_t)255;
    return p;
  };
  const size_t NQTOT = (size_t)B_SZ * NQ;        // 16384
  const size_t NKTOT = (size_t)B_SZ * NK;        // 4096
  u16* qbf = (u16*)alloc(NQTOT * QDIM * 2);      // query bf16; reused as AO later
  u16* kbf = (u16*)alloc(NKTOT * KDIM * 2);
  u16* vbf = (u16*)alloc(NKTOT * KDIM * 2);
  u16* wqt = (u16*)alloc((size_t)QDIM * QDIM * 2);
  u16* wkt = (u16*)alloc((size_t)KDIM * QDIM * 2);
  u16* wvt = (u16*)alloc((size_t)KDIM * QDIM * 2);
  u16* wot = (u16*)alloc((size_t)QDIM * QDIM * 2);
  u16* Qp  = (u16*)alloc(NQTOT * QDIM * 2);
  u16* Kp  = (u16*)alloc(NKTOT * QDIM * 2);
  u16* VT  = (u16*)alloc((size_t)QDIM * NKTOT * 2);  // (1024, B*NK) transposed V-proj
  u16* AO  = qbf;  // qbf dead after Q-projection

  // 1) dtype conversions (query alone; key+value merged into one launch)
  {
    int n4 = (int)(NQTOT * QDIM / 4);
    f32_to_bf16_k<<<(n4 + 255) / 256, 256, 0, stream>>>(query, qbf, n4);
  }
  {
    int n4 = (int)(NKTOT * KDIM / 4);
    f32_to_bf16_2k<<<dim3((n4 + 255) / 256, 2), 256, 0, stream>>>(key, value, kbf,
                                                                  vbf, n4);
  }
  // 2) weight transposes (K x N -> N x K bf16)
  transpose_bf16_k<<<dim3(QDIM / 32, QDIM / 32), 256, 0, stream>>>(Wq, wqt, QDIM, QDIM);
  transpose_bf16_k<<<dim3(QDIM / 32, KDIM / 32), 256, 0, stream>>>(Wk, wkt, KDIM, QDIM);
  transpose_bf16_k<<<dim3(QDIM / 32, KDIM / 32), 256, 0, stream>>>(Wv, wvt, KDIM, QDIM);
  transpose_bf16_k<<<dim3(QDIM / 32, QDIM / 32), 256, 0, stream>>>(Wo, wot, QDIM, QDIM);

  // 3) projections: Q scaled by QSCALE (softmax exp2-domain fold); K+V fused
  gemm_bt<<<dim3(NQTOT / 128, QDIM / 128), 256, 0, stream>>>(
      qbf, wqt, bq, nullptr, Qp, (int)NQTOT, QDIM, QDIM, 1, QSCALE);
  gemm_kv<<<dim3(NKTOT / 128, QDIM / 128, 2), 256, 0, stream>>>(
      kbf, vbf, wkt, wvt, bk, bv, Kp, VT, (int)NKTOT, QDIM, KDIM);

  // 4) fused attention -> AO (bf16, (B*Nq, 1024))
  attn_kernel<<<dim3(NQ / 128, B_SZ * NH), 256, 0, stream>>>(Qp, Kp, VT, AO);

  // 5) output projection (fp32 out)
  gemm_bt<<<dim3(NQTOT / 128, QDIM / 128), 256, 0, stream>>>(
      AO, wot, bo, (float*)d_out, nullptr, (int)NQTOT, QDIM, QDIM, 0, 1.0f);

  (void)in_sizes; (void)n_in; (void)out_size; (void)ws_size;
}

// Round 4
// 421.982 us; speedup vs baseline: 1.0208x; 1.0026x over previous
//
#include <hip/hip_runtime.h>
#include <hip/hip_bf16.h>
#include <stdint.h>

// ---------------------------------------------------------------------------
// CrossAttention: out = softmax((X Wq)(K Wk)^T * s) (V Wv) Wo  (+biases)
// B=4, Nq=4096, Nk=1024, QUERY_DIM=1024, KEY_DIM=768, H=16, HD=64
// R8: T4 counted-vmcnt barrier in attn. The __syncthreads() at loop end
//     drained vmcnt(0) every iteration (staged tile kc+1 forced to complete
//     before any wave proceeds -> ~1500 cyc/iter stall). Now: K staged
//     before V each iteration; loop-end barrier = s_waitcnt vmcnt(2) +
//     sched_barrier + raw s_barrier (K(kc+1) done, V(kc+1) may fly - PV is
//     deferred so V isn't read until kc+2). Post-loop vmcnt(0)+barrier
//     covers the final PV's V reads.
// Carried (R7): deferred-PV pipeline QK^T(kc)++PV(kc-1), V triple-buffer,
//     raw v_exp_f32, hoisted LDS offsets, setprio, XOR-swizzled LDS, no-max
//     exp2 softmax, MFMA row-sum, fused K/V projection.
// ---------------------------------------------------------------------------

typedef unsigned short u16;
typedef __attribute__((ext_vector_type(8))) short short8;   // 8 bf16 = 4 VGPRs
typedef __attribute__((ext_vector_type(4))) float f32x4;    // MFMA C/D frag

#define B_SZ 4
#define NQ   4096
#define NK   1024
#define QDIM 1024
#define KDIM 768
#define NH   16
#define HD   64
// scale * log2(e): softmax computed in exp2 domain (folded into Q projection)
#define QSCALE (0.125f * 1.44269504f)

__device__ __forceinline__ u16 f2bf(float f) {
  union { float f; uint32_t u; } v; v.f = f;
  uint32_t u = v.u;
  return (u16)((u + 0x7FFFu + ((u >> 16) & 1u)) >> 16);  // RNE
}

// packed f32x2 -> bf16x2 (v_cvt_pk_bf16_f32 on gfx950)
__device__ __forceinline__ uint32_t pk2(float a, float b) {
  union { __hip_bfloat162 h; uint32_t u; } cv;
  cv.h = __float22bfloat162_rn(float2{a, b});
  return cv.u;
}

// raw v_exp_f32 (no denormal-guard expansion; underflow flushes to 0 - fine
// for softmax numerator)
__device__ __forceinline__ float fexp2(float x) {
  return __builtin_amdgcn_exp2f(x);
}

// global -> LDS async copy, 16B per lane; lds base must be wave-uniform.
__device__ __forceinline__ void async16(u16* lds, const u16* g) {
  __builtin_amdgcn_global_load_lds(
      (__attribute__((address_space(1))) void*)(g),
      (__attribute__((address_space(3))) void*)(lds), 16, 0, 0);
}

// ---------------------------------------------------------------------------
// fp32 -> bf16 elementwise (vectorized x4, packed cvt)
// ---------------------------------------------------------------------------
__global__ __launch_bounds__(256) void f32_to_bf16_k(const float* __restrict__ in,
                                                     u16* __restrict__ out, int n4) {
  int i = blockIdx.x * 256 + threadIdx.x;
  if (i < n4) {
    f32x4 v = ((const f32x4*)in)[i];
    uint2 o = {pk2(v.x, v.y), pk2(v.z, v.w)};
    ((uint2*)out)[i] = o;
  }
}

// two-tensor variant: blockIdx.y selects (a->oa) or (b->ob); one launch for K+V
__global__ __launch_bounds__(256) void f32_to_bf16_2k(const float* __restrict__ a,
                                                      const float* __restrict__ b,
                                                      u16* __restrict__ oa,
                                                      u16* __restrict__ ob, int n4) {
  int i = blockIdx.x * 256 + threadIdx.x;
  const float* in = blockIdx.y ? b : a;
  u16* out = blockIdx.y ? ob : oa;
  if (i < n4) {
    f32x4 v = ((const f32x4*)in)[i];
    uint2 o = {pk2(v.x, v.y), pk2(v.z, v.w)};
    ((uint2*)out)[i] = o;
  }
}

// ---------------------------------------------------------------------------
// W (K x N fp32, row-major) -> Wt (N x K bf16, row-major)   [LDS-tiled]
// ---------------------------------------------------------------------------
__global__ __launch_bounds__(256) void transpose_bf16_k(const float* __restrict__ W,
                                                        u16* __restrict__ Wt,
                                                        int K, int N) {
  __shared__ float t[32][33];
  int tx = threadIdx.x & 31, ty = threadIdx.x >> 5;  // 32 x 8
  int nb = blockIdx.x * 32, kb = blockIdx.y * 32;
#pragma unroll
  for (int i = 0; i < 4; ++i)
    t[ty + i * 8][tx] = W[(size_t)(kb + ty + i * 8) * N + nb + tx];
  __syncthreads();
#pragma unroll
  for (int i = 0; i < 4; ++i)
    Wt[(size_t)(nb + ty + i * 8) * K + kb + tx] = f2bf(t[tx][ty + i * 8]);
}

// ---------------------------------------------------------------------------
// C[M,N] = (A[M,K] * Bt[N,K]^T + bias) * scale ; out bf16 or fp32
// 128x128 tile, BK=64, 256 threads (4 waves, each 64x64 = 4x4 16x16 frags)
// LDS rows (128B) chunk-swizzled: physical 16B chunk p holds logical p^(row&7)
// ---------------------------------------------------------------------------
__global__ __launch_bounds__(256) void gemm_bt(const u16* __restrict__ A,
                                               const u16* __restrict__ Bt,
                                               const float* __restrict__ bias,
                                               float* __restrict__ Cf,
                                               u16* __restrict__ Cb,
                                               int M, int N, int K, int out_bf16,
                                               float scale) {
  __shared__ __align__(16) u16 Al[128 * 64];
  __shared__ __align__(16) u16 Bl[128 * 64];
  const int tid = threadIdx.x;
  const int w = tid >> 6, lane = tid & 63;
  const int g = lane >> 4, l15 = lane & 15;
  const int sw = l15 & 7;  // fragment-row swizzle key (row&7 == l15&7)
  const int mbase = blockIdx.x * 128, nbase = blockIdx.y * 128;
  const int wm = (w & 1) * 64, wn = (w >> 1) * 64;

  f32x4 zero4 = {0.f, 0.f, 0.f, 0.f};
  f32x4 acc[4][4];
#pragma unroll
  for (int i = 0; i < 4; ++i)
#pragma unroll
    for (int j = 0; j < 4; ++j) acc[i][j] = zero4;

  for (int kb = 0; kb < K; kb += 64) {
#pragma unroll
    for (int i = 0; i < 4; ++i) {
      int cbase = w * 256 + i * 64;          // wave-uniform region base (chunks)
      int c = cbase + lane;
      int row = c >> 3;
      int kc8 = ((c & 7) ^ (row & 7)) * 8;   // swizzled source chunk
      async16(&Al[cbase * 8], A + (size_t)(mbase + row) * K + kb + kc8);
      async16(&Bl[cbase * 8], Bt + (size_t)(nbase + row) * K + kb + kc8);
    }
    __syncthreads();
#pragma unroll
    for (int ks = 0; ks < 2; ++ks) {
      short8 af[4], bf[4];
#pragma unroll
      for (int mt = 0; mt < 4; ++mt)
        af[mt] = *(const short8*)&Al[(wm + mt * 16 + l15) * 64 + ((ks * 4 + g) ^ sw) * 8];
#pragma unroll
      for (int nt = 0; nt < 4; ++nt)
        bf[nt] = *(const short8*)&Bl[(wn + nt * 16 + l15) * 64 + ((ks * 4 + g) ^ sw) * 8];
#pragma unroll
      for (int mt = 0; mt < 4; ++mt)
#pragma unroll
        for (int nt = 0; nt < 4; ++nt)
          acc[mt][nt] = __builtin_amdgcn_mfma_f32_16x16x32_bf16(af[mt], bf[nt],
                                                                acc[mt][nt], 0, 0, 0);
    }
    __syncthreads();
  }

#pragma unroll
  for (int nt = 0; nt < 4; ++nt) {
    int col = nbase + wn + nt * 16 + l15;
    float bv = bias[col];
#pragma unroll
    for (int mt = 0; mt < 4; ++mt)
#pragma unroll
      for (int r = 0; r < 4; ++r) {
        int row = mbase + wm + mt * 16 + g * 4 + r;
        float v = (acc[mt][nt][r] + bv) * scale;
        if (out_bf16) Cb[(size_t)row * N + col] = f2bf(v);
        else          Cf[(size_t)row * N + col] = v;
      }
  }
}

// ---------------------------------------------------------------------------
// Combined K/V projection: blockIdx.z==0 -> Kp[M,N] = kA*Wk^T + bk (row store)
//                          blockIdx.z==1 -> VT[N,M] = (vA*Wv^T + bv)^T
// ---------------------------------------------------------------------------
__global__ __launch_bounds__(256) void gemm_kv(const u16* __restrict__ kA,
                                               const u16* __restrict__ vA,
                                               const u16* __restrict__ Wk,
                                               const u16* __restrict__ Wv,
                                               const float* __restrict__ bk,
                                               const float* __restrict__ bv,
                                               u16* __restrict__ Kp,
                                               u16* __restrict__ VT,
                                               int M, int N, int K) {
  __shared__ __align__(16) u16 Al[128 * 64];
  __shared__ __align__(16) u16 Bl[128 * 64];
  const int ct = blockIdx.z;  // uniform
  const u16* A  = ct ? vA : kA;
  const u16* Bt = ct ? Wv : Wk;
  const float* bias = ct ? bv : bk;
  const int tid = threadIdx.x;
  const int w = tid >> 6, lane = tid & 63;
  const int g = lane >> 4, l15 = lane & 15;
  const int sw = l15 & 7;
  const int mbase = blockIdx.x * 128, nbase = blockIdx.y * 128;
  const int wm = (w & 1) * 64, wn = (w >> 1) * 64;

  f32x4 zero4 = {0.f, 0.f, 0.f, 0.f};
  f32x4 acc[4][4];  // z=0: [mt][nt]; z=1: [nt][mt] (transposed D)
#pragma unroll
  for (int i = 0; i < 4; ++i)
#pragma unroll
    for (int j = 0; j < 4; ++j) acc[i][j] = zero4;

  for (int kb = 0; kb < K; kb += 64) {
#pragma unroll
    for (int i = 0; i < 4; ++i) {
      int cbase = w * 256 + i * 64;
      int c = cbase + lane;
      int row = c >> 3;
      int kc8 = ((c & 7) ^ (row & 7)) * 8;
      async16(&Al[cbase * 8], A + (size_t)(mbase + row) * K + kb + kc8);
      async16(&Bl[cbase * 8], Bt + (size_t)(nbase + row) * K + kb + kc8);
    }
    __syncthreads();
#pragma unroll
    for (int ks = 0; ks < 2; ++ks) {
      short8 af[4], bf[4];
#pragma unroll
      for (int mt = 0; mt < 4; ++mt)
        af[mt] = *(const short8*)&Al[(wm + mt * 16 + l15) * 64 + ((ks * 4 + g) ^ sw) * 8];
#pragma unroll
      for (int nt = 0; nt < 4; ++nt)
        bf[nt] = *(const short8*)&Bl[(wn + nt * 16 + l15) * 64 + ((ks * 4 + g) ^ sw) * 8];
      if (ct) {
#pragma unroll
        for (int nt = 0; nt < 4; ++nt)
#pragma unroll
          for (int mt = 0; mt < 4; ++mt)
            acc[nt][mt] = __builtin_amdgcn_mfma_f32_16x16x32_bf16(bf[nt], af[mt],
                                                                  acc[nt][mt], 0, 0, 0);
      } else {
#pragma unroll
        for (int mt = 0; mt < 4; ++mt)
#pragma unroll
          for (int nt = 0; nt < 4; ++nt)
            acc[mt][nt] = __builtin_amdgcn_mfma_f32_16x16x32_bf16(af[mt], bf[nt],
                                                                  acc[mt][nt], 0, 0, 0);
      }
    }
    __syncthreads();
  }

  if (ct) {
    // D = C^T: lane holds VT[n=nbase+wn+nt*16+g*4+r][m=mbase+wm+mt*16+l15]
#pragma unroll
    for (int mt = 0; mt < 4; ++mt) {
      int m = mbase + wm + mt * 16 + l15;
#pragma unroll
      for (int nt = 0; nt < 4; ++nt)
#pragma unroll
        for (int r = 0; r < 4; ++r) {
          int n = nbase + wn + nt * 16 + g * 4 + r;
          VT[(size_t)n * M + m] = f2bf(acc[nt][mt][r] + bias[n]);
        }
    }
  } else {
#pragma unroll
    for (int nt = 0; nt < 4; ++nt) {
      int col = nbase + wn + nt * 16 + l15;
      float bvv = bias[col];
#pragma unroll
      for (int mt = 0; mt < 4; ++mt)
#pragma unroll
        for (int r = 0; r < 4; ++r) {
          int row = mbase + wm + mt * 16 + g * 4 + r;
          Kp[(size_t)row * N + col] = f2bf(acc[mt][nt][r] + bvv);
        }
    }
  }
}

// ---------------------------------------------------------------------------
// Fused flash attention, S^T/O^T orientation, no-max softmax, MFMA row-sum.
// Grid: (Nq/128, B*H). 256 thr = 4 waves; wave owns 32 q-rows (2 subtiles).
// R8 pipeline per iteration kc: [stage K(kc+1) then V(kc+1)] [ds_read
// pb(kc-1), vf(kc-1), kf(kc)] [MFMA: QK^T(kc) ++ PV(kc-1)] [exp(kc)->P_lds]
// [s_waitcnt vmcnt(2); s_barrier]  -- K(kc+1) done, V(kc+1) may stay in
// flight (read only at kc+2). Post-loop vmcnt(0)+barrier for final PV.
// ---------------------------------------------------------------------------
__global__ __launch_bounds__(256, 2) void attn_kernel(const u16* __restrict__ Qp,
                                                      const u16* __restrict__ Kp,
                                                      const u16* __restrict__ VT,
                                                      u16* __restrict__ AO) {
  __shared__ __align__(16) u16 K_lds[2][64 * 64];     // [buf][kcol][d] swizzled
  __shared__ __align__(16) u16 V_lds[3][64 * 64];     // [buf][d][kcol] swizzled
  __shared__ __align__(16) u16 P_lds[4][32 * 64];     // per-wave [qrow][kcol] swz

  const int tid = threadIdx.x;
  const int w = tid >> 6, lane = tid & 63;
  const int g = lane >> 4, l15 = lane & 15;
  const int sw = l15 & 7;
  const int bh = blockIdx.y, b = bh >> 4, h = bh & 15;
  const int qrow0 = blockIdx.x * 128 + w * 32;
  const int MT = B_SZ * NK;  // VT leading dim

  // ---- staging lane constants (two 64-chunk regions per wave) ----
  const int cbase0 = (w * 2 + 0) * 64;
  const int cbase1 = (w * 2 + 1) * 64;
  const int c0 = cbase0 + lane, c1 = cbase1 + lane;
  const int row0 = c0 >> 3, kc80 = ((c0 & 7) ^ (row0 & 7)) * 8;
  const int row1 = c1 >> 3, kc81 = ((c1 & 7) ^ (row1 & 7)) * 8;

  // incremental per-lane global source pointers
  const u16* kp0 = Kp + (size_t)(b * NK + row0) * QDIM + h * HD + kc80;
  const u16* kp1 = Kp + (size_t)(b * NK + row1) * QDIM + h * HD + kc81;
  const u16* vp0 = VT + (size_t)(h * HD + row0) * MT + b * NK + kc80;
  const u16* vp1 = VT + (size_t)(h * HD + row1) * MT + b * NK + kc81;

  // ---- compute lane constants ----
  const int rb = l15 * 64;                      // fragment row base (elements)
  const int cs0 = (g ^ sw) * 8;                 // ks=0 chunk select
  const int cs1 = ((4 + g) ^ sw) * 8;           // ks=1 chunk select
  // P-store: addr = qt*1024 + pwb + ((mt*2)^pms)*8
  const int pwb = rb + (((g >> 1) ^ (sw & 1)) * 8) + (g & 1) * 4;
  const int pms = sw & 6;

  // ones A-fragment (bf16 1.0 in every slot) for the MFMA row-sum
  short8 ones8;
#pragma unroll
  for (int j = 0; j < 8; ++j) ones8[j] = (short)0x3F80;

  // Q fragments (B-operand role): lane holds Q[qrow=qt*16+l15][d=ks*32+g*8+j]
  short8 qf[2][2];
#pragma unroll
  for (int qt = 0; qt < 2; ++qt)
#pragma unroll
    for (int ks = 0; ks < 2; ++ks) {
      size_t row = (size_t)(b * NQ + qrow0 + qt * 16 + l15);
      qf[qt][ks] = *(const short8*)(Qp + row * QDIM + h * HD + ks * 32 + g * 8);
    }

  f32x4 zero4 = {0.f, 0.f, 0.f, 0.f};
  f32x4 o4[4][2];              // O^T frags: [dt][qt], r-index = d
  f32x4 lacc[2];               // row-sum via mfma(ones, P): col=qrow, rows dup
#pragma unroll
  for (int dt = 0; dt < 4; ++dt)
#pragma unroll
    for (int qt = 0; qt < 2; ++qt) o4[dt][qt] = zero4;
  lacc[0] = zero4; lacc[1] = zero4;

  u16* Pl = &P_lds[w][0];

  // ---- prologue: stage tile 0 (K0,V0), then tile 1 (K1,V1) ----
  async16(&K_lds[0][cbase0 * 8], kp0);
  async16(&K_lds[0][cbase1 * 8], kp1);
  async16(&V_lds[0][cbase0 * 8], vp0);
  async16(&V_lds[0][cbase1 * 8], vp1);
  kp0 += 64 * QDIM; kp1 += 64 * QDIM; vp0 += 64; vp1 += 64;
  __syncthreads();  // tile 0 resident (full drain; prologue only)

  async16(&K_lds[1][cbase0 * 8], kp0);
  async16(&K_lds[1][cbase1 * 8], kp1);
  async16(&V_lds[1][cbase0 * 8], vp0);
  async16(&V_lds[1][cbase1 * 8], vp1);
  kp0 += 64 * QDIM; kp1 += 64 * QDIM; vp0 += 64; vp1 += 64;

  // QK^T(0) + exp -> P(0)
  {
    const u16* Kl = &K_lds[0][0];
    f32x4 sc[4][2];
    short8 kf0[4], kf1[4];
#pragma unroll
    for (int mt = 0; mt < 4; ++mt) {
      kf0[mt] = *(const short8*)&Kl[mt * 1024 + rb + cs0];
      kf1[mt] = *(const short8*)&Kl[mt * 1024 + rb + cs1];
    }
    __builtin_amdgcn_s_setprio(1);
#pragma unroll
    for (int mt = 0; mt < 4; ++mt)
#pragma unroll
      for (int qt = 0; qt < 2; ++qt)
        sc[mt][qt] = __builtin_amdgcn_mfma_f32_16x16x32_bf16(kf0[mt], qf[qt][0],
                                                             zero4, 0, 0, 0);
#pragma unroll
    for (int mt = 0; mt < 4; ++mt)
#pragma unroll
      for (int qt = 0; qt < 2; ++qt)
        sc[mt][qt] = __builtin_amdgcn_mfma_f32_16x16x32_bf16(kf1[mt], qf[qt][1],
                                                             sc[mt][qt], 0, 0, 0);
    __builtin_amdgcn_s_setprio(0);
#pragma unroll
    for (int qt = 0; qt < 2; ++qt)
#pragma unroll
      for (int mt = 0; mt < 4; ++mt) {
        float p0 = fexp2(sc[mt][qt][0]);
        float p1 = fexp2(sc[mt][qt][1]);
        float p2 = fexp2(sc[mt][qt][2]);
        float p3 = fexp2(sc[mt][qt][3]);
        uint2 pk = {pk2(p0, p1), pk2(p2, p3)};
        *(uint2*)&Pl[qt * 1024 + pwb + ((mt * 2) ^ pms) * 8] = pk;
      }
  }
  __syncthreads();  // tile 1 resident (full drain; prologue only)

  // ---- main loop: QK^T(kc) ++ PV(kc-1), then exp(kc) ----
  for (int kc = 1; kc < NK / 64; ++kc) {
    const int pv = (kc - 1) % 3;          // V slot of tile kc-1
    // stage tile kc+1: K first, V second (vmcnt(2) leaves only V in flight)
    if (kc + 1 < NK / 64) {
      const int nk = (kc + 1) & 1, nv = (kc + 1) % 3;
      async16(&K_lds[nk][cbase0 * 8], kp0);
      async16(&K_lds[nk][cbase1 * 8], kp1);
      async16(&V_lds[nv][cbase0 * 8], vp0);
      async16(&V_lds[nv][cbase1 * 8], vp1);
      kp0 += 64 * QDIM; kp1 += 64 * QDIM; vp0 += 64; vp1 += 64;
    }
    const u16* Kl = &K_lds[kc & 1][0];
    const u16* Vl = &V_lds[pv][0];

    // hoisted fragment loads: pb/vf feed PV(kc-1), kf feeds QK^T(kc)
    short8 pb[2][2], vf[2][4], kf[2][4];
#pragma unroll
    for (int qt = 0; qt < 2; ++qt) {
      pb[0][qt] = *(const short8*)&Pl[qt * 1024 + rb + cs0];
      pb[1][qt] = *(const short8*)&Pl[qt * 1024 + rb + cs1];
    }
#pragma unroll
    for (int dt = 0; dt < 4; ++dt) {
      vf[0][dt] = *(const short8*)&Vl[dt * 1024 + rb + cs0];
      vf[1][dt] = *(const short8*)&Vl[dt * 1024 + rb + cs1];
    }
#pragma unroll
    for (int mt = 0; mt < 4; ++mt) {
      kf[0][mt] = *(const short8*)&Kl[mt * 1024 + rb + cs0];
      kf[1][mt] = *(const short8*)&Kl[mt * 1024 + rb + cs1];
    }

    // merged MFMA cluster: QK^T(kc) and PV(kc-1) are independent
    f32x4 sc[4][2];
    __builtin_amdgcn_s_setprio(1);
#pragma unroll
    for (int mt = 0; mt < 4; ++mt)
#pragma unroll
      for (int qt = 0; qt < 2; ++qt)
        sc[mt][qt] = __builtin_amdgcn_mfma_f32_16x16x32_bf16(kf[0][mt], qf[qt][0],
                                                             zero4, 0, 0, 0);
#pragma unroll
    for (int qt = 0; qt < 2; ++qt)
      lacc[qt] = __builtin_amdgcn_mfma_f32_16x16x32_bf16(ones8, pb[0][qt],
                                                         lacc[qt], 0, 0, 0);
#pragma unroll
    for (int dt = 0; dt < 4; ++dt)
#pragma unroll
      for (int qt = 0; qt < 2; ++qt)
        o4[dt][qt] = __builtin_amdgcn_mfma_f32_16x16x32_bf16(vf[0][dt], pb[0][qt],
                                                             o4[dt][qt], 0, 0, 0);
#pragma unroll
    for (int mt = 0; mt < 4; ++mt)
#pragma unroll
      for (int qt = 0; qt < 2; ++qt)
        sc[mt][qt] = __builtin_amdgcn_mfma_f32_16x16x32_bf16(kf[1][mt], qf[qt][1],
                                                             sc[mt][qt], 0, 0, 0);
#pragma unroll
    for (int qt = 0; qt < 2; ++qt)
      lacc[qt] = __builtin_amdgcn_mfma_f32_16x16x32_bf16(ones8, pb[1][qt],
                                                         lacc[qt], 0, 0, 0);
#pragma unroll
    for (int dt = 0; dt < 4; ++dt)
#pragma unroll
      for (int qt = 0; qt < 2; ++qt)
        o4[dt][qt] = __builtin_amdgcn_mfma_f32_16x16x32_bf16(vf[1][dt], pb[1][qt],
                                                             o4[dt][qt], 0, 0, 0);
    __builtin_amdgcn_s_setprio(0);

    // exp(kc) -> P_lds (overwrites P(kc-1); same-wave DS in-order vs pb reads)
#pragma unroll
    for (int qt = 0; qt < 2; ++qt)
#pragma unroll
      for (int mt = 0; mt < 4; ++mt) {
        float p0 = fexp2(sc[mt][qt][0]);
        float p1 = fexp2(sc[mt][qt][1]);
        float p2 = fexp2(sc[mt][qt][2]);
        float p3 = fexp2(sc[mt][qt][3]);
        uint2 pk = {pk2(p0, p1), pk2(p2, p3)};
        *(uint2*)&Pl[qt * 1024 + pwb + ((mt * 2) ^ pms) * 8] = pk;
      }

    // T4 counted barrier: wait K(kc+1) (all but 2 newest loads), let V(kc+1)
    // stay in flight - it is not read until iteration kc+2 (deferred PV).
    asm volatile("s_waitcnt vmcnt(2)" ::: "memory");
    __builtin_amdgcn_sched_barrier(0);
    __builtin_amdgcn_s_barrier();
  }

  // drain remaining staged loads (V of the last tile) before final PV
  asm volatile("s_waitcnt vmcnt(0)" ::: "memory");
  __builtin_amdgcn_sched_barrier(0);
  __builtin_amdgcn_s_barrier();

  // ---- epilogue: PV for the last tile (15), V slot 15%3 = 0 ----
  {
    const u16* Vl = &V_lds[(NK / 64 - 1) % 3][0];
    short8 pb[2][2], vf[2][4];
#pragma unroll
    for (int qt = 0; qt < 2; ++qt) {
      pb[0][qt] = *(const short8*)&Pl[qt * 1024 + rb + cs0];
      pb[1][qt] = *(const short8*)&Pl[qt * 1024 + rb + cs1];
    }
#pragma unroll
    for (int dt = 0; dt < 4; ++dt) {
      vf[0][dt] = *(const short8*)&Vl[dt * 1024 + rb + cs0];
      vf[1][dt] = *(const short8*)&Vl[dt * 1024 + rb + cs1];
    }
    __builtin_amdgcn_s_setprio(1);
#pragma unroll
    for (int ks = 0; ks < 2; ++ks) {
#pragma unroll
      for (int qt = 0; qt < 2; ++qt)
        lacc[qt] = __builtin_amdgcn_mfma_f32_16x16x32_bf16(ones8, pb[ks][qt],
                                                           lacc[qt], 0, 0, 0);
#pragma unroll
      for (int dt = 0; dt < 4; ++dt)
#pragma unroll
        for (int qt = 0; qt < 2; ++qt)
          o4[dt][qt] = __builtin_amdgcn_mfma_f32_16x16x32_bf16(vf[ks][dt], pb[ks][qt],
                                                               o4[dt][qt], 0, 0, 0);
    }
    __builtin_amdgcn_s_setprio(0);
  }

  // epilogue: lacc[qt][r] all hold the full row-sum for qrow=qt*16+l15
#pragma unroll
  for (int qt = 0; qt < 2; ++qt) {
    float inv = __builtin_amdgcn_rcpf(lacc[qt][0]);
    size_t row = (size_t)(b * NQ + qrow0 + qt * 16 + l15);
#pragma unroll
    for (int dt = 0; dt < 4; ++dt) {
      uint2 pk = {pk2(o4[dt][qt][0] * inv, o4[dt][qt][1] * inv),
                  pk2(o4[dt][qt][2] * inv, o4[dt][qt][3] * inv)};
      *(uint2*)(AO + row * QDIM + h * HD + dt * 16 + g * 4) = pk;
    }
  }
}

// ---------------------------------------------------------------------------
extern "C" void kernel_launch(void* const* d_in, const int* in_sizes, int n_in,
                              void* d_out, int out_size, void* d_ws, size_t ws_size,
                              hipStream_t stream) {
  const float* query = (const float*)d_in[0];
  const float* key   = (const float*)d_in[1];
  const float* value = (const float*)d_in[2];
  const float* Wq = (const float*)d_in[3];
  const float* bq = (const float*)d_in[4];
  const float* Wk = (const float*)d_in[5];
  const float* bk = (const float*)d_in[6];
  const float* Wv = (const float*)d_in[7];
  const float* bv = (const float*)d_in[8];
  const float* Wo = (const float*)d_in[9];
  const float* bo = (const float*)d_in[10];

  char* ws = (char*)d_ws;
  size_t off = 0;
  auto alloc = [&](size_t bytes) -> void* {
    void* p = ws + off;
    off += (bytes + 255) & ~(size_t)255;
    return p;
  };
  const size_t NQTOT = (size_t)B_SZ * NQ;        // 16384
  const size_t NKTOT = (size_t)B_SZ * NK;        // 4096
  u16* qbf = (u16*)alloc(NQTOT * QDIM * 2);      // query bf16; reused as AO later
  u16* kbf = (u16*)alloc(NKTOT * KDIM * 2);
  u16* vbf = (u16*)alloc(NKTOT * KDIM * 2);
  u16* wqt = (u16*)alloc((size_t)QDIM * QDIM * 2);
  u16* wkt = (u16*)alloc((size_t)KDIM * QDIM * 2);
  u16* wvt = (u16*)alloc((size_t)KDIM * QDIM * 2);
  u16* wot = (u16*)alloc((size_t)QDIM * QDIM * 2);
  u16* Qp  = (u16*)alloc(NQTOT * QDIM * 2);
  u16* Kp  = (u16*)alloc(NKTOT * QDIM * 2);
  u16* VT  = (u16*)alloc((size_t)QDIM * NKTOT * 2);  // (1024, B*NK) transposed V-proj
  u16* AO  = qbf;  // qbf dead after Q-projection

  // 1) dtype conversions (query alone; key+value merged into one launch)
  {
    int n4 = (int)(NQTOT * QDIM / 4);
    f32_to_bf16_k<<<(n4 + 255) / 256, 256, 0, stream>>>(query, qbf, n4);
  }
  {
    int n4 = (int)(NKTOT * KDIM / 4);
    f32_to_bf16_2k<<<dim3((n4 + 255) / 256, 2), 256, 0, stream>>>(key, value, kbf,
                                                                  vbf, n4);
  }
  // 2) weight transposes (K x N -> N x K bf16)
  transpose_bf16_k<<<dim3(QDIM / 32, QDIM / 32), 256, 0, stream>>>(Wq, wqt, QDIM, QDIM);
  transpose_bf16_k<<<dim3(QDIM / 32, KDIM / 32), 256, 0, stream>>>(Wk, wkt, KDIM, QDIM);
  transpose_bf16_k<<<dim3(QDIM / 32, KDIM / 32), 256, 0, stream>>>(Wv, wvt, KDIM, QDIM);
  transpose_bf16_k<<<dim3(QDIM / 32, QDIM / 32), 256, 0, stream>>>(Wo, wot, QDIM, QDIM);

  // 3) projections: Q scaled by QSCALE (softmax exp2-domain fold); K+V fused
  gemm_bt<<<dim3(NQTOT / 128, QDIM / 128), 256, 0, stream>>>(
      qbf, wqt, bq, nullptr, Qp, (int)NQTOT, QDIM, QDIM, 1, QSCALE);
  gemm_kv<<<dim3(NKTOT / 128, QDIM / 128, 2), 256, 0, stream>>>(
      kbf, vbf, wkt, wvt, bk, bv, Kp, VT, (int)NKTOT, QDIM, KDIM);

  // 4) fused attention -> AO (bf16, (B*Nq, 1024))
  attn_kernel<<<dim3(NQ / 128, B_SZ * NH), 256, 0, stream>>>(Qp, Kp, VT, AO);

  // 5) output projection (fp32 out)
  gemm_bt<<<dim3(NQTOT / 128, QDIM / 128), 256, 0, stream>>>(
      AO, wot, bo, (float*)d_out, nullptr, (int)NQTOT, QDIM, QDIM, 0, 1.0f);

  (void)in_sizes; (void)n_in; (void)out_size; (void)ws_size;
}

// Round 5
// 415.425 us; speedup vs baseline: 1.0370x; 1.0158x over previous
//
#include <hip/hip_runtime.h>
#include <hip/hip_bf16.h>
#include <stdint.h>

// ---------------------------------------------------------------------------
// CrossAttention: out = softmax((X Wq)(K Wk)^T * s) (V Wv) Wo  (+biases)
// B=4, Nq=4096, Nk=1024, QUERY_DIM=1024, KEY_DIM=768, H=16, HD=64
// R9: Q-proj/O-proj GEMMs ported to a 3-buffer counted-vmcnt pipeline
//     (T3+T4+T5): 128x256 tile, BK=64, 512 thr / 8 waves, LDS 144 KB,
//     2 phases per K-tile {ds_read quadrant | stage kt+2 | barrier |
//     lgkmcnt(0) | 16 MFMA | barrier}, boundary s_waitcnt vmcnt(6) (never
//     drain to 0 in steady state). attn unchanged from R8 (114 us, NULL
//     delta for counted vmcnt there - kept since equal & verified).
// Carried: deferred-PV attn pipeline, raw v_exp_f32, XOR-swizzled LDS,
//     no-max exp2 softmax, MFMA row-sum, fused K/V projection.
// ---------------------------------------------------------------------------

typedef unsigned short u16;
typedef __attribute__((ext_vector_type(8))) short short8;   // 8 bf16 = 4 VGPRs
typedef __attribute__((ext_vector_type(4))) float f32x4;    // MFMA C/D frag

#define B_SZ 4
#define NQ   4096
#define NK   1024
#define QDIM 1024
#define KDIM 768
#define NH   16
#define HD   64
// scale * log2(e): softmax computed in exp2 domain (folded into Q projection)
#define QSCALE (0.125f * 1.44269504f)

__device__ __forceinline__ u16 f2bf(float f) {
  union { float f; uint32_t u; } v; v.f = f;
  uint32_t u = v.u;
  return (u16)((u + 0x7FFFu + ((u >> 16) & 1u)) >> 16);  // RNE
}

// packed f32x2 -> bf16x2 (v_cvt_pk_bf16_f32 on gfx950)
__device__ __forceinline__ uint32_t pk2(float a, float b) {
  union { __hip_bfloat162 h; uint32_t u; } cv;
  cv.h = __float22bfloat162_rn(float2{a, b});
  return cv.u;
}

// raw v_exp_f32 (no denormal-guard expansion; underflow flushes to 0 - fine
// for softmax numerator)
__device__ __forceinline__ float fexp2(float x) {
  return __builtin_amdgcn_exp2f(x);
}

// global -> LDS async copy, 16B per lane; lds base must be wave-uniform.
__device__ __forceinline__ void async16(u16* lds, const u16* g) {
  __builtin_amdgcn_global_load_lds(
      (__attribute__((address_space(1))) void*)(g),
      (__attribute__((address_space(3))) void*)(lds), 16, 0, 0);
}

// ---------------------------------------------------------------------------
// fp32 -> bf16 elementwise (vectorized x4, packed cvt)
// ---------------------------------------------------------------------------
__global__ __launch_bounds__(256) void f32_to_bf16_k(const float* __restrict__ in,
                                                     u16* __restrict__ out, int n4) {
  int i = blockIdx.x * 256 + threadIdx.x;
  if (i < n4) {
    f32x4 v = ((const f32x4*)in)[i];
    uint2 o = {pk2(v.x, v.y), pk2(v.z, v.w)};
    ((uint2*)out)[i] = o;
  }
}

// two-tensor variant: blockIdx.y selects (a->oa) or (b->ob); one launch for K+V
__global__ __launch_bounds__(256) void f32_to_bf16_2k(const float* __restrict__ a,
                                                      const float* __restrict__ b,
                                                      u16* __restrict__ oa,
                                                      u16* __restrict__ ob, int n4) {
  int i = blockIdx.x * 256 + threadIdx.x;
  const float* in = blockIdx.y ? b : a;
  u16* out = blockIdx.y ? ob : oa;
  if (i < n4) {
    f32x4 v = ((const f32x4*)in)[i];
    uint2 o = {pk2(v.x, v.y), pk2(v.z, v.w)};
    ((uint2*)out)[i] = o;
  }
}

// ---------------------------------------------------------------------------
// W (K x N fp32, row-major) -> Wt (N x K bf16, row-major)   [LDS-tiled]
// ---------------------------------------------------------------------------
__global__ __launch_bounds__(256) void transpose_bf16_k(const float* __restrict__ W,
                                                        u16* __restrict__ Wt,
                                                        int K, int N) {
  __shared__ float t[32][33];
  int tx = threadIdx.x & 31, ty = threadIdx.x >> 5;  // 32 x 8
  int nb = blockIdx.x * 32, kb = blockIdx.y * 32;
#pragma unroll
  for (int i = 0; i < 4; ++i)
    t[ty + i * 8][tx] = W[(size_t)(kb + ty + i * 8) * N + nb + tx];
  __syncthreads();
#pragma unroll
  for (int i = 0; i < 4; ++i)
    Wt[(size_t)(nb + ty + i * 8) * K + kb + tx] = f2bf(t[tx][ty + i * 8]);
}

// ---------------------------------------------------------------------------
// R9: C[M,N] = (A[M,K] * Bt[N,K]^T + bias) * scale ; out bf16 or fp32
// 128x256 tile, BK=64, 512 threads (8 waves: 2M x 4N, each 64x64 out).
// 3 LDS K-tile buffers (48 KB each), staging runs 2 K-tiles ahead.
// Per K-tile: 2 phases, each {ds_read | stage part of kt+2 | s_barrier |
// lgkmcnt(0) | setprio(1) 16 MFMA setprio(0) | s_barrier}; boundary
// vmcnt(6) (kt+1 landed, kt+2 in flight). Requires K >= 128, K%64==0.
// ---------------------------------------------------------------------------
__global__ __launch_bounds__(512, 2) void gemm_bt256(const u16* __restrict__ A,
                                                     const u16* __restrict__ Bt,
                                                     const float* __restrict__ bias,
                                                     float* __restrict__ Cf,
                                                     u16* __restrict__ Cb,
                                                     int M, int N, int K,
                                                     int out_bf16, float scale) {
  __shared__ __align__(16) u16 Al[3][128 * 64];
  __shared__ __align__(16) u16 Bl[3][256 * 64];
  const int tid = threadIdx.x;
  const int w = tid >> 6, lane = tid & 63;
  const int g = lane >> 4, l15 = lane & 15;
  const int sw = l15 & 7;
  const int mbase = blockIdx.x * 128, nbase = blockIdx.y * 256;
  const int wm = (w & 1) * 64, wn = (w >> 1) * 64;
  const int NT = K >> 6;

  // ---- staging lane constants ----
  // A tile: 128x64 = 1024 chunks, 2 per thread; B tile: 256x64 = 2048, 4/thr.
  const int ca0 = 0 * 512 + tid, ca1 = 1 * 512 + tid;
  const int ra0 = ca0 >> 3, rc0 = ((ca0 & 7) ^ (ra0 & 7)) * 8;
  const int ra1 = ca1 >> 3, rc1 = ((ca1 & 7) ^ (ra1 & 7)) * 8;
  const u16* pa0 = A + (size_t)(mbase + ra0) * K + rc0;
  const u16* pa1 = A + (size_t)(mbase + ra1) * K + rc1;
  const u16* pb[4];
#pragma unroll
  for (int i = 0; i < 4; ++i) {
    int c = i * 512 + tid;
    int row = c >> 3, col = ((c & 7) ^ (row & 7)) * 8;
    pb[i] = Bt + (size_t)(nbase + row) * K + col;
  }
  const int lA0 = (0 * 512 + w * 64) * 8, lA1 = (1 * 512 + w * 64) * 8;
  int lB[4];
#pragma unroll
  for (int i = 0; i < 4; ++i) lB[i] = (i * 512 + w * 64) * 8;

  f32x4 zero4 = {0.f, 0.f, 0.f, 0.f};
  f32x4 acc[4][4];
#pragma unroll
  for (int i = 0; i < 4; ++i)
#pragma unroll
    for (int j = 0; j < 4; ++j) acc[i][j] = zero4;

  // ---- prologue: stage kt0 -> buf0, kt1 -> buf1 ----
  async16(&Al[0][lA0], pa0); async16(&Al[0][lA1], pa1);
#pragma unroll
  for (int i = 0; i < 4; ++i) async16(&Bl[0][lB[i]], pb[i]);
  pa0 += 64; pa1 += 64;
#pragma unroll
  for (int i = 0; i < 4; ++i) pb[i] += 64;
  async16(&Al[1][lA0], pa0); async16(&Al[1][lA1], pa1);
#pragma unroll
  for (int i = 0; i < 4; ++i) async16(&Bl[1][lB[i]], pb[i]);
  pa0 += 64; pa1 += 64;
#pragma unroll
  for (int i = 0; i < 4; ++i) pb[i] += 64;
  asm volatile("s_waitcnt vmcnt(6)" ::: "memory");  // kt0 landed; kt1 in flight
  __builtin_amdgcn_sched_barrier(0);
  __builtin_amdgcn_s_barrier();

  int cb = 0, sb = 2;
  for (int kt = 0; kt < NT; ++kt) {
    const u16* Ap = &Al[cb][0];
    const u16* Bp = &Bl[cb][0];
    const bool st = (kt + 2 < NT);

    // ---- phase 0: acc[0..3][0..1] ----
    short8 af[4][2], bfa[2][2];
#pragma unroll
    for (int mt = 0; mt < 4; ++mt) {
      af[mt][0] = *(const short8*)&Ap[(wm + mt * 16 + l15) * 64 + (g ^ sw) * 8];
      af[mt][1] = *(const short8*)&Ap[(wm + mt * 16 + l15) * 64 + ((4 + g) ^ sw) * 8];
    }
#pragma unroll
    for (int nt = 0; nt < 2; ++nt) {
      bfa[nt][0] = *(const short8*)&Bp[(wn + nt * 16 + l15) * 64 + (g ^ sw) * 8];
      bfa[nt][1] = *(const short8*)&Bp[(wn + nt * 16 + l15) * 64 + ((4 + g) ^ sw) * 8];
    }
    if (st) {
      async16(&Al[sb][lA0], pa0);
      async16(&Al[sb][lA1], pa1);
      async16(&Bl[sb][lB[0]], pb[0]);
      async16(&Bl[sb][lB[1]], pb[1]);
    }
    __builtin_amdgcn_s_barrier();
    asm volatile("s_waitcnt lgkmcnt(0)" ::: "memory");
    __builtin_amdgcn_sched_barrier(0);
    __builtin_amdgcn_s_setprio(1);
#pragma unroll
    for (int ks = 0; ks < 2; ++ks)
#pragma unroll
      for (int mt = 0; mt < 4; ++mt)
#pragma unroll
        for (int nt = 0; nt < 2; ++nt)
          acc[mt][nt] = __builtin_amdgcn_mfma_f32_16x16x32_bf16(af[mt][ks], bfa[nt][ks],
                                                                acc[mt][nt], 0, 0, 0);
    __builtin_amdgcn_s_setprio(0);
    __builtin_amdgcn_s_barrier();

    // ---- phase 1: acc[0..3][2..3] ----
    short8 bfb[2][2];
#pragma unroll
    for (int nt = 0; nt < 2; ++nt) {
      bfb[nt][0] = *(const short8*)&Bp[(wn + (nt + 2) * 16 + l15) * 64 + (g ^ sw) * 8];
      bfb[nt][1] = *(const short8*)&Bp[(wn + (nt + 2) * 16 + l15) * 64 + ((4 + g) ^ sw) * 8];
    }
    if (st) {
      async16(&Bl[sb][lB[2]], pb[2]);
      async16(&Bl[sb][lB[3]], pb[3]);
      pa0 += 64; pa1 += 64;
#pragma unroll
      for (int i = 0; i < 4; ++i) pb[i] += 64;
    }
    __builtin_amdgcn_s_barrier();
    asm volatile("s_waitcnt lgkmcnt(0)" ::: "memory");
    __builtin_amdgcn_sched_barrier(0);
    __builtin_amdgcn_s_setprio(1);
#pragma unroll
    for (int ks = 0; ks < 2; ++ks)
#pragma unroll
      for (int mt = 0; mt < 4; ++mt)
#pragma unroll
        for (int nt = 0; nt < 2; ++nt)
          acc[mt][nt + 2] = __builtin_amdgcn_mfma_f32_16x16x32_bf16(af[mt][ks], bfb[nt][ks],
                                                                    acc[mt][nt + 2], 0, 0, 0);
    __builtin_amdgcn_s_setprio(0);

    // ---- K-tile boundary: ensure kt+1 landed; kt+2 may stay in flight ----
    if (kt < NT - 2) {
      asm volatile("s_waitcnt vmcnt(6)" ::: "memory");
    } else if (kt == NT - 2) {
      asm volatile("s_waitcnt vmcnt(0)" ::: "memory");
    }
    __builtin_amdgcn_sched_barrier(0);
    __builtin_amdgcn_s_barrier();
    cb = (cb == 2) ? 0 : cb + 1;
    sb = (sb == 2) ? 0 : sb + 1;
  }

  // ---- epilogue ----
#pragma unroll
  for (int nt = 0; nt < 4; ++nt) {
    int col = nbase + wn + nt * 16 + l15;
    float bv = bias[col];
#pragma unroll
    for (int mt = 0; mt < 4; ++mt)
#pragma unroll
      for (int r = 0; r < 4; ++r) {
        int row = mbase + wm + mt * 16 + g * 4 + r;
        float v = (acc[mt][nt][r] + bv) * scale;
        if (out_bf16) Cb[(size_t)row * N + col] = f2bf(v);
        else          Cf[(size_t)row * N + col] = v;
      }
  }
}

// ---------------------------------------------------------------------------
// Combined K/V projection: blockIdx.z==0 -> Kp[M,N] = kA*Wk^T + bk (row store)
//                          blockIdx.z==1 -> VT[N,M] = (vA*Wv^T + bv)^T
// (128x128 tile retained: M=4096 would starve a 256-wide grid)
// ---------------------------------------------------------------------------
__global__ __launch_bounds__(256) void gemm_kv(const u16* __restrict__ kA,
                                               const u16* __restrict__ vA,
                                               const u16* __restrict__ Wk,
                                               const u16* __restrict__ Wv,
                                               const float* __restrict__ bk,
                                               const float* __restrict__ bv,
                                               u16* __restrict__ Kp,
                                               u16* __restrict__ VT,
                                               int M, int N, int K) {
  __shared__ __align__(16) u16 Al[128 * 64];
  __shared__ __align__(16) u16 Bl[128 * 64];
  const int ct = blockIdx.z;  // uniform
  const u16* A  = ct ? vA : kA;
  const u16* Bt = ct ? Wv : Wk;
  const float* bias = ct ? bv : bk;
  const int tid = threadIdx.x;
  const int w = tid >> 6, lane = tid & 63;
  const int g = lane >> 4, l15 = lane & 15;
  const int sw = l15 & 7;
  const int mbase = blockIdx.x * 128, nbase = blockIdx.y * 128;
  const int wm = (w & 1) * 64, wn = (w >> 1) * 64;

  f32x4 zero4 = {0.f, 0.f, 0.f, 0.f};
  f32x4 acc[4][4];  // z=0: [mt][nt]; z=1: [nt][mt] (transposed D)
#pragma unroll
  for (int i = 0; i < 4; ++i)
#pragma unroll
    for (int j = 0; j < 4; ++j) acc[i][j] = zero4;

  for (int kb = 0; kb < K; kb += 64) {
#pragma unroll
    for (int i = 0; i < 4; ++i) {
      int cbase = w * 256 + i * 64;
      int c = cbase + lane;
      int row = c >> 3;
      int kc8 = ((c & 7) ^ (row & 7)) * 8;
      async16(&Al[cbase * 8], A + (size_t)(mbase + row) * K + kb + kc8);
      async16(&Bl[cbase * 8], Bt + (size_t)(nbase + row) * K + kb + kc8);
    }
    __syncthreads();
#pragma unroll
    for (int ks = 0; ks < 2; ++ks) {
      short8 af[4], bf[4];
#pragma unroll
      for (int mt = 0; mt < 4; ++mt)
        af[mt] = *(const short8*)&Al[(wm + mt * 16 + l15) * 64 + ((ks * 4 + g) ^ sw) * 8];
#pragma unroll
      for (int nt = 0; nt < 4; ++nt)
        bf[nt] = *(const short8*)&Bl[(wn + nt * 16 + l15) * 64 + ((ks * 4 + g) ^ sw) * 8];
      if (ct) {
#pragma unroll
        for (int nt = 0; nt < 4; ++nt)
#pragma unroll
          for (int mt = 0; mt < 4; ++mt)
            acc[nt][mt] = __builtin_amdgcn_mfma_f32_16x16x32_bf16(bf[nt], af[mt],
                                                                  acc[nt][mt], 0, 0, 0);
      } else {
#pragma unroll
        for (int mt = 0; mt < 4; ++mt)
#pragma unroll
          for (int nt = 0; nt < 4; ++nt)
            acc[mt][nt] = __builtin_amdgcn_mfma_f32_16x16x32_bf16(af[mt], bf[nt],
                                                                  acc[mt][nt], 0, 0, 0);
      }
    }
    __syncthreads();
  }

  if (ct) {
    // D = C^T: lane holds VT[n=nbase+wn+nt*16+g*4+r][m=mbase+wm+mt*16+l15]
#pragma unroll
    for (int mt = 0; mt < 4; ++mt) {
      int m = mbase + wm + mt * 16 + l15;
#pragma unroll
      for (int nt = 0; nt < 4; ++nt)
#pragma unroll
        for (int r = 0; r < 4; ++r) {
          int n = nbase + wn + nt * 16 + g * 4 + r;
          VT[(size_t)n * M + m] = f2bf(acc[nt][mt][r] + bias[n]);
        }
    }
  } else {
#pragma unroll
    for (int nt = 0; nt < 4; ++nt) {
      int col = nbase + wn + nt * 16 + l15;
      float bvv = bias[col];
#pragma unroll
      for (int mt = 0; mt < 4; ++mt)
#pragma unroll
        for (int r = 0; r < 4; ++r) {
          int row = mbase + wm + mt * 16 + g * 4 + r;
          Kp[(size_t)row * N + col] = f2bf(acc[mt][nt][r] + bvv);
        }
    }
  }
}

// ---------------------------------------------------------------------------
// Fused flash attention, S^T/O^T orientation, no-max softmax, MFMA row-sum.
// Grid: (Nq/128, B*H). 256 thr = 4 waves; wave owns 32 q-rows (2 subtiles).
// Pipeline per iteration kc: [stage K(kc+1) then V(kc+1)] [ds_read pb(kc-1),
// vf(kc-1), kf(kc)] [MFMA: QK^T(kc) ++ PV(kc-1)] [exp(kc)->P_lds]
// [s_waitcnt vmcnt(2); s_barrier]. Post-loop vmcnt(0)+barrier for final PV.
// ---------------------------------------------------------------------------
__global__ __launch_bounds__(256, 2) void attn_kernel(const u16* __restrict__ Qp,
                                                      const u16* __restrict__ Kp,
                                                      const u16* __restrict__ VT,
                                                      u16* __restrict__ AO) {
  __shared__ __align__(16) u16 K_lds[2][64 * 64];     // [buf][kcol][d] swizzled
  __shared__ __align__(16) u16 V_lds[3][64 * 64];     // [buf][d][kcol] swizzled
  __shared__ __align__(16) u16 P_lds[4][32 * 64];     // per-wave [qrow][kcol] swz

  const int tid = threadIdx.x;
  const int w = tid >> 6, lane = tid & 63;
  const int g = lane >> 4, l15 = lane & 15;
  const int sw = l15 & 7;
  const int bh = blockIdx.y, b = bh >> 4, h = bh & 15;
  const int qrow0 = blockIdx.x * 128 + w * 32;
  const int MT = B_SZ * NK;  // VT leading dim

  // ---- staging lane constants (two 64-chunk regions per wave) ----
  const int cbase0 = (w * 2 + 0) * 64;
  const int cbase1 = (w * 2 + 1) * 64;
  const int c0 = cbase0 + lane, c1 = cbase1 + lane;
  const int row0 = c0 >> 3, kc80 = ((c0 & 7) ^ (row0 & 7)) * 8;
  const int row1 = c1 >> 3, kc81 = ((c1 & 7) ^ (row1 & 7)) * 8;

  // incremental per-lane global source pointers
  const u16* kp0 = Kp + (size_t)(b * NK + row0) * QDIM + h * HD + kc80;
  const u16* kp1 = Kp + (size_t)(b * NK + row1) * QDIM + h * HD + kc81;
  const u16* vp0 = VT + (size_t)(h * HD + row0) * MT + b * NK + kc80;
  const u16* vp1 = VT + (size_t)(h * HD + row1) * MT + b * NK + kc81;

  // ---- compute lane constants ----
  const int rb = l15 * 64;                      // fragment row base (elements)
  const int cs0 = (g ^ sw) * 8;                 // ks=0 chunk select
  const int cs1 = ((4 + g) ^ sw) * 8;           // ks=1 chunk select
  // P-store: addr = qt*1024 + pwb + ((mt*2)^pms)*8
  const int pwb = rb + (((g >> 1) ^ (sw & 1)) * 8) + (g & 1) * 4;
  const int pms = sw & 6;

  // ones A-fragment (bf16 1.0 in every slot) for the MFMA row-sum
  short8 ones8;
#pragma unroll
  for (int j = 0; j < 8; ++j) ones8[j] = (short)0x3F80;

  // Q fragments (B-operand role): lane holds Q[qrow=qt*16+l15][d=ks*32+g*8+j]
  short8 qf[2][2];
#pragma unroll
  for (int qt = 0; qt < 2; ++qt)
#pragma unroll
    for (int ks = 0; ks < 2; ++ks) {
      size_t row = (size_t)(b * NQ + qrow0 + qt * 16 + l15);
      qf[qt][ks] = *(const short8*)(Qp + row * QDIM + h * HD + ks * 32 + g * 8);
    }

  f32x4 zero4 = {0.f, 0.f, 0.f, 0.f};
  f32x4 o4[4][2];              // O^T frags: [dt][qt], r-index = d
  f32x4 lacc[2];               // row-sum via mfma(ones, P): col=qrow, rows dup
#pragma unroll
  for (int dt = 0; dt < 4; ++dt)
#pragma unroll
    for (int qt = 0; qt < 2; ++qt) o4[dt][qt] = zero4;
  lacc[0] = zero4; lacc[1] = zero4;

  u16* Pl = &P_lds[w][0];

  // ---- prologue: stage tile 0 (K0,V0), then tile 1 (K1,V1) ----
  async16(&K_lds[0][cbase0 * 8], kp0);
  async16(&K_lds[0][cbase1 * 8], kp1);
  async16(&V_lds[0][cbase0 * 8], vp0);
  async16(&V_lds[0][cbase1 * 8], vp1);
  kp0 += 64 * QDIM; kp1 += 64 * QDIM; vp0 += 64; vp1 += 64;
  __syncthreads();  // tile 0 resident (full drain; prologue only)

  async16(&K_lds[1][cbase0 * 8], kp0);
  async16(&K_lds[1][cbase1 * 8], kp1);
  async16(&V_lds[1][cbase0 * 8], vp0);
  async16(&V_lds[1][cbase1 * 8], vp1);
  kp0 += 64 * QDIM; kp1 += 64 * QDIM; vp0 += 64; vp1 += 64;

  // QK^T(0) + exp -> P(0)
  {
    const u16* Kl = &K_lds[0][0];
    f32x4 sc[4][2];
    short8 kf0[4], kf1[4];
#pragma unroll
    for (int mt = 0; mt < 4; ++mt) {
      kf0[mt] = *(const short8*)&Kl[mt * 1024 + rb + cs0];
      kf1[mt] = *(const short8*)&Kl[mt * 1024 + rb + cs1];
    }
    __builtin_amdgcn_s_setprio(1);
#pragma unroll
    for (int mt = 0; mt < 4; ++mt)
#pragma unroll
      for (int qt = 0; qt < 2; ++qt)
        sc[mt][qt] = __builtin_amdgcn_mfma_f32_16x16x32_bf16(kf0[mt], qf[qt][0],
                                                             zero4, 0, 0, 0);
#pragma unroll
    for (int mt = 0; mt < 4; ++mt)
#pragma unroll
      for (int qt = 0; qt < 2; ++qt)
        sc[mt][qt] = __builtin_amdgcn_mfma_f32_16x16x32_bf16(kf1[mt], qf[qt][1],
                                                             sc[mt][qt], 0, 0, 0);
    __builtin_amdgcn_s_setprio(0);
#pragma unroll
    for (int qt = 0; qt < 2; ++qt)
#pragma unroll
      for (int mt = 0; mt < 4; ++mt) {
        float p0 = fexp2(sc[mt][qt][0]);
        float p1 = fexp2(sc[mt][qt][1]);
        float p2 = fexp2(sc[mt][qt][2]);
        float p3 = fexp2(sc[mt][qt][3]);
        uint2 pk = {pk2(p0, p1), pk2(p2, p3)};
        *(uint2*)&Pl[qt * 1024 + pwb + ((mt * 2) ^ pms) * 8] = pk;
      }
  }
  __syncthreads();  // tile 1 resident (full drain; prologue only)

  // ---- main loop: QK^T(kc) ++ PV(kc-1), then exp(kc) ----
  for (int kc = 1; kc < NK / 64; ++kc) {
    const int pv = (kc - 1) % 3;          // V slot of tile kc-1
    // stage tile kc+1: K first, V second (vmcnt(2) leaves only V in flight)
    if (kc + 1 < NK / 64) {
      const int nk = (kc + 1) & 1, nv = (kc + 1) % 3;
      async16(&K_lds[nk][cbase0 * 8], kp0);
      async16(&K_lds[nk][cbase1 * 8], kp1);
      async16(&V_lds[nv][cbase0 * 8], vp0);
      async16(&V_lds[nv][cbase1 * 8], vp1);
      kp0 += 64 * QDIM; kp1 += 64 * QDIM; vp0 += 64; vp1 += 64;
    }
    const u16* Kl = &K_lds[kc & 1][0];
    const u16* Vl = &V_lds[pv][0];

    // hoisted fragment loads: pb/vf feed PV(kc-1), kf feeds QK^T(kc)
    short8 pb[2][2], vf[2][4], kf[2][4];
#pragma unroll
    for (int qt = 0; qt < 2; ++qt) {
      pb[0][qt] = *(const short8*)&Pl[qt * 1024 + rb + cs0];
      pb[1][qt] = *(const short8*)&Pl[qt * 1024 + rb + cs1];
    }
#pragma unroll
    for (int dt = 0; dt < 4; ++dt) {
      vf[0][dt] = *(const short8*)&Vl[dt * 1024 + rb + cs0];
      vf[1][dt] = *(const short8*)&Vl[dt * 1024 + rb + cs1];
    }
#pragma unroll
    for (int mt = 0; mt < 4; ++mt) {
      kf[0][mt] = *(const short8*)&Kl[mt * 1024 + rb + cs0];
      kf[1][mt] = *(const short8*)&Kl[mt * 1024 + rb + cs1];
    }

    // merged MFMA cluster: QK^T(kc) and PV(kc-1) are independent
    f32x4 sc[4][2];
    __builtin_amdgcn_s_setprio(1);
#pragma unroll
    for (int mt = 0; mt < 4; ++mt)
#pragma unroll
      for (int qt = 0; qt < 2; ++qt)
        sc[mt][qt] = __builtin_amdgcn_mfma_f32_16x16x32_bf16(kf[0][mt], qf[qt][0],
                                                             zero4, 0, 0, 0);
#pragma unroll
    for (int qt = 0; qt < 2; ++qt)
      lacc[qt] = __builtin_amdgcn_mfma_f32_16x16x32_bf16(ones8, pb[0][qt],
                                                         lacc[qt], 0, 0, 0);
#pragma unroll
    for (int dt = 0; dt < 4; ++dt)
#pragma unroll
      for (int qt = 0; qt < 2; ++qt)
        o4[dt][qt] = __builtin_amdgcn_mfma_f32_16x16x32_bf16(vf[0][dt], pb[0][qt],
                                                             o4[dt][qt], 0, 0, 0);
#pragma unroll
    for (int mt = 0; mt < 4; ++mt)
#pragma unroll
      for (int qt = 0; qt < 2; ++qt)
        sc[mt][qt] = __builtin_amdgcn_mfma_f32_16x16x32_bf16(kf[1][mt], qf[qt][1],
                                                             sc[mt][qt], 0, 0, 0);
#pragma unroll
    for (int qt = 0; qt < 2; ++qt)
      lacc[qt] = __builtin_amdgcn_mfma_f32_16x16x32_bf16(ones8, pb[1][qt],
                                                         lacc[qt], 0, 0, 0);
#pragma unroll
    for (int dt = 0; dt < 4; ++dt)
#pragma unroll
      for (int qt = 0; qt < 2; ++qt)
        o4[dt][qt] = __builtin_amdgcn_mfma_f32_16x16x32_bf16(vf[1][dt], pb[1][qt],
                                                             o4[dt][qt], 0, 0, 0);
    __builtin_amdgcn_s_setprio(0);

    // exp(kc) -> P_lds (overwrites P(kc-1); same-wave DS in-order vs pb reads)
#pragma unroll
    for (int qt = 0; qt < 2; ++qt)
#pragma unroll
      for (int mt = 0; mt < 4; ++mt) {
        float p0 = fexp2(sc[mt][qt][0]);
        float p1 = fexp2(sc[mt][qt][1]);
        float p2 = fexp2(sc[mt][qt][2]);
        float p3 = fexp2(sc[mt][qt][3]);
        uint2 pk = {pk2(p0, p1), pk2(p2, p3)};
        *(uint2*)&Pl[qt * 1024 + pwb + ((mt * 2) ^ pms) * 8] = pk;
      }

    // counted barrier: wait K(kc+1) (all but 2 newest loads), let V(kc+1)
    // stay in flight - it is not read until iteration kc+2 (deferred PV).
    asm volatile("s_waitcnt vmcnt(2)" ::: "memory");
    __builtin_amdgcn_sched_barrier(0);
    __builtin_amdgcn_s_barrier();
  }

  // drain remaining staged loads (V of the last tile) before final PV
  asm volatile("s_waitcnt vmcnt(0)" ::: "memory");
  __builtin_amdgcn_sched_barrier(0);
  __builtin_amdgcn_s_barrier();

  // ---- epilogue: PV for the last tile (15), V slot 15%3 = 0 ----
  {
    const u16* Vl = &V_lds[(NK / 64 - 1) % 3][0];
    short8 pb[2][2], vf[2][4];
#pragma unroll
    for (int qt = 0; qt < 2; ++qt) {
      pb[0][qt] = *(const short8*)&Pl[qt * 1024 + rb + cs0];
      pb[1][qt] = *(const short8*)&Pl[qt * 1024 + rb + cs1];
    }
#pragma unroll
    for (int dt = 0; dt < 4; ++dt) {
      vf[0][dt] = *(const short8*)&Vl[dt * 1024 + rb + cs0];
      vf[1][dt] = *(const short8*)&Vl[dt * 1024 + rb + cs1];
    }
    __builtin_amdgcn_s_setprio(1);
#pragma unroll
    for (int ks = 0; ks < 2; ++ks) {
#pragma unroll
      for (int qt = 0; qt < 2; ++qt)
        lacc[qt] = __builtin_amdgcn_mfma_f32_16x16x32_bf16(ones8, pb[ks][qt],
                                                           lacc[qt], 0, 0, 0);
#pragma unroll
      for (int dt = 0; dt < 4; ++dt)
#pragma unroll
        for (int qt = 0; qt < 2; ++qt)
          o4[dt][qt] = __builtin_amdgcn_mfma_f32_16x16x32_bf16(vf[ks][dt], pb[ks][qt],
                                                               o4[dt][qt], 0, 0, 0);
    }
    __builtin_amdgcn_s_setprio(0);
  }

  // epilogue: lacc[qt][r] all hold the full row-sum for qrow=qt*16+l15
#pragma unroll
  for (int qt = 0; qt < 2; ++qt) {
    float inv = __builtin_amdgcn_rcpf(lacc[qt][0]);
    size_t row = (size_t)(b * NQ + qrow0 + qt * 16 + l15);
#pragma unroll
    for (int dt = 0; dt < 4; ++dt) {
      uint2 pk = {pk2(o4[dt][qt][0] * inv, o4[dt][qt][1] * inv),
                  pk2(o4[dt][qt][2] * inv, o4[dt][qt][3] * inv)};
      *(uint2*)(AO + row * QDIM + h * HD + dt * 16 + g * 4) = pk;
    }
  }
}

// ---------------------------------------------------------------------------
extern "C" void kernel_launch(void* const* d_in, const int* in_sizes, int n_in,
                              void* d_out, int out_size, void* d_ws, size_t ws_size,
                              hipStream_t stream) {
  const float* query = (const float*)d_in[0];
  const float* key   = (const float*)d_in[1];
  const float* value = (const float*)d_in[2];
  const float* Wq = (const float*)d_in[3];
  const float* bq = (const float*)d_in[4];
  const float* Wk = (const float*)d_in[5];
  const float* bk = (const float*)d_in[6];
  const float* Wv = (const float*)d_in[7];
  const float* bv = (const float*)d_in[8];
  const float* Wo = (const float*)d_in[9];
  const float* bo = (const float*)d_in[10];

  char* ws = (char*)d_ws;
  size_t off = 0;
  auto alloc = [&](size_t bytes) -> void* {
    void* p = ws + off;
    off += (bytes + 255) & ~(size_t)255;
    return p;
  };
  const size_t NQTOT = (size_t)B_SZ * NQ;        // 16384
  const size_t NKTOT = (size_t)B_SZ * NK;        // 4096
  u16* qbf = (u16*)alloc(NQTOT * QDIM * 2);      // query bf16; reused as AO later
  u16* kbf = (u16*)alloc(NKTOT * KDIM * 2);
  u16* vbf = (u16*)alloc(NKTOT * KDIM * 2);
  u16* wqt = (u16*)alloc((size_t)QDIM * QDIM * 2);
  u16* wkt = (u16*)alloc((size_t)KDIM * QDIM * 2);
  u16* wvt = (u16*)alloc((size_t)KDIM * QDIM * 2);
  u16* wot = (u16*)alloc((size_t)QDIM * QDIM * 2);
  u16* Qp  = (u16*)alloc(NQTOT * QDIM * 2);
  u16* Kp  = (u16*)alloc(NKTOT * QDIM * 2);
  u16* VT  = (u16*)alloc((size_t)QDIM * NKTOT * 2);  // (1024, B*NK) transposed V-proj
  u16* AO  = qbf;  // qbf dead after Q-projection

  // 1) dtype conversions (query alone; key+value merged into one launch)
  {
    int n4 = (int)(NQTOT * QDIM / 4);
    f32_to_bf16_k<<<(n4 + 255) / 256, 256, 0, stream>>>(query, qbf, n4);
  }
  {
    int n4 = (int)(NKTOT * KDIM / 4);
    f32_to_bf16_2k<<<dim3((n4 + 255) / 256, 2), 256, 0, stream>>>(key, value, kbf,
                                                                  vbf, n4);
  }
  // 2) weight transposes (K x N -> N x K bf16)
  transpose_bf16_k<<<dim3(QDIM / 32, QDIM / 32), 256, 0, stream>>>(Wq, wqt, QDIM, QDIM);
  transpose_bf16_k<<<dim3(QDIM / 32, KDIM / 32), 256, 0, stream>>>(Wk, wkt, KDIM, QDIM);
  transpose_bf16_k<<<dim3(QDIM / 32, KDIM / 32), 256, 0, stream>>>(Wv, wvt, KDIM, QDIM);
  transpose_bf16_k<<<dim3(QDIM / 32, QDIM / 32), 256, 0, stream>>>(Wo, wot, QDIM, QDIM);

  // 3) projections: Q scaled by QSCALE (softmax exp2-domain fold); K+V fused
  gemm_bt256<<<dim3(NQTOT / 128, QDIM / 256), 512, 0, stream>>>(
      qbf, wqt, bq, nullptr, Qp, (int)NQTOT, QDIM, QDIM, 1, QSCALE);
  gemm_kv<<<dim3(NKTOT / 128, QDIM / 128, 2), 256, 0, stream>>>(
      kbf, vbf, wkt, wvt, bk, bv, Kp, VT, (int)NKTOT, QDIM, KDIM);

  // 4) fused attention -> AO (bf16, (B*Nq, 1024))
  attn_kernel<<<dim3(NQ / 128, B_SZ * NH), 256, 0, stream>>>(Qp, Kp, VT, AO);

  // 5) output projection (fp32 out)
  gemm_bt256<<<dim3(NQTOT / 128, QDIM / 256), 512, 0, stream>>>(
      AO, wot, bo, (float*)d_out, nullptr, (int)NQTOT, QDIM, QDIM, 0, 1.0f);

  (void)in_sizes; (void)n_in; (void)out_size; (void)ws_size;
}

// Round 6
// 392.084 us; speedup vs baseline: 1.0987x; 1.0595x over previous
//
#include <hip/hip_runtime.h>
#include <hip/hip_bf16.h>
#include <stdint.h>

// ---------------------------------------------------------------------------
// CrossAttention: out = softmax((X Wq)(K Wk)^T * s) (V Wv) Wo  (+biases)
// B=4, Nq=4096, Nk=1024, QUERY_DIM=1024, KEY_DIM=768, H=16, HD=64
// R10: (a) T1 XCD-chunked swizzle on gemm_bt256 and gemm_kv: N-panel index
//      fastest within each XCD's contiguous chunk -> each A row-block is
//      fetched once per XCD and reused across all N-panels from L2
//      (A-refetch ~128MB -> ~32MB per big GEMM).
//      (b) Launch fusion: 3 conversions -> 1 kernel, 4 transposes -> 1
//      kernel; 10 -> 6 dispatches.
// Carried: R9 3-buffer counted-vmcnt 128x256 GEMM pipeline, deferred-PV
//      attn (R8), raw v_exp_f32, XOR-swizzled LDS, no-max exp2 softmax,
//      MFMA row-sum, fused K/V projection.
// ---------------------------------------------------------------------------

typedef unsigned short u16;
typedef __attribute__((ext_vector_type(8))) short short8;   // 8 bf16 = 4 VGPRs
typedef __attribute__((ext_vector_type(4))) float f32x4;    // MFMA C/D frag

#define B_SZ 4
#define NQ   4096
#define NK   1024
#define QDIM 1024
#define KDIM 768
#define NH   16
#define HD   64
// scale * log2(e): softmax computed in exp2 domain (folded into Q projection)
#define QSCALE (0.125f * 1.44269504f)

__device__ __forceinline__ u16 f2bf(float f) {
  union { float f; uint32_t u; } v; v.f = f;
  uint32_t u = v.u;
  return (u16)((u + 0x7FFFu + ((u >> 16) & 1u)) >> 16);  // RNE
}

// packed f32x2 -> bf16x2 (v_cvt_pk_bf16_f32 on gfx950)
__device__ __forceinline__ uint32_t pk2(float a, float b) {
  union { __hip_bfloat162 h; uint32_t u; } cv;
  cv.h = __float22bfloat162_rn(float2{a, b});
  return cv.u;
}

// raw v_exp_f32 (no denormal-guard expansion; underflow flushes to 0 - fine
// for softmax numerator)
__device__ __forceinline__ float fexp2(float x) {
  return __builtin_amdgcn_exp2f(x);
}

// global -> LDS async copy, 16B per lane; lds base must be wave-uniform.
__device__ __forceinline__ void async16(u16* lds, const u16* g) {
  __builtin_amdgcn_global_load_lds(
      (__attribute__((address_space(1))) void*)(g),
      (__attribute__((address_space(3))) void*)(lds), 16, 0, 0);
}

// ---------------------------------------------------------------------------
// fused fp32 -> bf16 for query/key/value (range-partitioned single launch)
// ---------------------------------------------------------------------------
__global__ __launch_bounds__(256) void f32_to_bf16_all(const float* __restrict__ q,
                                                       const float* __restrict__ k,
                                                       const float* __restrict__ v,
                                                       u16* __restrict__ oq,
                                                       u16* __restrict__ ok,
                                                       u16* __restrict__ ov,
                                                       int n4q, int n4kv) {
  int i = blockIdx.x * 256 + threadIdx.x;
  const float* in; u16* out; int idx;
  if (i < n4q) { in = q; out = oq; idx = i; }
  else if (i < n4q + n4kv) { in = k; out = ok; idx = i - n4q; }
  else if (i < n4q + 2 * n4kv) { in = v; out = ov; idx = i - n4q - n4kv; }
  else return;
  f32x4 vv = ((const f32x4*)in)[idx];
  uint2 o = {pk2(vv.x, vv.y), pk2(vv.z, vv.w)};
  ((uint2*)out)[idx] = o;
}

// ---------------------------------------------------------------------------
// fused weight transposes: z selects {Wq, Wk, Wv, Wo}; K in {1024,768,768,1024}
// W (K x N fp32, row-major) -> Wt (N x K bf16, row-major)   [LDS-tiled]
// ---------------------------------------------------------------------------
__global__ __launch_bounds__(256) void transpose4_k(const float* __restrict__ W0,
                                                    const float* __restrict__ W1,
                                                    const float* __restrict__ W2,
                                                    const float* __restrict__ W3,
                                                    u16* __restrict__ T0,
                                                    u16* __restrict__ T1,
                                                    u16* __restrict__ T2,
                                                    u16* __restrict__ T3) {
  const int z = blockIdx.z;
  const float* W = (z == 0) ? W0 : (z == 1) ? W1 : (z == 2) ? W2 : W3;
  u16* T = (z == 0) ? T0 : (z == 1) ? T1 : (z == 2) ? T2 : T3;
  const int K = (z == 1 || z == 2) ? KDIM : QDIM;
  const int N = QDIM;
  int nb = blockIdx.x * 32, kb = blockIdx.y * 32;
  if (kb >= K) return;  // block-uniform exit (before barrier)
  __shared__ float t[32][33];
  int tx = threadIdx.x & 31, ty = threadIdx.x >> 5;  // 32 x 8
#pragma unroll
  for (int i = 0; i < 4; ++i)
    t[ty + i * 8][tx] = W[(size_t)(kb + ty + i * 8) * N + nb + tx];
  __syncthreads();
#pragma unroll
  for (int i = 0; i < 4; ++i)
    T[(size_t)(nb + ty + i * 8) * K + kb + tx] = f2bf(t[tx][ty + i * 8]);
}

// ---------------------------------------------------------------------------
// C[M,N] = (A[M,K] * Bt[N,K]^T + bias) * scale ; out bf16 or fp32
// 128x256 tile, BK=64, 512 threads (8 waves: 2M x 4N, each 64x64 out).
// 3 LDS K-tile buffers, staging 2 K-tiles ahead, counted vmcnt(6).
// R10: 1D grid + XCD-chunked swizzle; N-panel fastest in work decode so
// each XCD reuses one A row-block across all N/256 panels via its L2.
// Requires gridDim.x % 8 == 0, K >= 128, K%64==0.
// ---------------------------------------------------------------------------
__global__ __launch_bounds__(512, 2) void gemm_bt256(const u16* __restrict__ A,
                                                     const u16* __restrict__ Bt,
                                                     const float* __restrict__ bias,
                                                     float* __restrict__ Cf,
                                                     u16* __restrict__ Cb,
                                                     int M, int N, int K,
                                                     int out_bf16, float scale) {
  __shared__ __align__(16) u16 Al[3][128 * 64];
  __shared__ __align__(16) u16 Bl[3][256 * 64];
  const int tid = threadIdx.x;
  const int w = tid >> 6, lane = tid & 63;
  const int g = lane >> 4, l15 = lane & 15;
  const int sw = l15 & 7;
  // XCD-chunked swizzle (T1): hw XCD = bid%8; give each XCD a contiguous
  // work chunk; within a chunk the N-panel index varies fastest.
  const int bid = blockIdx.x;
  const int cpx = gridDim.x >> 3;
  const int swz = (bid & 7) * cpx + (bid >> 3);
  const int nby = N >> 8;
  const int mbase = (swz / nby) * 128, nbase = (swz % nby) * 256;
  const int wm = (w & 1) * 64, wn = (w >> 1) * 64;
  const int NT = K >> 6;

  // ---- staging lane constants ----
  const int ca0 = 0 * 512 + tid, ca1 = 1 * 512 + tid;
  const int ra0 = ca0 >> 3, rc0 = ((ca0 & 7) ^ (ra0 & 7)) * 8;
  const int ra1 = ca1 >> 3, rc1 = ((ca1 & 7) ^ (ra1 & 7)) * 8;
  const u16* pa0 = A + (size_t)(mbase + ra0) * K + rc0;
  const u16* pa1 = A + (size_t)(mbase + ra1) * K + rc1;
  const u16* pb[4];
#pragma unroll
  for (int i = 0; i < 4; ++i) {
    int c = i * 512 + tid;
    int row = c >> 3, col = ((c & 7) ^ (row & 7)) * 8;
    pb[i] = Bt + (size_t)(nbase + row) * K + col;
  }
  const int lA0 = (0 * 512 + w * 64) * 8, lA1 = (1 * 512 + w * 64) * 8;
  int lB[4];
#pragma unroll
  for (int i = 0; i < 4; ++i) lB[i] = (i * 512 + w * 64) * 8;

  f32x4 zero4 = {0.f, 0.f, 0.f, 0.f};
  f32x4 acc[4][4];
#pragma unroll
  for (int i = 0; i < 4; ++i)
#pragma unroll
    for (int j = 0; j < 4; ++j) acc[i][j] = zero4;

  // ---- prologue: stage kt0 -> buf0, kt1 -> buf1 ----
  async16(&Al[0][lA0], pa0); async16(&Al[0][lA1], pa1);
#pragma unroll
  for (int i = 0; i < 4; ++i) async16(&Bl[0][lB[i]], pb[i]);
  pa0 += 64; pa1 += 64;
#pragma unroll
  for (int i = 0; i < 4; ++i) pb[i] += 64;
  async16(&Al[1][lA0], pa0); async16(&Al[1][lA1], pa1);
#pragma unroll
  for (int i = 0; i < 4; ++i) async16(&Bl[1][lB[i]], pb[i]);
  pa0 += 64; pa1 += 64;
#pragma unroll
  for (int i = 0; i < 4; ++i) pb[i] += 64;
  asm volatile("s_waitcnt vmcnt(6)" ::: "memory");  // kt0 landed; kt1 in flight
  __builtin_amdgcn_sched_barrier(0);
  __builtin_amdgcn_s_barrier();

  int cb = 0, sb = 2;
  for (int kt = 0; kt < NT; ++kt) {
    const u16* Ap = &Al[cb][0];
    const u16* Bp = &Bl[cb][0];
    const bool st = (kt + 2 < NT);

    // ---- phase 0: acc[0..3][0..1] ----
    short8 af[4][2], bfa[2][2];
#pragma unroll
    for (int mt = 0; mt < 4; ++mt) {
      af[mt][0] = *(const short8*)&Ap[(wm + mt * 16 + l15) * 64 + (g ^ sw) * 8];
      af[mt][1] = *(const short8*)&Ap[(wm + mt * 16 + l15) * 64 + ((4 + g) ^ sw) * 8];
    }
#pragma unroll
    for (int nt = 0; nt < 2; ++nt) {
      bfa[nt][0] = *(const short8*)&Bp[(wn + nt * 16 + l15) * 64 + (g ^ sw) * 8];
      bfa[nt][1] = *(const short8*)&Bp[(wn + nt * 16 + l15) * 64 + ((4 + g) ^ sw) * 8];
    }
    if (st) {
      async16(&Al[sb][lA0], pa0);
      async16(&Al[sb][lA1], pa1);
      async16(&Bl[sb][lB[0]], pb[0]);
      async16(&Bl[sb][lB[1]], pb[1]);
    }
    __builtin_amdgcn_s_barrier();
    asm volatile("s_waitcnt lgkmcnt(0)" ::: "memory");
    __builtin_amdgcn_sched_barrier(0);
    __builtin_amdgcn_s_setprio(1);
#pragma unroll
    for (int ks = 0; ks < 2; ++ks)
#pragma unroll
      for (int mt = 0; mt < 4; ++mt)
#pragma unroll
        for (int nt = 0; nt < 2; ++nt)
          acc[mt][nt] = __builtin_amdgcn_mfma_f32_16x16x32_bf16(af[mt][ks], bfa[nt][ks],
                                                                acc[mt][nt], 0, 0, 0);
    __builtin_amdgcn_s_setprio(0);
    __builtin_amdgcn_s_barrier();

    // ---- phase 1: acc[0..3][2..3] ----
    short8 bfb[2][2];
#pragma unroll
    for (int nt = 0; nt < 2; ++nt) {
      bfb[nt][0] = *(const short8*)&Bp[(wn + (nt + 2) * 16 + l15) * 64 + (g ^ sw) * 8];
      bfb[nt][1] = *(const short8*)&Bp[(wn + (nt + 2) * 16 + l15) * 64 + ((4 + g) ^ sw) * 8];
    }
    if (st) {
      async16(&Bl[sb][lB[2]], pb[2]);
      async16(&Bl[sb][lB[3]], pb[3]);
      pa0 += 64; pa1 += 64;
#pragma unroll
      for (int i = 0; i < 4; ++i) pb[i] += 64;
    }
    __builtin_amdgcn_s_barrier();
    asm volatile("s_waitcnt lgkmcnt(0)" ::: "memory");
    __builtin_amdgcn_sched_barrier(0);
    __builtin_amdgcn_s_setprio(1);
#pragma unroll
    for (int ks = 0; ks < 2; ++ks)
#pragma unroll
      for (int mt = 0; mt < 4; ++mt)
#pragma unroll
        for (int nt = 0; nt < 2; ++nt)
          acc[mt][nt + 2] = __builtin_amdgcn_mfma_f32_16x16x32_bf16(af[mt][ks], bfb[nt][ks],
                                                                    acc[mt][nt + 2], 0, 0, 0);
    __builtin_amdgcn_s_setprio(0);

    // ---- K-tile boundary: ensure kt+1 landed; kt+2 may stay in flight ----
    if (kt < NT - 2) {
      asm volatile("s_waitcnt vmcnt(6)" ::: "memory");
    } else if (kt == NT - 2) {
      asm volatile("s_waitcnt vmcnt(0)" ::: "memory");
    }
    __builtin_amdgcn_sched_barrier(0);
    __builtin_amdgcn_s_barrier();
    cb = (cb == 2) ? 0 : cb + 1;
    sb = (sb == 2) ? 0 : sb + 1;
  }

  // ---- epilogue ----
#pragma unroll
  for (int nt = 0; nt < 4; ++nt) {
    int col = nbase + wn + nt * 16 + l15;
    float bv = bias[col];
#pragma unroll
    for (int mt = 0; mt < 4; ++mt)
#pragma unroll
      for (int r = 0; r < 4; ++r) {
        int row = mbase + wm + mt * 16 + g * 4 + r;
        float v = (acc[mt][nt][r] + bv) * scale;
        if (out_bf16) Cb[(size_t)row * N + col] = f2bf(v);
        else          Cf[(size_t)row * N + col] = v;
      }
  }
}

// ---------------------------------------------------------------------------
// Combined K/V projection, 1D grid + XCD-chunked swizzle.
// work id: ct = swz>>8, xw = swz&31 (M block), yw = (swz>>5)&7 (N block).
// ct==0 -> Kp[M,N] = kA*Wk^T + bk (row store)
// ct==1 -> VT[N,M] = (vA*Wv^T + bv)^T
// ---------------------------------------------------------------------------
__global__ __launch_bounds__(256) void gemm_kv(const u16* __restrict__ kA,
                                               const u16* __restrict__ vA,
                                               const u16* __restrict__ Wk,
                                               const u16* __restrict__ Wv,
                                               const float* __restrict__ bk,
                                               const float* __restrict__ bv,
                                               u16* __restrict__ Kp,
                                               u16* __restrict__ VT,
                                               int M, int N, int K) {
  __shared__ __align__(16) u16 Al[128 * 64];
  __shared__ __align__(16) u16 Bl[128 * 64];
  const int bid = blockIdx.x;                     // 512 blocks
  const int swz = (bid & 7) * 64 + (bid >> 3);    // XCD-chunked
  const int ct = swz >> 8;                        // uniform
  const int mbase = (swz & 31) * 128, nbase = ((swz >> 5) & 7) * 128;
  const u16* A  = ct ? vA : kA;
  const u16* Bt = ct ? Wv : Wk;
  const float* bias = ct ? bv : bk;
  const int tid = threadIdx.x;
  const int w = tid >> 6, lane = tid & 63;
  const int g = lane >> 4, l15 = lane & 15;
  const int sw = l15 & 7;
  const int wm = (w & 1) * 64, wn = (w >> 1) * 64;

  f32x4 zero4 = {0.f, 0.f, 0.f, 0.f};
  f32x4 acc[4][4];  // ct=0: [mt][nt]; ct=1: [nt][mt] (transposed D)
#pragma unroll
  for (int i = 0; i < 4; ++i)
#pragma unroll
    for (int j = 0; j < 4; ++j) acc[i][j] = zero4;

  for (int kb = 0; kb < K; kb += 64) {
#pragma unroll
    for (int i = 0; i < 4; ++i) {
      int cbase = w * 256 + i * 64;
      int c = cbase + lane;
      int row = c >> 3;
      int kc8 = ((c & 7) ^ (row & 7)) * 8;
      async16(&Al[cbase * 8], A + (size_t)(mbase + row) * K + kb + kc8);
      async16(&Bl[cbase * 8], Bt + (size_t)(nbase + row) * K + kb + kc8);
    }
    __syncthreads();
#pragma unroll
    for (int ks = 0; ks < 2; ++ks) {
      short8 af[4], bf[4];
#pragma unroll
      for (int mt = 0; mt < 4; ++mt)
        af[mt] = *(const short8*)&Al[(wm + mt * 16 + l15) * 64 + ((ks * 4 + g) ^ sw) * 8];
#pragma unroll
      for (int nt = 0; nt < 4; ++nt)
        bf[nt] = *(const short8*)&Bl[(wn + nt * 16 + l15) * 64 + ((ks * 4 + g) ^ sw) * 8];
      if (ct) {
#pragma unroll
        for (int nt = 0; nt < 4; ++nt)
#pragma unroll
          for (int mt = 0; mt < 4; ++mt)
            acc[nt][mt] = __builtin_amdgcn_mfma_f32_16x16x32_bf16(bf[nt], af[mt],
                                                                  acc[nt][mt], 0, 0, 0);
      } else {
#pragma unroll
        for (int mt = 0; mt < 4; ++mt)
#pragma unroll
          for (int nt = 0; nt < 4; ++nt)
            acc[mt][nt] = __builtin_amdgcn_mfma_f32_16x16x32_bf16(af[mt], bf[nt],
                                                                  acc[mt][nt], 0, 0, 0);
      }
    }
    __syncthreads();
  }

  if (ct) {
    // D = C^T: lane holds VT[n=nbase+wn+nt*16+g*4+r][m=mbase+wm+mt*16+l15]
#pragma unroll
    for (int mt = 0; mt < 4; ++mt) {
      int m = mbase + wm + mt * 16 + l15;
#pragma unroll
      for (int nt = 0; nt < 4; ++nt)
#pragma unroll
        for (int r = 0; r < 4; ++r) {
          int n = nbase + wn + nt * 16 + g * 4 + r;
          VT[(size_t)n * M + m] = f2bf(acc[nt][mt][r] + bias[n]);
        }
    }
  } else {
#pragma unroll
    for (int nt = 0; nt < 4; ++nt) {
      int col = nbase + wn + nt * 16 + l15;
      float bvv = bias[col];
#pragma unroll
      for (int mt = 0; mt < 4; ++mt)
#pragma unroll
        for (int r = 0; r < 4; ++r) {
          int row = mbase + wm + mt * 16 + g * 4 + r;
          Kp[(size_t)row * N + col] = f2bf(acc[mt][nt][r] + bvv);
        }
    }
  }
}

// ---------------------------------------------------------------------------
// Fused flash attention, S^T/O^T orientation, no-max softmax, MFMA row-sum.
// Grid: (Nq/128, B*H). 256 thr = 4 waves; wave owns 32 q-rows (2 subtiles).
// Pipeline per iteration kc: [stage K(kc+1) then V(kc+1)] [ds_read pb(kc-1),
// vf(kc-1), kf(kc)] [MFMA: QK^T(kc) ++ PV(kc-1)] [exp(kc)->P_lds]
// [s_waitcnt vmcnt(2); s_barrier]. Post-loop vmcnt(0)+barrier for final PV.
// ---------------------------------------------------------------------------
__global__ __launch_bounds__(256, 2) void attn_kernel(const u16* __restrict__ Qp,
                                                      const u16* __restrict__ Kp,
                                                      const u16* __restrict__ VT,
                                                      u16* __restrict__ AO) {
  __shared__ __align__(16) u16 K_lds[2][64 * 64];     // [buf][kcol][d] swizzled
  __shared__ __align__(16) u16 V_lds[3][64 * 64];     // [buf][d][kcol] swizzled
  __shared__ __align__(16) u16 P_lds[4][32 * 64];     // per-wave [qrow][kcol] swz

  const int tid = threadIdx.x;
  const int w = tid >> 6, lane = tid & 63;
  const int g = lane >> 4, l15 = lane & 15;
  const int sw = l15 & 7;
  const int bh = blockIdx.y, b = bh >> 4, h = bh & 15;
  const int qrow0 = blockIdx.x * 128 + w * 32;
  const int MT = B_SZ * NK;  // VT leading dim

  // ---- staging lane constants (two 64-chunk regions per wave) ----
  const int cbase0 = (w * 2 + 0) * 64;
  const int cbase1 = (w * 2 + 1) * 64;
  const int c0 = cbase0 + lane, c1 = cbase1 + lane;
  const int row0 = c0 >> 3, kc80 = ((c0 & 7) ^ (row0 & 7)) * 8;
  const int row1 = c1 >> 3, kc81 = ((c1 & 7) ^ (row1 & 7)) * 8;

  // incremental per-lane global source pointers
  const u16* kp0 = Kp + (size_t)(b * NK + row0) * QDIM + h * HD + kc80;
  const u16* kp1 = Kp + (size_t)(b * NK + row1) * QDIM + h * HD + kc81;
  const u16* vp0 = VT + (size_t)(h * HD + row0) * MT + b * NK + kc80;
  const u16* vp1 = VT + (size_t)(h * HD + row1) * MT + b * NK + kc81;

  // ---- compute lane constants ----
  const int rb = l15 * 64;                      // fragment row base (elements)
  const int cs0 = (g ^ sw) * 8;                 // ks=0 chunk select
  const int cs1 = ((4 + g) ^ sw) * 8;           // ks=1 chunk select
  // P-store: addr = qt*1024 + pwb + ((mt*2)^pms)*8
  const int pwb = rb + (((g >> 1) ^ (sw & 1)) * 8) + (g & 1) * 4;
  const int pms = sw & 6;

  // ones A-fragment (bf16 1.0 in every slot) for the MFMA row-sum
  short8 ones8;
#pragma unroll
  for (int j = 0; j < 8; ++j) ones8[j] = (short)0x3F80;

  // Q fragments (B-operand role): lane holds Q[qrow=qt*16+l15][d=ks*32+g*8+j]
  short8 qf[2][2];
#pragma unroll
  for (int qt = 0; qt < 2; ++qt)
#pragma unroll
    for (int ks = 0; ks < 2; ++ks) {
      size_t row = (size_t)(b * NQ + qrow0 + qt * 16 + l15);
      qf[qt][ks] = *(const short8*)(Qp + row * QDIM + h * HD + ks * 32 + g * 8);
    }

  f32x4 zero4 = {0.f, 0.f, 0.f, 0.f};
  f32x4 o4[4][2];              // O^T frags: [dt][qt], r-index = d
  f32x4 lacc[2];               // row-sum via mfma(ones, P): col=qrow, rows dup
#pragma unroll
  for (int dt = 0; dt < 4; ++dt)
#pragma unroll
    for (int qt = 0; qt < 2; ++qt) o4[dt][qt] = zero4;
  lacc[0] = zero4; lacc[1] = zero4;

  u16* Pl = &P_lds[w][0];

  // ---- prologue: stage tile 0 (K0,V0), then tile 1 (K1,V1) ----
  async16(&K_lds[0][cbase0 * 8], kp0);
  async16(&K_lds[0][cbase1 * 8], kp1);
  async16(&V_lds[0][cbase0 * 8], vp0);
  async16(&V_lds[0][cbase1 * 8], vp1);
  kp0 += 64 * QDIM; kp1 += 64 * QDIM; vp0 += 64; vp1 += 64;
  __syncthreads();  // tile 0 resident (full drain; prologue only)

  async16(&K_lds[1][cbase0 * 8], kp0);
  async16(&K_lds[1][cbase1 * 8], kp1);
  async16(&V_lds[1][cbase0 * 8], vp0);
  async16(&V_lds[1][cbase1 * 8], vp1);
  kp0 += 64 * QDIM; kp1 += 64 * QDIM; vp0 += 64; vp1 += 64;

  // QK^T(0) + exp -> P(0)
  {
    const u16* Kl = &K_lds[0][0];
    f32x4 sc[4][2];
    short8 kf0[4], kf1[4];
#pragma unroll
    for (int mt = 0; mt < 4; ++mt) {
      kf0[mt] = *(const short8*)&Kl[mt * 1024 + rb + cs0];
      kf1[mt] = *(const short8*)&Kl[mt * 1024 + rb + cs1];
    }
    __builtin_amdgcn_s_setprio(1);
#pragma unroll
    for (int mt = 0; mt < 4; ++mt)
#pragma unroll
      for (int qt = 0; qt < 2; ++qt)
        sc[mt][qt] = __builtin_amdgcn_mfma_f32_16x16x32_bf16(kf0[mt], qf[qt][0],
                                                             zero4, 0, 0, 0);
#pragma unroll
    for (int mt = 0; mt < 4; ++mt)
#pragma unroll
      for (int qt = 0; qt < 2; ++qt)
        sc[mt][qt] = __builtin_amdgcn_mfma_f32_16x16x32_bf16(kf1[mt], qf[qt][1],
                                                             sc[mt][qt], 0, 0, 0);
    __builtin_amdgcn_s_setprio(0);
#pragma unroll
    for (int qt = 0; qt < 2; ++qt)
#pragma unroll
      for (int mt = 0; mt < 4; ++mt) {
        float p0 = fexp2(sc[mt][qt][0]);
        float p1 = fexp2(sc[mt][qt][1]);
        float p2 = fexp2(sc[mt][qt][2]);
        float p3 = fexp2(sc[mt][qt][3]);
        uint2 pk = {pk2(p0, p1), pk2(p2, p3)};
        *(uint2*)&Pl[qt * 1024 + pwb + ((mt * 2) ^ pms) * 8] = pk;
      }
  }
  __syncthreads();  // tile 1 resident (full drain; prologue only)

  // ---- main loop: QK^T(kc) ++ PV(kc-1), then exp(kc) ----
  for (int kc = 1; kc < NK / 64; ++kc) {
    const int pv = (kc - 1) % 3;          // V slot of tile kc-1
    // stage tile kc+1: K first, V second (vmcnt(2) leaves only V in flight)
    if (kc + 1 < NK / 64) {
      const int nk = (kc + 1) & 1, nv = (kc + 1) % 3;
      async16(&K_lds[nk][cbase0 * 8], kp0);
      async16(&K_lds[nk][cbase1 * 8], kp1);
      async16(&V_lds[nv][cbase0 * 8], vp0);
      async16(&V_lds[nv][cbase1 * 8], vp1);
      kp0 += 64 * QDIM; kp1 += 64 * QDIM; vp0 += 64; vp1 += 64;
    }
    const u16* Kl = &K_lds[kc & 1][0];
    const u16* Vl = &V_lds[pv][0];

    // hoisted fragment loads: pb/vf feed PV(kc-1), kf feeds QK^T(kc)
    short8 pb[2][2], vf[2][4], kf[2][4];
#pragma unroll
    for (int qt = 0; qt < 2; ++qt) {
      pb[0][qt] = *(const short8*)&Pl[qt * 1024 + rb + cs0];
      pb[1][qt] = *(const short8*)&Pl[qt * 1024 + rb + cs1];
    }
#pragma unroll
    for (int dt = 0; dt < 4; ++dt) {
      vf[0][dt] = *(const short8*)&Vl[dt * 1024 + rb + cs0];
      vf[1][dt] = *(const short8*)&Vl[dt * 1024 + rb + cs1];
    }
#pragma unroll
    for (int mt = 0; mt < 4; ++mt) {
      kf[0][mt] = *(const short8*)&Kl[mt * 1024 + rb + cs0];
      kf[1][mt] = *(const short8*)&Kl[mt * 1024 + rb + cs1];
    }

    // merged MFMA cluster: QK^T(kc) and PV(kc-1) are independent
    f32x4 sc[4][2];
    __builtin_amdgcn_s_setprio(1);
#pragma unroll
    for (int mt = 0; mt < 4; ++mt)
#pragma unroll
      for (int qt = 0; qt < 2; ++qt)
        sc[mt][qt] = __builtin_amdgcn_mfma_f32_16x16x32_bf16(kf[0][mt], qf[qt][0],
                                                             zero4, 0, 0, 0);
#pragma unroll
    for (int qt = 0; qt < 2; ++qt)
      lacc[qt] = __builtin_amdgcn_mfma_f32_16x16x32_bf16(ones8, pb[0][qt],
                                                         lacc[qt], 0, 0, 0);
#pragma unroll
    for (int dt = 0; dt < 4; ++dt)
#pragma unroll
      for (int qt = 0; qt < 2; ++qt)
        o4[dt][qt] = __builtin_amdgcn_mfma_f32_16x16x32_bf16(vf[0][dt], pb[0][qt],
                                                             o4[dt][qt], 0, 0, 0);
#pragma unroll
    for (int mt = 0; mt < 4; ++mt)
#pragma unroll
      for (int qt = 0; qt < 2; ++qt)
        sc[mt][qt] = __builtin_amdgcn_mfma_f32_16x16x32_bf16(kf[1][mt], qf[qt][1],
                                                             sc[mt][qt], 0, 0, 0);
#pragma unroll
    for (int qt = 0; qt < 2; ++qt)
      lacc[qt] = __builtin_amdgcn_mfma_f32_16x16x32_bf16(ones8, pb[1][qt],
                                                         lacc[qt], 0, 0, 0);
#pragma unroll
    for (int dt = 0; dt < 4; ++dt)
#pragma unroll
      for (int qt = 0; qt < 2; ++qt)
        o4[dt][qt] = __builtin_amdgcn_mfma_f32_16x16x32_bf16(vf[1][dt], pb[1][qt],
                                                             o4[dt][qt], 0, 0, 0);
    __builtin_amdgcn_s_setprio(0);

    // exp(kc) -> P_lds (overwrites P(kc-1); same-wave DS in-order vs pb reads)
#pragma unroll
    for (int qt = 0; qt < 2; ++qt)
#pragma unroll
      for (int mt = 0; mt < 4; ++mt) {
        float p0 = fexp2(sc[mt][qt][0]);
        float p1 = fexp2(sc[mt][qt][1]);
        float p2 = fexp2(sc[mt][qt][2]);
        float p3 = fexp2(sc[mt][qt][3]);
        uint2 pk = {pk2(p0, p1), pk2(p2, p3)};
        *(uint2*)&Pl[qt * 1024 + pwb + ((mt * 2) ^ pms) * 8] = pk;
      }

    // counted barrier: wait K(kc+1) (all but 2 newest loads), let V(kc+1)
    // stay in flight - it is not read until iteration kc+2 (deferred PV).
    asm volatile("s_waitcnt vmcnt(2)" ::: "memory");
    __builtin_amdgcn_sched_barrier(0);
    __builtin_amdgcn_s_barrier();
  }

  // drain remaining staged loads (V of the last tile) before final PV
  asm volatile("s_waitcnt vmcnt(0)" ::: "memory");
  __builtin_amdgcn_sched_barrier(0);
  __builtin_amdgcn_s_barrier();

  // ---- epilogue: PV for the last tile (15), V slot 15%3 = 0 ----
  {
    const u16* Vl = &V_lds[(NK / 64 - 1) % 3][0];
    short8 pb[2][2], vf[2][4];
#pragma unroll
    for (int qt = 0; qt < 2; ++qt) {
      pb[0][qt] = *(const short8*)&Pl[qt * 1024 + rb + cs0];
      pb[1][qt] = *(const short8*)&Pl[qt * 1024 + rb + cs1];
    }
#pragma unroll
    for (int dt = 0; dt < 4; ++dt) {
      vf[0][dt] = *(const short8*)&Vl[dt * 1024 + rb + cs0];
      vf[1][dt] = *(const short8*)&Vl[dt * 1024 + rb + cs1];
    }
    __builtin_amdgcn_s_setprio(1);
#pragma unroll
    for (int ks = 0; ks < 2; ++ks) {
#pragma unroll
      for (int qt = 0; qt < 2; ++qt)
        lacc[qt] = __builtin_amdgcn_mfma_f32_16x16x32_bf16(ones8, pb[ks][qt],
                                                           lacc[qt], 0, 0, 0);
#pragma unroll
      for (int dt = 0; dt < 4; ++dt)
#pragma unroll
        for (int qt = 0; qt < 2; ++qt)
          o4[dt][qt] = __builtin_amdgcn_mfma_f32_16x16x32_bf16(vf[ks][dt], pb[ks][qt],
                                                               o4[dt][qt], 0, 0, 0);
    }
    __builtin_amdgcn_s_setprio(0);
  }

  // epilogue: lacc[qt][r] all hold the full row-sum for qrow=qt*16+l15
#pragma unroll
  for (int qt = 0; qt < 2; ++qt) {
    float inv = __builtin_amdgcn_rcpf(lacc[qt][0]);
    size_t row = (size_t)(b * NQ + qrow0 + qt * 16 + l15);
#pragma unroll
    for (int dt = 0; dt < 4; ++dt) {
      uint2 pk = {pk2(o4[dt][qt][0] * inv, o4[dt][qt][1] * inv),
                  pk2(o4[dt][qt][2] * inv, o4[dt][qt][3] * inv)};
      *(uint2*)(AO + row * QDIM + h * HD + dt * 16 + g * 4) = pk;
    }
  }
}

// ---------------------------------------------------------------------------
extern "C" void kernel_launch(void* const* d_in, const int* in_sizes, int n_in,
                              void* d_out, int out_size, void* d_ws, size_t ws_size,
                              hipStream_t stream) {
  const float* query = (const float*)d_in[0];
  const float* key   = (const float*)d_in[1];
  const float* value = (const float*)d_in[2];
  const float* Wq = (const float*)d_in[3];
  const float* bq = (const float*)d_in[4];
  const float* Wk = (const float*)d_in[5];
  const float* bk = (const float*)d_in[6];
  const float* Wv = (const float*)d_in[7];
  const float* bv = (const float*)d_in[8];
  const float* Wo = (const float*)d_in[9];
  const float* bo = (const float*)d_in[10];

  char* ws = (char*)d_ws;
  size_t off = 0;
  auto alloc = [&](size_t bytes) -> void* {
    void* p = ws + off;
    off += (bytes + 255) & ~(size_t)255;
    return p;
  };
  const size_t NQTOT = (size_t)B_SZ * NQ;        // 16384
  const size_t NKTOT = (size_t)B_SZ * NK;        // 4096
  u16* qbf = (u16*)alloc(NQTOT * QDIM * 2);      // query bf16; reused as AO later
  u16* kbf = (u16*)alloc(NKTOT * KDIM * 2);
  u16* vbf = (u16*)alloc(NKTOT * KDIM * 2);
  u16* wqt = (u16*)alloc((size_t)QDIM * QDIM * 2);
  u16* wkt = (u16*)alloc((size_t)KDIM * QDIM * 2);
  u16* wvt = (u16*)alloc((size_t)KDIM * QDIM * 2);
  u16* wot = (u16*)alloc((size_t)QDIM * QDIM * 2);
  u16* Qp  = (u16*)alloc(NQTOT * QDIM * 2);
  u16* Kp  = (u16*)alloc(NKTOT * QDIM * 2);
  u16* VT  = (u16*)alloc((size_t)QDIM * NKTOT * 2);  // (1024, B*NK) transposed V-proj
  u16* AO  = qbf;  // qbf dead after Q-projection

  // 1) dtype conversions: all three tensors in ONE launch
  {
    int n4q  = (int)(NQTOT * QDIM / 4);   // 4,194,304
    int n4kv = (int)(NKTOT * KDIM / 4);   //   786,432
    int nb = (n4q + 2 * n4kv + 255) / 256;
    f32_to_bf16_all<<<nb, 256, 0, stream>>>(query, key, value, qbf, kbf, vbf,
                                            n4q, n4kv);
  }
  // 2) weight transposes: all four in ONE launch (z selects)
  transpose4_k<<<dim3(QDIM / 32, QDIM / 32, 4), 256, 0, stream>>>(
      Wq, Wk, Wv, Wo, wqt, wkt, wvt, wot);

  // 3) projections: Q scaled by QSCALE (softmax exp2-domain fold); K+V fused
  gemm_bt256<<<(NQTOT / 128) * (QDIM / 256), 512, 0, stream>>>(
      qbf, wqt, bq, nullptr, Qp, (int)NQTOT, QDIM, QDIM, 1, QSCALE);
  gemm_kv<<<(NKTOT / 128) * (QDIM / 128) * 2, 256, 0, stream>>>(
      kbf, vbf, wkt, wvt, bk, bv, Kp, VT, (int)NKTOT, QDIM, KDIM);

  // 4) fused attention -> AO (bf16, (B*Nq, 1024))
  attn_kernel<<<dim3(NQ / 128, B_SZ * NH), 256, 0, stream>>>(Qp, Kp, VT, AO);

  // 5) output projection (fp32 out)
  gemm_bt256<<<(NQTOT / 128) * (QDIM / 256), 512, 0, stream>>>(
      AO, wot, bo, (float*)d_out, nullptr, (int)NQTOT, QDIM, QDIM, 0, 1.0f);

  (void)in_sizes; (void)n_in; (void)out_size; (void)ws_size;
}

// Round 7
// 391.279 us; speedup vs baseline: 1.1010x; 1.0021x over previous
//
#include <hip/hip_runtime.h>
#include <hip/hip_bf16.h>
#include <stdint.h>

// ---------------------------------------------------------------------------
// CrossAttention: out = softmax((X Wq)(K Wk)^T * s) (V Wv) Wo  (+biases)
// B=4, Nq=4096, Nk=1024, QUERY_DIM=1024, KEY_DIM=768, H=16, HD=64
// R11: attn occupancy attack. LDS 56->48 KB (V triple->double buffer) lifts
//      the residency cap 2->3 blocks/CU (OccupancyPercent pinned ~20% since
//      R7 = the 2-block LDS cap; kernel is latency-bound, so TLP is the
//      lever). V double-buffer made safe by a read-fence: all fragment
//      ds_reads issued, then lgkmcnt(0)+s_barrier (all waves' reads in
//      registers), THEN stage into the now-dead slot. launch_bounds(256,3).
// Carried (R10): XCD-chunked swizzle on both GEMMs, fused conversions and
//      transposes, R9 3-buffer counted-vmcnt 128x256 GEMM pipeline,
//      deferred-PV attn pipeline, raw v_exp_f32, XOR-swizzled LDS, no-max
//      exp2 softmax, MFMA row-sum, fused K/V projection.
// ---------------------------------------------------------------------------

typedef unsigned short u16;
typedef __attribute__((ext_vector_type(8))) short short8;   // 8 bf16 = 4 VGPRs
typedef __attribute__((ext_vector_type(4))) float f32x4;    // MFMA C/D frag

#define B_SZ 4
#define NQ   4096
#define NK   1024
#define QDIM 1024
#define KDIM 768
#define NH   16
#define HD   64
// scale * log2(e): softmax computed in exp2 domain (folded into Q projection)
#define QSCALE (0.125f * 1.44269504f)

__device__ __forceinline__ u16 f2bf(float f) {
  union { float f; uint32_t u; } v; v.f = f;
  uint32_t u = v.u;
  return (u16)((u + 0x7FFFu + ((u >> 16) & 1u)) >> 16);  // RNE
}

// packed f32x2 -> bf16x2 (v_cvt_pk_bf16_f32 on gfx950)
__device__ __forceinline__ uint32_t pk2(float a, float b) {
  union { __hip_bfloat162 h; uint32_t u; } cv;
  cv.h = __float22bfloat162_rn(float2{a, b});
  return cv.u;
}

// raw v_exp_f32 (no denormal-guard expansion; underflow flushes to 0 - fine
// for softmax numerator)
__device__ __forceinline__ float fexp2(float x) {
  return __builtin_amdgcn_exp2f(x);
}

// global -> LDS async copy, 16B per lane; lds base must be wave-uniform.
__device__ __forceinline__ void async16(u16* lds, const u16* g) {
  __builtin_amdgcn_global_load_lds(
      (__attribute__((address_space(1))) void*)(g),
      (__attribute__((address_space(3))) void*)(lds), 16, 0, 0);
}

// ---------------------------------------------------------------------------
// fused fp32 -> bf16 for query/key/value (range-partitioned single launch)
// ---------------------------------------------------------------------------
__global__ __launch_bounds__(256) void f32_to_bf16_all(const float* __restrict__ q,
                                                       const float* __restrict__ k,
                                                       const float* __restrict__ v,
                                                       u16* __restrict__ oq,
                                                       u16* __restrict__ ok,
                                                       u16* __restrict__ ov,
                                                       int n4q, int n4kv) {
  int i = blockIdx.x * 256 + threadIdx.x;
  const float* in; u16* out; int idx;
  if (i < n4q) { in = q; out = oq; idx = i; }
  else if (i < n4q + n4kv) { in = k; out = ok; idx = i - n4q; }
  else if (i < n4q + 2 * n4kv) { in = v; out = ov; idx = i - n4q - n4kv; }
  else return;
  f32x4 vv = ((const f32x4*)in)[idx];
  uint2 o = {pk2(vv.x, vv.y), pk2(vv.z, vv.w)};
  ((uint2*)out)[idx] = o;
}

// ---------------------------------------------------------------------------
// fused weight transposes: z selects {Wq, Wk, Wv, Wo}; K in {1024,768,768,1024}
// W (K x N fp32, row-major) -> Wt (N x K bf16, row-major)   [LDS-tiled]
// ---------------------------------------------------------------------------
__global__ __launch_bounds__(256) void transpose4_k(const float* __restrict__ W0,
                                                    const float* __restrict__ W1,
                                                    const float* __restrict__ W2,
                                                    const float* __restrict__ W3,
                                                    u16* __restrict__ T0,
                                                    u16* __restrict__ T1,
                                                    u16* __restrict__ T2,
                                                    u16* __restrict__ T3) {
  const int z = blockIdx.z;
  const float* W = (z == 0) ? W0 : (z == 1) ? W1 : (z == 2) ? W2 : W3;
  u16* T = (z == 0) ? T0 : (z == 1) ? T1 : (z == 2) ? T2 : T3;
  const int K = (z == 1 || z == 2) ? KDIM : QDIM;
  const int N = QDIM;
  int nb = blockIdx.x * 32, kb = blockIdx.y * 32;
  if (kb >= K) return;  // block-uniform exit (before barrier)
  __shared__ float t[32][33];
  int tx = threadIdx.x & 31, ty = threadIdx.x >> 5;  // 32 x 8
#pragma unroll
  for (int i = 0; i < 4; ++i)
    t[ty + i * 8][tx] = W[(size_t)(kb + ty + i * 8) * N + nb + tx];
  __syncthreads();
#pragma unroll
  for (int i = 0; i < 4; ++i)
    T[(size_t)(nb + ty + i * 8) * K + kb + tx] = f2bf(t[tx][ty + i * 8]);
}

// ---------------------------------------------------------------------------
// C[M,N] = (A[M,K] * Bt[N,K]^T + bias) * scale ; out bf16 or fp32
// 128x256 tile, BK=64, 512 threads (8 waves: 2M x 4N, each 64x64 out).
// 3 LDS K-tile buffers, staging 2 K-tiles ahead, counted vmcnt(6).
// 1D grid + XCD-chunked swizzle; N-panel fastest in work decode so each
// XCD reuses one A row-block across all N/256 panels via its L2.
// Requires gridDim.x % 8 == 0, K >= 128, K%64==0.
// ---------------------------------------------------------------------------
__global__ __launch_bounds__(512, 2) void gemm_bt256(const u16* __restrict__ A,
                                                     const u16* __restrict__ Bt,
                                                     const float* __restrict__ bias,
                                                     float* __restrict__ Cf,
                                                     u16* __restrict__ Cb,
                                                     int M, int N, int K,
                                                     int out_bf16, float scale) {
  __shared__ __align__(16) u16 Al[3][128 * 64];
  __shared__ __align__(16) u16 Bl[3][256 * 64];
  const int tid = threadIdx.x;
  const int w = tid >> 6, lane = tid & 63;
  const int g = lane >> 4, l15 = lane & 15;
  const int sw = l15 & 7;
  const int bid = blockIdx.x;
  const int cpx = gridDim.x >> 3;
  const int swz = (bid & 7) * cpx + (bid >> 3);
  const int nby = N >> 8;
  const int mbase = (swz / nby) * 128, nbase = (swz % nby) * 256;
  const int wm = (w & 1) * 64, wn = (w >> 1) * 64;
  const int NT = K >> 6;

  // ---- staging lane constants ----
  const int ca0 = 0 * 512 + tid, ca1 = 1 * 512 + tid;
  const int ra0 = ca0 >> 3, rc0 = ((ca0 & 7) ^ (ra0 & 7)) * 8;
  const int ra1 = ca1 >> 3, rc1 = ((ca1 & 7) ^ (ra1 & 7)) * 8;
  const u16* pa0 = A + (size_t)(mbase + ra0) * K + rc0;
  const u16* pa1 = A + (size_t)(mbase + ra1) * K + rc1;
  const u16* pb[4];
#pragma unroll
  for (int i = 0; i < 4; ++i) {
    int c = i * 512 + tid;
    int row = c >> 3, col = ((c & 7) ^ (row & 7)) * 8;
    pb[i] = Bt + (size_t)(nbase + row) * K + col;
  }
  const int lA0 = (0 * 512 + w * 64) * 8, lA1 = (1 * 512 + w * 64) * 8;
  int lB[4];
#pragma unroll
  for (int i = 0; i < 4; ++i) lB[i] = (i * 512 + w * 64) * 8;

  f32x4 zero4 = {0.f, 0.f, 0.f, 0.f};
  f32x4 acc[4][4];
#pragma unroll
  for (int i = 0; i < 4; ++i)
#pragma unroll
    for (int j = 0; j < 4; ++j) acc[i][j] = zero4;

  // ---- prologue: stage kt0 -> buf0, kt1 -> buf1 ----
  async16(&Al[0][lA0], pa0); async16(&Al[0][lA1], pa1);
#pragma unroll
  for (int i = 0; i < 4; ++i) async16(&Bl[0][lB[i]], pb[i]);
  pa0 += 64; pa1 += 64;
#pragma unroll
  for (int i = 0; i < 4; ++i) pb[i] += 64;
  async16(&Al[1][lA0], pa0); async16(&Al[1][lA1], pa1);
#pragma unroll
  for (int i = 0; i < 4; ++i) async16(&Bl[1][lB[i]], pb[i]);
  pa0 += 64; pa1 += 64;
#pragma unroll
  for (int i = 0; i < 4; ++i) pb[i] += 64;
  asm volatile("s_waitcnt vmcnt(6)" ::: "memory");  // kt0 landed; kt1 in flight
  __builtin_amdgcn_sched_barrier(0);
  __builtin_amdgcn_s_barrier();

  int cb = 0, sb = 2;
  for (int kt = 0; kt < NT; ++kt) {
    const u16* Ap = &Al[cb][0];
    const u16* Bp = &Bl[cb][0];
    const bool st = (kt + 2 < NT);

    // ---- phase 0: acc[0..3][0..1] ----
    short8 af[4][2], bfa[2][2];
#pragma unroll
    for (int mt = 0; mt < 4; ++mt) {
      af[mt][0] = *(const short8*)&Ap[(wm + mt * 16 + l15) * 64 + (g ^ sw) * 8];
      af[mt][1] = *(const short8*)&Ap[(wm + mt * 16 + l15) * 64 + ((4 + g) ^ sw) * 8];
    }
#pragma unroll
    for (int nt = 0; nt < 2; ++nt) {
      bfa[nt][0] = *(const short8*)&Bp[(wn + nt * 16 + l15) * 64 + (g ^ sw) * 8];
      bfa[nt][1] = *(const short8*)&Bp[(wn + nt * 16 + l15) * 64 + ((4 + g) ^ sw) * 8];
    }
    if (st) {
      async16(&Al[sb][lA0], pa0);
      async16(&Al[sb][lA1], pa1);
      async16(&Bl[sb][lB[0]], pb[0]);
      async16(&Bl[sb][lB[1]], pb[1]);
    }
    __builtin_amdgcn_s_barrier();
    asm volatile("s_waitcnt lgkmcnt(0)" ::: "memory");
    __builtin_amdgcn_sched_barrier(0);
    __builtin_amdgcn_s_setprio(1);
#pragma unroll
    for (int ks = 0; ks < 2; ++ks)
#pragma unroll
      for (int mt = 0; mt < 4; ++mt)
#pragma unroll
        for (int nt = 0; nt < 2; ++nt)
          acc[mt][nt] = __builtin_amdgcn_mfma_f32_16x16x32_bf16(af[mt][ks], bfa[nt][ks],
                                                                acc[mt][nt], 0, 0, 0);
    __builtin_amdgcn_s_setprio(0);
    __builtin_amdgcn_s_barrier();

    // ---- phase 1: acc[0..3][2..3] ----
    short8 bfb[2][2];
#pragma unroll
    for (int nt = 0; nt < 2; ++nt) {
      bfb[nt][0] = *(const short8*)&Bp[(wn + (nt + 2) * 16 + l15) * 64 + (g ^ sw) * 8];
      bfb[nt][1] = *(const short8*)&Bp[(wn + (nt + 2) * 16 + l15) * 64 + ((4 + g) ^ sw) * 8];
    }
    if (st) {
      async16(&Bl[sb][lB[2]], pb[2]);
      async16(&Bl[sb][lB[3]], pb[3]);
      pa0 += 64; pa1 += 64;
#pragma unroll
      for (int i = 0; i < 4; ++i) pb[i] += 64;
    }
    __builtin_amdgcn_s_barrier();
    asm volatile("s_waitcnt lgkmcnt(0)" ::: "memory");
    __builtin_amdgcn_sched_barrier(0);
    __builtin_amdgcn_s_setprio(1);
#pragma unroll
    for (int ks = 0; ks < 2; ++ks)
#pragma unroll
      for (int mt = 0; mt < 4; ++mt)
#pragma unroll
        for (int nt = 0; nt < 2; ++nt)
          acc[mt][nt + 2] = __builtin_amdgcn_mfma_f32_16x16x32_bf16(af[mt][ks], bfb[nt][ks],
                                                                    acc[mt][nt + 2], 0, 0, 0);
    __builtin_amdgcn_s_setprio(0);

    // ---- K-tile boundary: ensure kt+1 landed; kt+2 may stay in flight ----
    if (kt < NT - 2) {
      asm volatile("s_waitcnt vmcnt(6)" ::: "memory");
    } else if (kt == NT - 2) {
      asm volatile("s_waitcnt vmcnt(0)" ::: "memory");
    }
    __builtin_amdgcn_sched_barrier(0);
    __builtin_amdgcn_s_barrier();
    cb = (cb == 2) ? 0 : cb + 1;
    sb = (sb == 2) ? 0 : sb + 1;
  }

  // ---- epilogue ----
#pragma unroll
  for (int nt = 0; nt < 4; ++nt) {
    int col = nbase + wn + nt * 16 + l15;
    float bv = bias[col];
#pragma unroll
    for (int mt = 0; mt < 4; ++mt)
#pragma unroll
      for (int r = 0; r < 4; ++r) {
        int row = mbase + wm + mt * 16 + g * 4 + r;
        float v = (acc[mt][nt][r] + bv) * scale;
        if (out_bf16) Cb[(size_t)row * N + col] = f2bf(v);
        else          Cf[(size_t)row * N + col] = v;
      }
  }
}

// ---------------------------------------------------------------------------
// Combined K/V projection, 1D grid + XCD-chunked swizzle.
// work id: ct = swz>>8, xw = swz&31 (M block), yw = (swz>>5)&7 (N block).
// ct==0 -> Kp[M,N] = kA*Wk^T + bk (row store)
// ct==1 -> VT[N,M] = (vA*Wv^T + bv)^T
// ---------------------------------------------------------------------------
__global__ __launch_bounds__(256) void gemm_kv(const u16* __restrict__ kA,
                                               const u16* __restrict__ vA,
                                               const u16* __restrict__ Wk,
                                               const u16* __restrict__ Wv,
                                               const float* __restrict__ bk,
                                               const float* __restrict__ bv,
                                               u16* __restrict__ Kp,
                                               u16* __restrict__ VT,
                                               int M, int N, int K) {
  __shared__ __align__(16) u16 Al[128 * 64];
  __shared__ __align__(16) u16 Bl[128 * 64];
  const int bid = blockIdx.x;                     // 512 blocks
  const int swz = (bid & 7) * 64 + (bid >> 3);    // XCD-chunked
  const int ct = swz >> 8;                        // uniform
  const int mbase = (swz & 31) * 128, nbase = ((swz >> 5) & 7) * 128;
  const u16* A  = ct ? vA : kA;
  const u16* Bt = ct ? Wv : Wk;
  const float* bias = ct ? bv : bk;
  const int tid = threadIdx.x;
  const int w = tid >> 6, lane = tid & 63;
  const int g = lane >> 4, l15 = lane & 15;
  const int sw = l15 & 7;
  const int wm = (w & 1) * 64, wn = (w >> 1) * 64;

  f32x4 zero4 = {0.f, 0.f, 0.f, 0.f};
  f32x4 acc[4][4];  // ct=0: [mt][nt]; ct=1: [nt][mt] (transposed D)
#pragma unroll
  for (int i = 0; i < 4; ++i)
#pragma unroll
    for (int j = 0; j < 4; ++j) acc[i][j] = zero4;

  for (int kb = 0; kb < K; kb += 64) {
#pragma unroll
    for (int i = 0; i < 4; ++i) {
      int cbase = w * 256 + i * 64;
      int c = cbase + lane;
      int row = c >> 3;
      int kc8 = ((c & 7) ^ (row & 7)) * 8;
      async16(&Al[cbase * 8], A + (size_t)(mbase + row) * K + kb + kc8);
      async16(&Bl[cbase * 8], Bt + (size_t)(nbase + row) * K + kb + kc8);
    }
    __syncthreads();
#pragma unroll
    for (int ks = 0; ks < 2; ++ks) {
      short8 af[4], bf[4];
#pragma unroll
      for (int mt = 0; mt < 4; ++mt)
        af[mt] = *(const short8*)&Al[(wm + mt * 16 + l15) * 64 + ((ks * 4 + g) ^ sw) * 8];
#pragma unroll
      for (int nt = 0; nt < 4; ++nt)
        bf[nt] = *(const short8*)&Bl[(wn + nt * 16 + l15) * 64 + ((ks * 4 + g) ^ sw) * 8];
      if (ct) {
#pragma unroll
        for (int nt = 0; nt < 4; ++nt)
#pragma unroll
          for (int mt = 0; mt < 4; ++mt)
            acc[nt][mt] = __builtin_amdgcn_mfma_f32_16x16x32_bf16(bf[nt], af[mt],
                                                                  acc[nt][mt], 0, 0, 0);
      } else {
#pragma unroll
        for (int mt = 0; mt < 4; ++mt)
#pragma unroll
          for (int nt = 0; nt < 4; ++nt)
            acc[mt][nt] = __builtin_amdgcn_mfma_f32_16x16x32_bf16(af[mt], bf[nt],
                                                                  acc[mt][nt], 0, 0, 0);
      }
    }
    __syncthreads();
  }

  if (ct) {
    // D = C^T: lane holds VT[n=nbase+wn+nt*16+g*4+r][m=mbase+wm+mt*16+l15]
#pragma unroll
    for (int mt = 0; mt < 4; ++mt) {
      int m = mbase + wm + mt * 16 + l15;
#pragma unroll
      for (int nt = 0; nt < 4; ++nt)
#pragma unroll
        for (int r = 0; r < 4; ++r) {
          int n = nbase + wn + nt * 16 + g * 4 + r;
          VT[(size_t)n * M + m] = f2bf(acc[nt][mt][r] + bias[n]);
        }
    }
  } else {
#pragma unroll
    for (int nt = 0; nt < 4; ++nt) {
      int col = nbase + wn + nt * 16 + l15;
      float bvv = bias[col];
#pragma unroll
      for (int mt = 0; mt < 4; ++mt)
#pragma unroll
        for (int r = 0; r < 4; ++r) {
          int row = mbase + wm + mt * 16 + g * 4 + r;
          Kp[(size_t)row * N + col] = f2bf(acc[mt][nt][r] + bvv);
        }
    }
  }
}

// ---------------------------------------------------------------------------
// Fused flash attention, S^T/O^T orientation, no-max softmax, MFMA row-sum.
// Grid: (Nq/128, B*H). 256 thr = 4 waves; wave owns 32 q-rows (2 subtiles).
// R11: K 2-buf, V 2-buf, P per-wave => LDS 48KB => 3 blocks/CU.
// Per iteration kc: [ds_read pb(kc-1), vf(kc-1), kf(kc)] [read-fence:
// lgkmcnt(0)+s_barrier] [stage K/V(kc+1) into (kc+1)&1 slots - now dead]
// [MFMA: QK^T(kc) ++ PV(kc-1)] [exp(kc)->P_lds] [__syncthreads].
// ---------------------------------------------------------------------------
__global__ __launch_bounds__(256, 3) void attn_kernel(const u16* __restrict__ Qp,
                                                      const u16* __restrict__ Kp,
                                                      const u16* __restrict__ VT,
                                                      u16* __restrict__ AO) {
  __shared__ __align__(16) u16 K_lds[2][64 * 64];     // [buf][kcol][d] swizzled
  __shared__ __align__(16) u16 V_lds[2][64 * 64];     // [buf][d][kcol] swizzled
  __shared__ __align__(16) u16 P_lds[4][32 * 64];     // per-wave [qrow][kcol] swz

  const int tid = threadIdx.x;
  const int w = tid >> 6, lane = tid & 63;
  const int g = lane >> 4, l15 = lane & 15;
  const int sw = l15 & 7;
  const int bh = blockIdx.y, b = bh >> 4, h = bh & 15;
  const int qrow0 = blockIdx.x * 128 + w * 32;
  const int MT = B_SZ * NK;  // VT leading dim
  const int NT4 = NK / 64;   // 16 K/V tiles

  // ---- staging lane constants (two 64-chunk regions per wave) ----
  const int cbase0 = (w * 2 + 0) * 64;
  const int cbase1 = (w * 2 + 1) * 64;
  const int c0 = cbase0 + lane, c1 = cbase1 + lane;
  const int row0 = c0 >> 3, kc80 = ((c0 & 7) ^ (row0 & 7)) * 8;
  const int row1 = c1 >> 3, kc81 = ((c1 & 7) ^ (row1 & 7)) * 8;

  // incremental per-lane global source pointers
  const u16* kp0 = Kp + (size_t)(b * NK + row0) * QDIM + h * HD + kc80;
  const u16* kp1 = Kp + (size_t)(b * NK + row1) * QDIM + h * HD + kc81;
  const u16* vp0 = VT + (size_t)(h * HD + row0) * MT + b * NK + kc80;
  const u16* vp1 = VT + (size_t)(h * HD + row1) * MT + b * NK + kc81;

  // ---- compute lane constants ----
  const int rb = l15 * 64;                      // fragment row base (elements)
  const int cs0 = (g ^ sw) * 8;                 // ks=0 chunk select
  const int cs1 = ((4 + g) ^ sw) * 8;           // ks=1 chunk select
  // P-store: addr = qt*1024 + pwb + ((mt*2)^pms)*8
  const int pwb = rb + (((g >> 1) ^ (sw & 1)) * 8) + (g & 1) * 4;
  const int pms = sw & 6;

  // ones A-fragment (bf16 1.0 in every slot) for the MFMA row-sum
  short8 ones8;
#pragma unroll
  for (int j = 0; j < 8; ++j) ones8[j] = (short)0x3F80;

  // Q fragments (B-operand role): lane holds Q[qrow=qt*16+l15][d=ks*32+g*8+j]
  short8 qf[2][2];
#pragma unroll
  for (int qt = 0; qt < 2; ++qt)
#pragma unroll
    for (int ks = 0; ks < 2; ++ks) {
      size_t row = (size_t)(b * NQ + qrow0 + qt * 16 + l15);
      qf[qt][ks] = *(const short8*)(Qp + row * QDIM + h * HD + ks * 32 + g * 8);
    }

  f32x4 zero4 = {0.f, 0.f, 0.f, 0.f};
  f32x4 o4[4][2];              // O^T frags: [dt][qt], r-index = d
  f32x4 lacc[2];               // row-sum via mfma(ones, P): col=qrow, rows dup
#pragma unroll
  for (int dt = 0; dt < 4; ++dt)
#pragma unroll
    for (int qt = 0; qt < 2; ++qt) o4[dt][qt] = zero4;
  lacc[0] = zero4; lacc[1] = zero4;

  u16* Pl = &P_lds[w][0];

  // ---- prologue: stage tile 0 (K[0],V[0]); then tile 1 (K[1],V[1]) ----
  async16(&K_lds[0][cbase0 * 8], kp0);
  async16(&K_lds[0][cbase1 * 8], kp1);
  async16(&V_lds[0][cbase0 * 8], vp0);
  async16(&V_lds[0][cbase1 * 8], vp1);
  kp0 += 64 * QDIM; kp1 += 64 * QDIM; vp0 += 64; vp1 += 64;
  __syncthreads();  // tile 0 resident

  async16(&K_lds[1][cbase0 * 8], kp0);
  async16(&K_lds[1][cbase1 * 8], kp1);
  async16(&V_lds[1][cbase0 * 8], vp0);
  async16(&V_lds[1][cbase1 * 8], vp1);
  kp0 += 64 * QDIM; kp1 += 64 * QDIM; vp0 += 64; vp1 += 64;

  // QK^T(0) + exp -> P(0)
  {
    const u16* Kl = &K_lds[0][0];
    f32x4 sc[4][2];
    short8 kf0[4], kf1[4];
#pragma unroll
    for (int mt = 0; mt < 4; ++mt) {
      kf0[mt] = *(const short8*)&Kl[mt * 1024 + rb + cs0];
      kf1[mt] = *(const short8*)&Kl[mt * 1024 + rb + cs1];
    }
    __builtin_amdgcn_s_setprio(1);
#pragma unroll
    for (int mt = 0; mt < 4; ++mt)
#pragma unroll
      for (int qt = 0; qt < 2; ++qt)
        sc[mt][qt] = __builtin_amdgcn_mfma_f32_16x16x32_bf16(kf0[mt], qf[qt][0],
                                                             zero4, 0, 0, 0);
#pragma unroll
    for (int mt = 0; mt < 4; ++mt)
#pragma unroll
      for (int qt = 0; qt < 2; ++qt)
        sc[mt][qt] = __builtin_amdgcn_mfma_f32_16x16x32_bf16(kf1[mt], qf[qt][1],
                                                             sc[mt][qt], 0, 0, 0);
    __builtin_amdgcn_s_setprio(0);
#pragma unroll
    for (int qt = 0; qt < 2; ++qt)
#pragma unroll
      for (int mt = 0; mt < 4; ++mt) {
        float p0 = fexp2(sc[mt][qt][0]);
        float p1 = fexp2(sc[mt][qt][1]);
        float p2 = fexp2(sc[mt][qt][2]);
        float p3 = fexp2(sc[mt][qt][3]);
        uint2 pk = {pk2(p0, p1), pk2(p2, p3)};
        *(uint2*)&Pl[qt * 1024 + pwb + ((mt * 2) ^ pms) * 8] = pk;
      }
  }
  __syncthreads();  // tile 1 resident

  // ---- main loop: QK^T(kc) ++ PV(kc-1), then exp(kc) ----
  for (int kc = 1; kc < NT4; ++kc) {
    const u16* Kl = &K_lds[kc & 1][0];
    const u16* Vl = &V_lds[(kc - 1) & 1][0];  // V of tile kc-1 (deferred PV)

    // fragment loads: pb/vf feed PV(kc-1), kf feeds QK^T(kc)
    short8 pb[2][2], vf[2][4], kf[2][4];
#pragma unroll
    for (int qt = 0; qt < 2; ++qt) {
      pb[0][qt] = *(const short8*)&Pl[qt * 1024 + rb + cs0];
      pb[1][qt] = *(const short8*)&Pl[qt * 1024 + rb + cs1];
    }
#pragma unroll
    for (int dt = 0; dt < 4; ++dt) {
      vf[0][dt] = *(const short8*)&Vl[dt * 1024 + rb + cs0];
      vf[1][dt] = *(const short8*)&Vl[dt * 1024 + rb + cs1];
    }
#pragma unroll
    for (int mt = 0; mt < 4; ++mt) {
      kf[0][mt] = *(const short8*)&Kl[mt * 1024 + rb + cs0];
      kf[1][mt] = *(const short8*)&Kl[mt * 1024 + rb + cs1];
    }

    // read-fence: this wave's reads in registers; barrier => ALL waves' reads
    // done, so the (kc+1)&1 slots (holding tile kc-1) are dead and stageable.
    asm volatile("s_waitcnt lgkmcnt(0)" ::: "memory");
    __builtin_amdgcn_sched_barrier(0);
    __builtin_amdgcn_s_barrier();

    if (kc + 1 < NT4) {
      const int ns = (kc + 1) & 1;
      async16(&K_lds[ns][cbase0 * 8], kp0);
      async16(&K_lds[ns][cbase1 * 8], kp1);
      async16(&V_lds[ns][cbase0 * 8], vp0);
      async16(&V_lds[ns][cbase1 * 8], vp1);
      kp0 += 64 * QDIM; kp1 += 64 * QDIM; vp0 += 64; vp1 += 64;
    }

    // merged MFMA cluster: QK^T(kc) and PV(kc-1) are independent
    f32x4 sc[4][2];
    __builtin_amdgcn_s_setprio(1);
#pragma unroll
    for (int mt = 0; mt < 4; ++mt)
#pragma unroll
      for (int qt = 0; qt < 2; ++qt)
        sc[mt][qt] = __builtin_amdgcn_mfma_f32_16x16x32_bf16(kf[0][mt], qf[qt][0],
                                                             zero4, 0, 0, 0);
#pragma unroll
    for (int qt = 0; qt < 2; ++qt)
      lacc[qt] = __builtin_amdgcn_mfma_f32_16x16x32_bf16(ones8, pb[0][qt],
                                                         lacc[qt], 0, 0, 0);
#pragma unroll
    for (int dt = 0; dt < 4; ++dt)
#pragma unroll
      for (int qt = 0; qt < 2; ++qt)
        o4[dt][qt] = __builtin_amdgcn_mfma_f32_16x16x32_bf16(vf[0][dt], pb[0][qt],
                                                             o4[dt][qt], 0, 0, 0);
#pragma unroll
    for (int mt = 0; mt < 4; ++mt)
#pragma unroll
      for (int qt = 0; qt < 2; ++qt)
        sc[mt][qt] = __builtin_amdgcn_mfma_f32_16x16x32_bf16(kf[1][mt], qf[qt][1],
                                                             sc[mt][qt], 0, 0, 0);
#pragma unroll
    for (int qt = 0; qt < 2; ++qt)
      lacc[qt] = __builtin_amdgcn_mfma_f32_16x16x32_bf16(ones8, pb[1][qt],
                                                         lacc[qt], 0, 0, 0);
#pragma unroll
    for (int dt = 0; dt < 4; ++dt)
#pragma unroll
      for (int qt = 0; qt < 2; ++qt)
        o4[dt][qt] = __builtin_amdgcn_mfma_f32_16x16x32_bf16(vf[1][dt], pb[1][qt],
                                                             o4[dt][qt], 0, 0, 0);
    __builtin_amdgcn_s_setprio(0);

    // exp(kc) -> P_lds (overwrites P(kc-1); same-wave DS in-order vs pb reads)
#pragma unroll
    for (int qt = 0; qt < 2; ++qt)
#pragma unroll
      for (int mt = 0; mt < 4; ++mt) {
        float p0 = fexp2(sc[mt][qt][0]);
        float p1 = fexp2(sc[mt][qt][1]);
        float p2 = fexp2(sc[mt][qt][2]);
        float p3 = fexp2(sc[mt][qt][3]);
        uint2 pk = {pk2(p0, p1), pk2(p2, p3)};
        *(uint2*)&Pl[qt * 1024 + pwb + ((mt * 2) ^ pms) * 8] = pk;
      }

    __syncthreads();  // drains staged tile kc+1; readable next iteration
  }

  // ---- epilogue: PV for the last tile (NT4-1), V slot (NT4-1)&1 ----
  {
    const u16* Vl = &V_lds[(NT4 - 1) & 1][0];
    short8 pb[2][2], vf[2][4];
#pragma unroll
    for (int qt = 0; qt < 2; ++qt) {
      pb[0][qt] = *(const short8*)&Pl[qt * 1024 + rb + cs0];
      pb[1][qt] = *(const short8*)&Pl[qt * 1024 + rb + cs1];
    }
#pragma unroll
    for (int dt = 0; dt < 4; ++dt) {
      vf[0][dt] = *(const short8*)&Vl[dt * 1024 + rb + cs0];
      vf[1][dt] = *(const short8*)&Vl[dt * 1024 + rb + cs1];
    }
    __builtin_amdgcn_s_setprio(1);
#pragma unroll
    for (int ks = 0; ks < 2; ++ks) {
#pragma unroll
      for (int qt = 0; qt < 2; ++qt)
        lacc[qt] = __builtin_amdgcn_mfma_f32_16x16x32_bf16(ones8, pb[ks][qt],
                                                           lacc[qt], 0, 0, 0);
#pragma unroll
      for (int dt = 0; dt < 4; ++dt)
#pragma unroll
        for (int qt = 0; qt < 2; ++qt)
          o4[dt][qt] = __builtin_amdgcn_mfma_f32_16x16x32_bf16(vf[ks][dt], pb[ks][qt],
                                                               o4[dt][qt], 0, 0, 0);
    }
    __builtin_amdgcn_s_setprio(0);
  }

  // epilogue: lacc[qt][r] all hold the full row-sum for qrow=qt*16+l15
#pragma unroll
  for (int qt = 0; qt < 2; ++qt) {
    float inv = __builtin_amdgcn_rcpf(lacc[qt][0]);
    size_t row = (size_t)(b * NQ + qrow0 + qt * 16 + l15);
#pragma unroll
    for (int dt = 0; dt < 4; ++dt) {
      uint2 pk = {pk2(o4[dt][qt][0] * inv, o4[dt][qt][1] * inv),
                  pk2(o4[dt][qt][2] * inv, o4[dt][qt][3] * inv)};
      *(uint2*)(AO + row * QDIM + h * HD + dt * 16 + g * 4) = pk;
    }
  }
}

// ---------------------------------------------------------------------------
extern "C" void kernel_launch(void* const* d_in, const int* in_sizes, int n_in,
                              void* d_out, int out_size, void* d_ws, size_t ws_size,
                              hipStream_t stream) {
  const float* query = (const float*)d_in[0];
  const float* key   = (const float*)d_in[1];
  const float* value = (const float*)d_in[2];
  const float* Wq = (const float*)d_in[3];
  const float* bq = (const float*)d_in[4];
  const float* Wk = (const float*)d_in[5];
  const float* bk = (const float*)d_in[6];
  const float* Wv = (const float*)d_in[7];
  const float* bv = (const float*)d_in[8];
  const float* Wo = (const float*)d_in[9];
  const float* bo = (const float*)d_in[10];

  char* ws = (char*)d_ws;
  size_t off = 0;
  auto alloc = [&](size_t bytes) -> void* {
    void* p = ws + off;
    off += (bytes + 255) & ~(size_t)255;
    return p;
  };
  const size_t NQTOT = (size_t)B_SZ * NQ;        // 16384
  const size_t NKTOT = (size_t)B_SZ * NK;        // 4096
  u16* qbf = (u16*)alloc(NQTOT * QDIM * 2);      // query bf16; reused as AO later
  u16* kbf = (u16*)alloc(NKTOT * KDIM * 2);
  u16* vbf = (u16*)alloc(NKTOT * KDIM * 2);
  u16* wqt = (u16*)alloc((size_t)QDIM * QDIM * 2);
  u16* wkt = (u16*)alloc((size_t)KDIM * QDIM * 2);
  u16* wvt = (u16*)alloc((size_t)KDIM * QDIM * 2);
  u16* wot = (u16*)alloc((size_t)QDIM * QDIM * 2);
  u16* Qp  = (u16*)alloc(NQTOT * QDIM * 2);
  u16* Kp  = (u16*)alloc(NKTOT * QDIM * 2);
  u16* VT  = (u16*)alloc((size_t)QDIM * NKTOT * 2);  // (1024, B*NK) transposed V-proj
  u16* AO  = qbf;  // qbf dead after Q-projection

  // 1) dtype conversions: all three tensors in ONE launch
  {
    int n4q  = (int)(NQTOT * QDIM / 4);   // 4,194,304
    int n4kv = (int)(NKTOT * KDIM / 4);   //   786,432
    int nb = (n4q + 2 * n4kv + 255) / 256;
    f32_to_bf16_all<<<nb, 256, 0, stream>>>(query, key, value, qbf, kbf, vbf,
                                            n4q, n4kv);
  }
  // 2) weight transposes: all four in ONE launch (z selects)
  transpose4_k<<<dim3(QDIM / 32, QDIM / 32, 4), 256, 0, stream>>>(
      Wq, Wk, Wv, Wo, wqt, wkt, wvt, wot);

  // 3) projections: Q scaled by QSCALE (softmax exp2-domain fold); K+V fused
  gemm_bt256<<<(NQTOT / 128) * (QDIM / 256), 512, 0, stream>>>(
      qbf, wqt, bq, nullptr, Qp, (int)NQTOT, QDIM, QDIM, 1, QSCALE);
  gemm_kv<<<(NKTOT / 128) * (QDIM / 128) * 2, 256, 0, stream>>>(
      kbf, vbf, wkt, wvt, bk, bv, Kp, VT, (int)NKTOT, QDIM, KDIM);

  // 4) fused attention -> AO (bf16, (B*Nq, 1024))
  attn_kernel<<<dim3(NQ / 128, B_SZ * NH), 256, 0, stream>>>(Qp, Kp, VT, AO);

  // 5) output projection (fp32 out)
  gemm_bt256<<<(NQTOT / 128) * (QDIM / 256), 512, 0, stream>>>(
      AO, wot, bo, (float*)d_out, nullptr, (int)NQTOT, QDIM, QDIM, 0, 1.0f);

  (void)in_sizes; (void)n_in; (void)out_size; (void)ws_size;
}